// Round 11
// baseline (505.164 us; speedup 1.0000x reference)
//
#include <hip/hip_runtime.h>
#include <hip/hip_bf16.h>
#include <math.h>

#define NSEQ 2048
#define ROWS 4096   // B*N
#define KNN 9
#define MB (1ull << 20)

typedef short bh8 __attribute__((ext_vector_type(8)));   // 8 bf16 in 4 VGPRs
typedef float f4v __attribute__((ext_vector_type(4)));
typedef unsigned long long u64k;

__device__ __forceinline__ short f2bf(float f) {
    union { float f; unsigned u; } v; v.f = f;
    unsigned r = (v.u + 0x7fffu + ((v.u >> 16) & 1u)) >> 16;
    return (short)r;
}
__device__ __forceinline__ float b2f(short s) {
    union { unsigned u; float f; } v; v.u = ((unsigned)(unsigned short)s) << 16; return v.f;
}

// async global->LDS, 16B per lane; LDS dest is wave-uniform base + lane*16
__device__ __forceinline__ void gload16(const void* g, void* l) {
    __builtin_amdgcn_global_load_lds(
        (const __attribute__((address_space(1))) void*)g,
        (__attribute__((address_space(3))) void*)l, 16, 0, 0);
}

// ---------- block reduce (blockDim.x == 256) ----------
__device__ __forceinline__ float blockReduceSum(float v, float* red) {
    int tid = threadIdx.x;
    red[tid] = v; __syncthreads();
    for (int s = 128; s > 0; s >>= 1) {
        if (tid < s) red[tid] += red[tid + s];
        __syncthreads();
    }
    float r = red[0]; __syncthreads();
    return r;
}

// ---------- f32 -> bf16 conversion (weights + X), 10 segments ----------
struct CvtArgs { const float* src[10]; short* dst[10]; int n4[10]; };
__global__ __launch_bounds__(256) void cvt_k(CvtArgs a) {
    int s = blockIdx.y;
    const float* sp = a.src[s]; short* dp = a.dst[s]; int n = a.n4[s];
    for (int i = blockIdx.x * 256 + threadIdx.x; i < n; i += gridDim.x * 256) {
        float4 v = ((const float4*)sp)[i];
        short4 o; o.x = f2bf(v.x); o.y = f2bf(v.y); o.z = f2bf(v.z); o.w = f2bf(v.w);
        ((short4*)dp)[i] = o;
    }
}

// ---------- shared epilogue writer ----------
template <int OUTMODE>
__device__ __forceinline__ void gemm_epilogue(int row, int col, int N, const f4v& a,
        float bv, float* Cf, short* Cb, short* Kb_, short* Vt_)
{
    if (OUTMODE == 3) {
        int b = row >> 11, n0 = row & 2047;
        if (col < 512) {
            int h = col >> 6, d = col & 63;
            size_t base = (((size_t)(b * 8 + h) * NSEQ + n0) << 6) + d;
            #pragma unroll
            for (int rr = 0; rr < 4; ++rr)
                Cb[base + ((size_t)rr << 6)] = f2bf((a[rr] + bv) * 0.18033688f);
        } else if (col < 1024) {
            int cc = col - 512, h = cc >> 6, d = cc & 63;
            size_t base = (((size_t)(b * 8 + h) * NSEQ + n0) << 6) + d;
            #pragma unroll
            for (int rr = 0; rr < 4; ++rr)
                Kb_[base + ((size_t)rr << 6)] = f2bf(a[rr] + bv);
        } else {
            int cc = col - 1024, h = cc >> 6, d = cc & 63;
            short4 ov;
            ov.x = f2bf(a[0] + bv); ov.y = f2bf(a[1] + bv);
            ov.z = f2bf(a[2] + bv); ov.w = f2bf(a[3] + bv);
            *(short4*)(Vt_ + (((size_t)((b * 8 + h) * 64 + d)) << 11) + n0) = ov;
        }
    } else {
        #pragma unroll
        for (int rr = 0; rr < 4; ++rr) {
            float v = a[rr] + bv;
            if (OUTMODE == 0) Cf[(size_t)(row + rr) * N + col] = v;
            else if (OUTMODE == 1) Cb[(size_t)(row + rr) * N + col] = f2bf(v);
            else if (OUTMODE == 2) {
                Cf[(size_t)(row + rr) * N + col] = v;
                Cb[(size_t)(row + rr) * N + col] = f2bf(v);
            } else if (OUTMODE == 4) {
                Cb[(size_t)(row + rr) * N + col] = f2bf(0.5f * v * (1.f + erff(v * 0.70710678118654752f)));
            } else if (OUTMODE == 5) {
                Cf[(size_t)(row + rr) * N + col] = tanhf(v);
            }
        }
    }
}

// ---------- MFMA GEMM 64x64 tile (N=512-class), dbuf prefetch, swizzled ----------
template <int OUTMODE>
__global__ __launch_bounds__(256) void mfma_gemm(
        const short* __restrict__ A, const short* __restrict__ W,
        const float* __restrict__ bias, float* __restrict__ Cf, short* __restrict__ Cb,
        int M, int N, int K)
{
    __shared__ short As[2][64 * 64];
    __shared__ short Bs[2][64 * 64];
    int tid = threadIdx.x;
    int wv = tid >> 6, l = tid & 63;
    int g = l >> 4, c = l & 15;
    int wr = wv >> 1, wc = wv & 1;
    int bm = blockIdx.y * 64, bn = blockIdx.x * 64;
    int sr = l >> 3, sc = ((l & 7) ^ sr) * 8;
    const short* Ap = A + (size_t)(bm + wv * 16 + sr) * K + sc;
    const short* Wp = W + (size_t)(bn + wv * 16 + sr) * K + sc;
    int ldsB = (wv * 16) * 64;

    #define GSTAGE(buf, k0) { \
        gload16(Ap + (k0), &As[buf][ldsB]); \
        gload16(Ap + (size_t)8 * K + (k0), &As[buf][ldsB + 8 * 64]); \
        gload16(Wp + (k0), &Bs[buf][ldsB]); \
        gload16(Wp + (size_t)8 * K + (k0), &Bs[buf][ldsB + 8 * 64]); }

    f4v acc[2][2] = {};
    GSTAGE(0, 0);
    __syncthreads();
    int nk = K >> 6;
    for (int t = 0; t < nk; ++t) {
        int cur = t & 1;
        if (t + 1 < nk) GSTAGE(cur ^ 1, (t + 1) << 6);
        #pragma unroll
        for (int ks = 0; ks < 2; ++ks) {
            bh8 af[2], bf_[2];
            #pragma unroll
            for (int mi = 0; mi < 2; ++mi) {
                int row = wr * 32 + mi * 16 + c;
                af[mi] = *(const bh8*)(&As[cur][row * 64 + (((ks * 4 + g) ^ (c & 7)) * 8)]);
            }
            #pragma unroll
            for (int ni = 0; ni < 2; ++ni) {
                int row = wc * 32 + ni * 16 + c;
                bf_[ni] = *(const bh8*)(&Bs[cur][row * 64 + (((ks * 4 + g) ^ (c & 7)) * 8)]);
            }
            #pragma unroll
            for (int mi = 0; mi < 2; ++mi)
                #pragma unroll
                for (int ni = 0; ni < 2; ++ni)
                    acc[mi][ni] = __builtin_amdgcn_mfma_f32_16x16x32_bf16(af[mi], bf_[ni], acc[mi][ni], 0, 0, 0);
        }
        __syncthreads();
    }
    #undef GSTAGE
    short* Kb_ = (OUTMODE == 3) ? Cb + 2097152 : nullptr;
    short* Vt_ = (OUTMODE == 3) ? Cb + 4194304 : nullptr;
    #pragma unroll
    for (int mi = 0; mi < 2; ++mi) {
        int row = bm + wr * 32 + mi * 16 + g * 4;
        #pragma unroll
        for (int ni = 0; ni < 2; ++ni) {
            int col = bn + wc * 32 + ni * 16 + c;
            gemm_epilogue<OUTMODE>(row, col, N, acc[mi][ni], bias[col], Cf, Cb, Kb_, Vt_);
        }
    }
}

// ---------- MFMA GEMM 128x128 tile (wide-N), wave tile 64x64, dbuf, swizzled ----------
template <int OUTMODE>
__global__ __launch_bounds__(256) void mfma_gemm_big(
        const short* __restrict__ A, const short* __restrict__ W,
        const float* __restrict__ bias, float* __restrict__ Cf, short* __restrict__ Cb,
        int M, int N, int K)
{
    __shared__ short As[2][128 * 64];
    __shared__ short Bs[2][128 * 64];
    int tid = threadIdx.x;
    int wv = tid >> 6, l = tid & 63;
    int g = l >> 4, c = l & 15;
    int wr = wv >> 1, wc = wv & 1;
    int bm = blockIdx.y * 128, bn = blockIdx.x * 128;
    int sr = l >> 3, sc = ((l & 7) ^ sr) * 8;
    const short* Ap = A + (size_t)(bm + wv * 32 + sr) * K + sc;
    const short* Wp = W + (size_t)(bn + wv * 32 + sr) * K + sc;
    int ldsB = (wv * 32) * 64;

    #define GSTAGE(buf, k0) { \
        gload16(Ap + (k0),                   &As[buf][ldsB]); \
        gload16(Ap + (size_t) 8 * K + (k0),  &As[buf][ldsB + 8 * 64]); \
        gload16(Ap + (size_t)16 * K + (k0),  &As[buf][ldsB + 16 * 64]); \
        gload16(Ap + (size_t)24 * K + (k0),  &As[buf][ldsB + 24 * 64]); \
        gload16(Wp + (k0),                   &Bs[buf][ldsB]); \
        gload16(Wp + (size_t) 8 * K + (k0),  &Bs[buf][ldsB + 8 * 64]); \
        gload16(Wp + (size_t)16 * K + (k0),  &Bs[buf][ldsB + 16 * 64]); \
        gload16(Wp + (size_t)24 * K + (k0),  &Bs[buf][ldsB + 24 * 64]); }

    f4v acc[4][4] = {};
    GSTAGE(0, 0);
    __syncthreads();
    int nk = K >> 6;
    for (int t = 0; t < nk; ++t) {
        int cur = t & 1;
        if (t + 1 < nk) GSTAGE(cur ^ 1, (t + 1) << 6);
        #pragma unroll
        for (int ks = 0; ks < 2; ++ks) {
            bh8 af[4], bf_[4];
            #pragma unroll
            for (int mi = 0; mi < 4; ++mi) {
                int row = wr * 64 + mi * 16 + c;
                af[mi] = *(const bh8*)(&As[cur][row * 64 + (((ks * 4 + g) ^ (c & 7)) * 8)]);
            }
            #pragma unroll
            for (int ni = 0; ni < 4; ++ni) {
                int row = wc * 64 + ni * 16 + c;
                bf_[ni] = *(const bh8*)(&Bs[cur][row * 64 + (((ks * 4 + g) ^ (c & 7)) * 8)]);
            }
            #pragma unroll
            for (int mi = 0; mi < 4; ++mi)
                #pragma unroll
                for (int ni = 0; ni < 4; ++ni)
                    acc[mi][ni] = __builtin_amdgcn_mfma_f32_16x16x32_bf16(af[mi], bf_[ni], acc[mi][ni], 0, 0, 0);
        }
        __syncthreads();
    }
    #undef GSTAGE
    short* Kb_ = (OUTMODE == 3) ? Cb + 2097152 : nullptr;
    short* Vt_ = (OUTMODE == 3) ? Cb + 4194304 : nullptr;
    #pragma unroll
    for (int mi = 0; mi < 4; ++mi) {
        int row = bm + wr * 64 + mi * 16 + g * 4;
        #pragma unroll
        for (int ni = 0; ni < 4; ++ni) {
            int col = bn + wc * 64 + ni * 16 + c;
            gemm_epilogue<OUTMODE>(row, col, N, acc[mi][ni], bias[col], Cf, Cb, Kb_, Vt_);
        }
    }
}

// ---------- gram for KNN distances, hi/lo split, 64x64 tiles, swizzled LDS ----------
__global__ __launch_bounds__(256) void mfma_gram(
        const short* __restrict__ Hi, const short* __restrict__ Lo,
        const float* __restrict__ SQ, float* __restrict__ D2)
{
    __shared__ short HiR[64 * 64], LoR[64 * 64], HiC[64 * 64], LoC[64 * 64];
    int tid = threadIdx.x;
    int wv = tid >> 6, l = tid & 63;
    int g = l >> 4, c = l & 15;
    int wr = wv >> 1, wc = wv & 1;
    int bm = blockIdx.y * 64, bn = blockIdx.x * 64;
    int sr = l >> 3, sc = ((l & 7) ^ sr) * 8;
    const short* hiR = Hi + (size_t)(bm + wv * 16 + sr) * 512 + sc;
    const short* loR = Lo + (size_t)(bm + wv * 16 + sr) * 512 + sc;
    const short* hiC = Hi + (size_t)(bn + wv * 16 + sr) * 512 + sc;
    const short* loC = Lo + (size_t)(bn + wv * 16 + sr) * 512 + sc;
    int ldsOff = (wv * 16) * 64;
    f4v acc[2][2] = {};
    for (int k0 = 0; k0 < 512; k0 += 64) {
        __syncthreads();
        gload16(hiR + k0, HiR + ldsOff);
        gload16(hiR + (size_t)8 * 512 + k0, HiR + ldsOff + 8 * 64);
        gload16(loR + k0, LoR + ldsOff);
        gload16(loR + (size_t)8 * 512 + k0, LoR + ldsOff + 8 * 64);
        gload16(hiC + k0, HiC + ldsOff);
        gload16(hiC + (size_t)8 * 512 + k0, HiC + ldsOff + 8 * 64);
        gload16(loC + k0, LoC + ldsOff);
        gload16(loC + (size_t)8 * 512 + k0, LoC + ldsOff + 8 * 64);
        __syncthreads();
        #pragma unroll
        for (int ks = 0; ks < 2; ++ks) {
            bh8 hr[2], lr_[2], hc[2], lc[2];
            #pragma unroll
            for (int mi = 0; mi < 2; ++mi) {
                int o = (wr * 32 + mi * 16 + c) * 64 + (((ks * 4 + g) ^ (c & 7)) * 8);
                hr[mi] = *(const bh8*)(HiR + o);
                lr_[mi] = *(const bh8*)(LoR + o);
            }
            #pragma unroll
            for (int ni = 0; ni < 2; ++ni) {
                int o = (wc * 32 + ni * 16 + c) * 64 + (((ks * 4 + g) ^ (c & 7)) * 8);
                hc[ni] = *(const bh8*)(HiC + o);
                lc[ni] = *(const bh8*)(LoC + o);
            }
            #pragma unroll
            for (int mi = 0; mi < 2; ++mi)
                #pragma unroll
                for (int ni = 0; ni < 2; ++ni) {
                    acc[mi][ni] = __builtin_amdgcn_mfma_f32_16x16x32_bf16(hr[mi], hc[ni], acc[mi][ni], 0, 0, 0);
                    acc[mi][ni] = __builtin_amdgcn_mfma_f32_16x16x32_bf16(hr[mi], lc[ni], acc[mi][ni], 0, 0, 0);
                    acc[mi][ni] = __builtin_amdgcn_mfma_f32_16x16x32_bf16(lr_[mi], hc[ni], acc[mi][ni], 0, 0, 0);
                }
        }
    }
    #pragma unroll
    for (int mi = 0; mi < 2; ++mi) {
        int row = bm + wr * 32 + mi * 16 + g * 4;
        #pragma unroll
        for (int ni = 0; ni < 2; ++ni) {
            int col = bn + wc * 32 + ni * 16 + c;
            float sqc = SQ[col];
            #pragma unroll
            for (int rr = 0; rr < 4; ++rr)
                D2[(size_t)(row + rr) * NSEQ + col] = SQ[row + rr] + sqc - 2.f * acc[mi][ni][rr];
        }
    }
}

// ---------- top-9 smallest per row: u64 keys, sort8 + LDS merge tree ----------
__global__ __launch_bounds__(256) void topk9_k(const float* __restrict__ D2, int* __restrict__ idx)
{
    int n = blockIdx.x, tid = threadIdx.x;
    __shared__ u64k lists[256][9];
    u64k a[8];
    union { float f; unsigned u; } cv;
    #pragma unroll
    for (int j = 0; j < 8; ++j) {
        int mcol = tid + j * 256;
        cv.f = fmaxf(D2[(size_t)n * NSEQ + mcol], 0.f);
        a[j] = ((u64k)cv.u << 32) | (unsigned)mcol;
    }
    #define CE(i,j) { u64k x = a[i], y = a[j]; bool t = x < y; a[i] = t ? x : y; a[j] = t ? y : x; }
    CE(0,1) CE(2,3) CE(4,5) CE(6,7)
    CE(0,2) CE(1,3) CE(4,6) CE(5,7)
    CE(1,2) CE(5,6)
    CE(0,4) CE(1,5) CE(2,6) CE(3,7)
    CE(2,4) CE(3,5)
    CE(1,2) CE(3,4) CE(5,6)
    #undef CE
    #pragma unroll
    for (int j = 0; j < 8; ++j) lists[tid][j] = a[j];
    lists[tid][8] = ~0ull;
    __syncthreads();
    for (int s = 128; s >= 1; s >>= 1) {
        if (tid < s) {
            u64k out[9];
            u64k* Al = lists[tid];
            u64k* Bl = lists[tid + s];
            int ia = 0, ib = 0;
            #pragma unroll
            for (int o = 0; o < 9; ++o) {
                u64k av = Al[ia], bv = Bl[ib];
                bool t = av <= bv;
                out[o] = t ? av : bv;
                ia += t; ib += !t;
            }
            #pragma unroll
            for (int o = 0; o < 9; ++o) Al[o] = out[o];
        }
        __syncthreads();
    }
    if (tid < 9) idx[n * KNN + tid] = (int)(lists[0][tid] & 0xffffffffu);
}

// ---------- GCN aggregate + LN + leaky + residual (writes f32 + bf16) ----------
__global__ __launch_bounds__(256) void gcn_post(
        const float* __restrict__ s, const int* __restrict__ idx,
        const float* __restrict__ g, const float* __restrict__ be,
        float* __restrict__ hg, short* __restrict__ hgb)
{
    int row = blockIdx.x, tid = threadIdx.x;
    int bb = row >> 11;
    __shared__ float os[512];
    __shared__ float red[256];
    int id[KNN];
    #pragma unroll
    for (int j = 0; j < KNN; ++j) id[j] = idx[row * KNN + j] + (bb << 11);
    for (int c = tid; c < 512; c += 256) {
        float acc = 0.f;
        #pragma unroll
        for (int j = 0; j < KNN; ++j) acc += s[((size_t)id[j] << 9) + c];
        os[c] = acc * (1.f / 9.f);
    }
    __syncthreads();
    float mean = blockReduceSum(os[tid] + os[tid + 256], red) * (1.f / 512.f);
    float d0 = os[tid] - mean, d1 = os[tid + 256] - mean;
    float var = blockReduceSum(d0 * d0 + d1 * d1, red) * (1.f / 512.f);
    float rs = rsqrtf(var + 1e-5f);
    size_t base = (size_t)row << 9;
    for (int c = tid; c < 512; c += 256) {
        float y = (os[c] - mean) * rs * g[c] + be[c];
        y = y > 0.f ? y : 0.2f * y;
        float nv = y + hg[base + c];
        hg[base + c] = nv;
        hgb[base + c] = f2bf(nv);
    }
}

// ---------- x = LN(x + r)*g + b (writes f32 + bf16) ----------
__global__ __launch_bounds__(256) void ln_res(
        float* __restrict__ x, const float* __restrict__ r,
        const float* __restrict__ g, const float* __restrict__ b, short* __restrict__ xb)
{
    int row = blockIdx.x, tid = threadIdx.x;
    __shared__ float xs[512];
    __shared__ float red[256];
    size_t base = (size_t)row << 9;
    for (int c = tid; c < 512; c += 256) xs[c] = x[base + c] + r[base + c];
    __syncthreads();
    float mean = blockReduceSum(xs[tid] + xs[tid + 256], red) * (1.f / 512.f);
    float d0 = xs[tid] - mean, d1 = xs[tid + 256] - mean;
    float var = blockReduceSum(d0 * d0 + d1 * d1, red) * (1.f / 512.f);
    float rs = rsqrtf(var + 1e-5f);
    for (int c = tid; c < 512; c += 256) {
        float y = (xs[c] - mean) * rs * g[c] + b[c];
        x[base + c] = y;
        xb[base + c] = f2bf(y);
    }
}

// ---------- flash attention: swapped-operand, KV-split=4, K+V LDS dbuf ----------
__global__ __launch_bounds__(256) void flash_attn(
        const short* __restrict__ Qb, const short* __restrict__ Kb,
        const short* __restrict__ Vt, short* __restrict__ Opb, float* __restrict__ Ml)
{
    __shared__ short Ks[2][4096];
    __shared__ short Vs[2][4096];
    int tid = threadIdx.x;
    int wid = tid >> 6, lane = tid & 63;
    int g = lane >> 4, c = lane & 15;
    int s = blockIdx.y, bh = blockIdx.z;
    int q0 = blockIdx.x * 64 + wid * 16;
    int srow = lane >> 3;
    int sc8 = ((lane & 7) ^ srow) * 8;
    int w8 = wid * 8;

    const short* KbB = Kb + ((size_t)bh * NSEQ + s * 512) * 64;
    const short* VtB = Vt + (size_t)bh * 64 * NSEQ + s * 512;

    const short* qbase = Qb + ((size_t)bh * NSEQ + q0 + c) * 64 + g * 8;
    bh8 qa0 = *(const bh8*)(qbase);
    bh8 qa1 = *(const bh8*)(qbase + 32);

    f4v o0 = {0,0,0,0}, o1 = {0,0,0,0}, o2 = {0,0,0,0}, o3 = {0,0,0,0};
    float lloc = 0.f;
    float mrun = -INFINITY;
    int hi2 = g >> 1;
    int s1 = c + (((g << 1) & 3) << 4);
    int s2 = c + ((((g << 1) + 1) & 3) << 4);

    #define FSTAGE(buf, kt) { \
        const short* kp_ = KbB + (size_t)(kt) * 64 * 64; \
        gload16(kp_ + (size_t)(w8 + srow) * 64 + sc8,        &Ks[buf][w8 * 64]); \
        gload16(kp_ + (size_t)(32 + w8 + srow) * 64 + sc8,   &Ks[buf][(32 + w8) * 64]); \
        const short* vp_ = VtB + (size_t)(kt) * 64; \
        gload16(vp_ + (size_t)(w8 + srow) * NSEQ + sc8,      &Vs[buf][w8 * 64]); \
        gload16(vp_ + (size_t)(32 + w8 + srow) * NSEQ + sc8, &Vs[buf][(32 + w8) * 64]); }

    FSTAGE(0, 0);
    __syncthreads();
    for (int t = 0; t < 8; ++t) {
        int cur = t & 1;
        if (t < 7) FSTAGE(cur ^ 1, t + 1);
        f4v sv[4];
        #pragma unroll
        for (int cb = 0; cb < 4; ++cb) {
            int row = cb * 16 + c;
            const short* kr = &Ks[cur][row * 64];
            bh8 kb0 = *(const bh8*)(kr + ((g ^ (row & 7)) * 8));
            bh8 kb1 = *(const bh8*)(kr + (((4 + g) ^ (row & 7)) * 8));
            f4v a = {0,0,0,0};
            a = __builtin_amdgcn_mfma_f32_16x16x32_bf16(kb0, qa0, a, 0, 0, 0);
            a = __builtin_amdgcn_mfma_f32_16x16x32_bf16(kb1, qa1, a, 0, 0, 0);
            sv[cb] = a;
        }
        float mt = fmaxf(fmaxf(fmaxf(sv[0][0], sv[0][1]), fmaxf(sv[0][2], sv[0][3])),
                         fmaxf(fmaxf(sv[1][0], sv[1][1]), fmaxf(sv[1][2], sv[1][3])));
        mt = fmaxf(mt, fmaxf(fmaxf(sv[2][0], sv[2][1]), fmaxf(sv[2][2], sv[2][3])));
        mt = fmaxf(mt, fmaxf(fmaxf(sv[3][0], sv[3][1]), fmaxf(sv[3][2], sv[3][3])));
        mt = fmaxf(mt, __shfl_xor(mt, 16));
        mt = fmaxf(mt, __shfl_xor(mt, 32));
        if (__any(mt > mrun + 6.f)) {
            float mn = fmaxf(mrun, mt);
            float al = __builtin_amdgcn_exp2f(mrun - mn);
            mrun = mn;
            o0 *= al; o1 *= al; o2 *= al; o3 *= al; lloc *= al;
        }
        unsigned wv_[8];
        #pragma unroll
        for (int cb = 0; cb < 4; ++cb) {
            float p0 = __builtin_amdgcn_exp2f(sv[cb][0] - mrun);
            float p1 = __builtin_amdgcn_exp2f(sv[cb][1] - mrun);
            float p2 = __builtin_amdgcn_exp2f(sv[cb][2] - mrun);
            float p3 = __builtin_amdgcn_exp2f(sv[cb][3] - mrun);
            lloc += (p0 + p1) + (p2 + p3);
            asm("v_cvt_pk_bf16_f32 %0, %1, %2" : "=v"(wv_[cb * 2])     : "v"(p0), "v"(p1));
            asm("v_cvt_pk_bf16_f32 %0, %1, %2" : "=v"(wv_[cb * 2 + 1]) : "v"(p2), "v"(p3));
        }
        union { unsigned u[4]; bh8 h; } pa0u, pa1u;
        {
            unsigned t0 = __shfl((int)wv_[0], s1), t2 = __shfl((int)wv_[2], s1);
            unsigned t1 = __shfl((int)wv_[1], s1), t3 = __shfl((int)wv_[3], s1);
            unsigned u0 = __shfl((int)wv_[0], s2), u2 = __shfl((int)wv_[2], s2);
            unsigned u1 = __shfl((int)wv_[1], s2), u3 = __shfl((int)wv_[3], s2);
            pa0u.u[0] = hi2 ? t2 : t0;
            pa0u.u[1] = hi2 ? t3 : t1;
            pa0u.u[2] = hi2 ? u2 : u0;
            pa0u.u[3] = hi2 ? u3 : u1;
        }
        {
            unsigned t0 = __shfl((int)wv_[4], s1), t2 = __shfl((int)wv_[6], s1);
            unsigned t1 = __shfl((int)wv_[5], s1), t3 = __shfl((int)wv_[7], s1);
            unsigned u0 = __shfl((int)wv_[4], s2), u2 = __shfl((int)wv_[6], s2);
            unsigned u1 = __shfl((int)wv_[5], s2), u3 = __shfl((int)wv_[7], s2);
            pa1u.u[0] = hi2 ? t2 : t0;
            pa1u.u[1] = hi2 ? t3 : t1;
            pa1u.u[2] = hi2 ? u2 : u0;
            pa1u.u[3] = hi2 ? u3 : u1;
        }
        #pragma unroll
        for (int db = 0; db < 4; ++db) {
            int row = db * 16 + c;
            const short* vr = &Vs[cur][row * 64];
            bh8 vb0 = *(const bh8*)(vr + ((g ^ (row & 7)) * 8));
            bh8 vb1 = *(const bh8*)(vr + (((4 + g) ^ (row & 7)) * 8));
            f4v* op = (db == 0) ? &o0 : (db == 1) ? &o1 : (db == 2) ? &o2 : &o3;
            *op = __builtin_amdgcn_mfma_f32_16x16x32_bf16(vb0, pa0u.h, *op, 0, 0, 0);
            *op = __builtin_amdgcn_mfma_f32_16x16x32_bf16(vb1, pa1u.h, *op, 0, 0, 0);
        }
        __syncthreads();
    }
    #undef FSTAGE
    float lsum = lloc;
    lsum += __shfl_xor(lsum, 16);
    lsum += __shfl_xor(lsum, 32);
    size_t qrow = ((size_t)(s * 16 + bh) * NSEQ) + q0 + c;
    size_t rb = qrow * 64 + g * 4;
    #pragma unroll
    for (int r = 0; r < 4; ++r) {
        Opb[rb + r]      = f2bf(o0[r]);
        Opb[rb + 16 + r] = f2bf(o1[r]);
        Opb[rb + 32 + r] = f2bf(o2[r]);
        Opb[rb + 48 + r] = f2bf(o3[r]);
    }
    if (g == 0) {
        Ml[qrow * 2]     = mrun;
        Ml[qrow * 2 + 1] = lsum;
    }
}

// ---------- merge 4 KV-splits -> bf16 attention output ----------
__global__ __launch_bounds__(256) void merge_k(const short* __restrict__ Opb, const float* __restrict__ Ml,
                                               short* __restrict__ aob)
{
    int idx = blockIdx.x * 256 + threadIdx.x;   // 16*2048*64
    int d = idx & 63, q = (idx >> 6) & 2047, bh = idx >> 17;
    float M = -INFINITY;
    float mv[4], lv[4];
    #pragma unroll
    for (int s = 0; s < 4; ++s) {
        size_t r = (size_t)(s * 16 + bh) * NSEQ + q;
        mv[s] = Ml[r * 2]; lv[s] = Ml[r * 2 + 1];
        M = fmaxf(M, mv[s]);
    }
    float L = 0.f, num = 0.f;
    #pragma unroll
    for (int s = 0; s < 4; ++s) {
        float w = __builtin_amdgcn_exp2f(mv[s] - M);
        L += lv[s] * w;
        num += b2f(Opb[((size_t)(s * 16 + bh) * NSEQ + q) * 64 + d]) * w;
    }
    int b = bh >> 3, h = bh & 7;
    aob[((size_t)(b * NSEQ + q)) * 512 + h * 64 + d] = f2bf(num / L);
}

// ---------- GLU per-row: h, copies, hi/lo split, fused row-sq ----------
__global__ __launch_bounds__(256) void glu_row_k(const float* __restrict__ vg, float* __restrict__ h,
        float* __restrict__ hgf, short* __restrict__ hi, short* __restrict__ lo,
        float* __restrict__ sq) {
    int row = blockIdx.x, tid = threadIdx.x;
    __shared__ float red[256];
    size_t vb = (size_t)row << 10;
    size_t hb = (size_t)row << 9;
    float ss = 0.f;
    #pragma unroll
    for (int j = 0; j < 2; ++j) {
        int c = tid + j * 256;
        float v = vg[vb + c], gt = vg[vb + 512 + c];
        float hv = v * (1.f / (1.f + __expf(-gt)));
        h[hb + c] = hv; hgf[hb + c] = hv;
        short hbb = f2bf(hv);
        hi[hb + c] = hbb;
        lo[hb + c] = f2bf(hv - b2f(hbb));
        ss = fmaf(hv, hv, ss);
    }
    float sm = blockReduceSum(ss, red);
    if (tid == 0) sq[row] = sm;
}

__global__ void concat_bf(const short* __restrict__ hgb, const short* __restrict__ htb,
                          short* __restrict__ cat) {
    for (int i = blockIdx.x * 256 + threadIdx.x; i < ROWS * 256; i += gridDim.x * 256) {
        int row = i >> 8, c4 = (i & 255) * 4;
        short4 v = (c4 < 512) ? *(const short4*)(hgb + ((size_t)row << 9) + c4)
                              : *(const short4*)(htb + ((size_t)row << 9) + c4 - 512);
        *(short4*)(cat + ((size_t)row << 10) + c4) = v;
    }
}

// ---------- pooling / classifier ----------
__global__ __launch_bounds__(256) void rowdot_k(const float* __restrict__ t, const float* __restrict__ w2,
                                                const float* __restrict__ b2, float* __restrict__ srow) {
    int row = blockIdx.x, tid = threadIdx.x;
    __shared__ float red[256];
    float s = blockReduceSum(t[(size_t)row * 256 + tid] * w2[tid], red);
    if (tid == 0) srow[row] = s + b2[0];
}
__global__ __launch_bounds__(256) void softmax_n_k(const float* __restrict__ srow, float* __restrict__ a,
                                                   float* __restrict__ out) {
    int b = blockIdx.x, tid = threadIdx.x;
    __shared__ float red[256];
    float mx = -INFINITY;
    for (int n = tid; n < NSEQ; n += 256) mx = fmaxf(mx, srow[b * NSEQ + n]);
    red[tid] = mx; __syncthreads();
    for (int s = 128; s > 0; s >>= 1) {
        if (tid < s) red[tid] = fmaxf(red[tid], red[tid + s]);
        __syncthreads();
    }
    mx = red[0]; __syncthreads();
    float sm = 0.f;
    for (int n = tid; n < NSEQ; n += 256) {
        float e = expf(srow[b * NSEQ + n] - mx);
        a[b * NSEQ + n] = e; sm += e;
    }
    float inv = 1.f / blockReduceSum(sm, red);
    for (int n = tid; n < NSEQ; n += 256) {
        float v = a[b * NSEQ + n] * inv;
        a[b * NSEQ + n] = v;
        out[2 + b * NSEQ + n] = v;
    }
}
__global__ __launch_bounds__(256) void pool_part(const float* __restrict__ hf, const float* __restrict__ a,
                                                 float* __restrict__ part) {
    int b = blockIdx.y, chunk = blockIdx.x, tid = threadIdx.x;
    float a0 = 0.f, a1 = 0.f;
    for (int r = 0; r < 64; ++r) {
        int n = chunk * 64 + r;
        float wgt = a[b * NSEQ + n];
        const float* row = hf + ((size_t)(b * NSEQ + n) << 9);
        a0 = fmaf(row[tid], wgt, a0);
        a1 = fmaf(row[tid + 256], wgt, a1);
    }
    part[((b * 32 + chunk) << 9) + tid] = a0;
    part[((b * 32 + chunk) << 9) + tid + 256] = a1;
}
__global__ __launch_bounds__(256) void pool_fin(const float* __restrict__ part, float* __restrict__ Mb,
                                                float* __restrict__ out) {
    int b = blockIdx.x, tid = threadIdx.x;
    float s0 = 0.f, s1 = 0.f;
    for (int ch = 0; ch < 32; ++ch) {
        s0 += part[((b * 32 + ch) << 9) + tid];
        s1 += part[((b * 32 + ch) << 9) + tid + 256];
    }
    Mb[b * 512 + tid] = s0; Mb[b * 512 + tid + 256] = s1;
    out[2 + ROWS + b * 512 + tid] = s0; out[2 + ROWS + b * 512 + tid + 256] = s1;
}
__global__ __launch_bounds__(256) void classifier_k(const float* __restrict__ Mb,
        const float* __restrict__ w1, const float* __restrict__ b1,
        const float* __restrict__ w2, const float* __restrict__ b2, float* __restrict__ out) {
    int b = blockIdx.x, tid = threadIdx.x;
    __shared__ float Ms[512];
    __shared__ float red[256];
    for (int c = tid; c < 512; c += 256) Ms[c] = Mb[b * 512 + c];
    __syncthreads();
    float acc = 0.f;
    for (int c = 0; c < 512; ++c) acc = fmaf(Ms[c], w1[tid * 512 + c], acc);
    acc += b1[tid];
    float hj = acc > 0.f ? acc : expm1f(acc);   // ELU alpha=1
    float s = blockReduceSum(hj * w2[tid], red);
    if (tid == 0) out[b] = s + b2[0];
}

extern "C" void kernel_launch(void* const* d_in, const int* in_sizes, int n_in,
                              void* d_out, int out_size, void* d_ws, size_t ws_size,
                              hipStream_t stream)
{
    const float* X      = (const float*)d_in[0];
    const float* Wstart = (const float*)d_in[1];
    const float* Bstart = (const float*)d_in[2];
    const float* GluW   = (const float*)d_in[3];
    const float* GluB   = (const float*)d_in[4];
    const float* GcnW   = (const float*)d_in[5];
    const float* GcnB   = (const float*)d_in[6];
    const float* GcnG   = (const float*)d_in[7];
    const float* GcnBe  = (const float*)d_in[8];
    const float* QkvW   = (const float*)d_in[9];
    const float* QkvB   = (const float*)d_in[10];
    const float* OutW   = (const float*)d_in[11];
    const float* OutB   = (const float*)d_in[12];
    const float* Ln1G   = (const float*)d_in[13];
    const float* Ln1B   = (const float*)d_in[14];
    const float* Ffn1W  = (const float*)d_in[15];
    const float* Ffn1B  = (const float*)d_in[16];
    const float* Ffn2W  = (const float*)d_in[17];
    const float* Ffn2B  = (const float*)d_in[18];
    const float* Ln2G   = (const float*)d_in[19];
    const float* Ln2B   = (const float*)d_in[20];
    const float* FusW   = (const float*)d_in[21];
    const float* FusB   = (const float*)d_in[22];
    const float* AW1    = (const float*)d_in[23];
    const float* AB1    = (const float*)d_in[24];
    const float* AW2    = (const float*)d_in[25];
    const float* AB2    = (const float*)d_in[26];
    const float* CW1    = (const float*)d_in[27];
    const float* CB1    = (const float*)d_in[28];
    const float* CW2    = (const float*)d_in[29];
    const float* CB2    = (const float*)d_in[30];
    float* out = (float*)d_out;

    if (ws_size < 86 * MB) return;

    char* w = (char*)d_ws;
    // bf16 weight arena [0,13MB)
    short* Wb = (short*)w;
    short* wbStart = Wb;
    short* wbGlu   = Wb + 524288;
    short* wbGcn   = Wb + 1048576;
    short* wbQkv   = Wb + 1572864;
    short* wbOut   = Wb + 3145728;
    short* wbFfn1  = Wb + 3670016;
    short* wbFfn2  = Wb + 4718592;
    short* wbFus   = Wb + 5767168;
    short* wbAw1   = Wb + 6291456;
    // small [13MB,14MB)
    float* sq   = (float*)(w + 13 * MB);
    int*   idx  = (int*)  (w + 13 * MB + (16u << 10));
    float* srow = (float*)(w + 13 * MB + (176u << 10));
    float* afb  = (float*)(w + 13 * MB + (192u << 10));
    float* Mbuf = (float*)(w + 13 * MB + (208u << 10));
    float* part = (float*)(w + 13 * MB + (212u << 10));
    // overlapped big buffers
    short* Xbf  = (short*)(w + 14 * MB);   // 8MB -> hg after fc_start
    float* hg   = (float*)(w + 14 * MB);
    short* hpreb= (short*)(w + 22 * MB);   // 4MB -> hgb after GLU gemm
    short* hgb  = (short*)(w + 22 * MB);
    float* big  = (float*)(w + 26 * MB);   // 26..42MB: vg/D2/gcn-s/Opb/out-proj
    short* Opb  = (short*)(w + 26 * MB);   // 16MB: 4 splits (bf16 O-partials)
    float* Ml   = (float*)(w + 42 * MB);   // 1MB (dead ffn2o window during attn)
    float* ffn2o= (float*)(w + 42 * MB);   // 8MB
    float* h    = (float*)(w + 50 * MB);   // 8MB; doubles as ht residual
    short* hhi  = (short*)(w + 58 * MB);   // 4MB; -> hf low half after loop
    short* hlo  = (short*)(w + 62 * MB);   // 4MB; dead after gram -> htb
    short* htb  = (short*)(w + 62 * MB);   // 4MB
    float* hf   = (float*)(w + 58 * MB);   // 8MB (after transformer loop)
    short* hfb  = (short*)(w + 66 * MB);   // 4MB
    short* aob  = (short*)(w + 70 * MB);   // 4MB; -> t256 (pool)
    float* t256 = (float*)(w + 70 * MB);
    short* Qb   = (short*)(w + 74 * MB);   // 4MB  (OUTMODE=3: K=Qb+4MB, Vt=Qb+8MB)
    short* Kb   = (short*)(w + 78 * MB);   // 4MB
    short* Vt   = (short*)(w + 82 * MB);   // 4MB (transposed V, written by qkv GEMM)
    short* ffb  = (short*)(w + 74 * MB);   // 8MB (ffn1 out; Qb/Kb dead) -> catb
    short* catb = (short*)(w + 74 * MB);

    dim3 blk(256);

    // convert X + all GEMM weights to bf16
    CvtArgs ca;
    ca.src[0] = X;     ca.dst[0] = Xbf;     ca.n4[0] = ROWS * 1024 / 4;
    ca.src[1] = Wstart;ca.dst[1] = wbStart; ca.n4[1] = 524288 / 4;
    ca.src[2] = GluW;  ca.dst[2] = wbGlu;   ca.n4[2] = 524288 / 4;
    ca.src[3] = GcnW;  ca.dst[3] = wbGcn;   ca.n4[3] = 524288 / 4;
    ca.src[4] = QkvW;  ca.dst[4] = wbQkv;   ca.n4[4] = 1572864 / 4;
    ca.src[5] = OutW;  ca.dst[5] = wbOut;   ca.n4[5] = 524288 / 4;
    ca.src[6] = Ffn1W; ca.dst[6] = wbFfn1;  ca.n4[6] = 1048576 / 4;
    ca.src[7] = Ffn2W; ca.dst[7] = wbFfn2;  ca.n4[7] = 1048576 / 4;
    ca.src[8] = FusW;  ca.dst[8] = wbFus;   ca.n4[8] = 524288 / 4;
    ca.src[9] = AW1;   ca.dst[9] = wbAw1;   ca.n4[9] = 131072 / 4;
    cvt_k<<<dim3(256, 10), blk, 0, stream>>>(ca);

    // fc_start -> GLU (fused rowsq)
    mfma_gemm<1><<<dim3(8, 64), blk, 0, stream>>>(Xbf, wbStart, Bstart, nullptr, hpreb, ROWS, 512, 1024);
    mfma_gemm_big<0><<<dim3(8, 32), blk, 0, stream>>>(hpreb, wbGlu, GluB, big, nullptr, ROWS, 1024, 512);
    glu_row_k<<<dim3(ROWS), blk, 0, stream>>>(big, h, hg, hhi, hlo, sq);

    // KNN graph (hi/lo split gram, f32-equivalent ranking)
    for (int b = 0; b < 2; ++b) {
        mfma_gram<<<dim3(32, 32), blk, 0, stream>>>(hhi + (size_t)b * NSEQ * 512,
                                                    hlo + (size_t)b * NSEQ * 512,
                                                    sq + b * NSEQ, big);
        topk9_k<<<dim3(NSEQ), blk, 0, stream>>>(big, idx + b * NSEQ * KNN);
    }

    // GCN branch
    const short* gA = hhi;
    for (int i = 0; i < 2; ++i) {
        mfma_gemm<0><<<dim3(8, 64), blk, 0, stream>>>(gA, wbGcn + (size_t)i * 262144,
                                                      GcnB + i * 512, big, nullptr, ROWS, 512, 512);
        gcn_post<<<dim3(ROWS), blk, 0, stream>>>(big, idx, GcnG + i * 512, GcnBe + i * 512, hg, hgb);
        gA = hgb;
    }

    // Transformer branch (h doubles as ht residual)
    const short* tA = hhi;
    for (int i = 0; i < 2; ++i) {
        mfma_gemm_big<3><<<dim3(12, 32), blk, 0, stream>>>(tA, wbQkv + (size_t)i * 786432,
                                                           QkvB + i * 1536, nullptr, Qb, ROWS, 1536, 512);
        flash_attn<<<dim3(32, 4, 16), blk, 0, stream>>>(Qb, Kb, Vt, Opb, Ml);
        merge_k<<<dim3(8192), blk, 0, stream>>>(Opb, Ml, aob);
        mfma_gemm<0><<<dim3(8, 64), blk, 0, stream>>>(aob, wbOut + (size_t)i * 262144,
                                                      OutB + i * 512, big, nullptr, ROWS, 512, 512);
        ln_res<<<dim3(ROWS), blk, 0, stream>>>(h, big, Ln1G + i * 512, Ln1B + i * 512, htb);
        mfma_gemm_big<4><<<dim3(8, 32), blk, 0, stream>>>(htb, wbFfn1 + (size_t)i * 524288,
                                                          Ffn1B + i * 1024, nullptr, ffb, ROWS, 1024, 512);
        mfma_gemm<0><<<dim3(8, 64), blk, 0, stream>>>(ffb, wbFfn2 + (size_t)i * 524288,
                                                      Ffn2B + i * 512, ffn2o, nullptr, ROWS, 512, 1024);
        ln_res<<<dim3(ROWS), blk, 0, stream>>>(h, ffn2o, Ln2G + i * 512, Ln2B + i * 512, htb);
        tA = htb;
    }

    // fusion
    concat_bf<<<dim3(2048), blk, 0, stream>>>(hgb, htb, catb);
    mfma_gemm<2><<<dim3(8, 64), blk, 0, stream>>>(catb, wbFus, FusB, hf, hfb, ROWS, 512, 1024);

    // gated attention pooling (tanh fused into GEMM)
    mfma_gemm<5><<<dim3(4, 64), blk, 0, stream>>>(hfb, wbAw1, AB1, t256, nullptr, ROWS, 256, 512);
    rowdot_k<<<dim3(ROWS), blk, 0, stream>>>(t256, AW2, AB2, srow);
    softmax_n_k<<<dim3(2), blk, 0, stream>>>(srow, afb, out);
    pool_part<<<dim3(32, 2), blk, 0, stream>>>(hf, afb, part);
    pool_fin<<<dim3(2), blk, 0, stream>>>(part, Mbuf, out);

    // classifier
    classifier_k<<<dim3(2), blk, 0, stream>>>(Mbuf, CW1, CB1, CW2, CB2, out);
}

// Round 12
// 436.316 us; speedup vs baseline: 1.1578x; 1.1578x over previous
//
#include <hip/hip_runtime.h>
#include <hip/hip_bf16.h>
#include <math.h>

#define NSEQ 2048
#define ROWS 4096   // B*N
#define KNN 9
#define MB (1ull << 20)

typedef short bh8 __attribute__((ext_vector_type(8)));   // 8 bf16 in 4 VGPRs
typedef float f4v __attribute__((ext_vector_type(4)));
typedef unsigned long long u64k;

__device__ __forceinline__ short f2bf(float f) {
    union { float f; unsigned u; } v; v.f = f;
    unsigned r = (v.u + 0x7fffu + ((v.u >> 16) & 1u)) >> 16;
    return (short)r;
}
__device__ __forceinline__ float b2f(short s) {
    union { unsigned u; float f; } v; v.u = ((unsigned)(unsigned short)s) << 16; return v.f;
}

// async global->LDS, 16B per lane; LDS dest is wave-uniform base + lane*16
__device__ __forceinline__ void gload16(const void* g, void* l) {
    __builtin_amdgcn_global_load_lds(
        (const __attribute__((address_space(1))) void*)g,
        (__attribute__((address_space(3))) void*)l, 16, 0, 0);
}

// ---------- block reduce (blockDim.x == 256) ----------
__device__ __forceinline__ float blockReduceSum(float v, float* red) {
    int tid = threadIdx.x;
    red[tid] = v; __syncthreads();
    for (int s = 128; s > 0; s >>= 1) {
        if (tid < s) red[tid] += red[tid + s];
        __syncthreads();
    }
    float r = red[0]; __syncthreads();
    return r;
}

// ---------- f32 -> bf16 conversion (weights + X), 10 segments ----------
struct CvtArgs { const float* src[10]; short* dst[10]; int n4[10]; };
__global__ __launch_bounds__(256) void cvt_k(CvtArgs a) {
    int s = blockIdx.y;
    const float* sp = a.src[s]; short* dp = a.dst[s]; int n = a.n4[s];
    for (int i = blockIdx.x * 256 + threadIdx.x; i < n; i += gridDim.x * 256) {
        float4 v = ((const float4*)sp)[i];
        short4 o; o.x = f2bf(v.x); o.y = f2bf(v.y); o.z = f2bf(v.z); o.w = f2bf(v.w);
        ((short4*)dp)[i] = o;
    }
}

// ---------- shared epilogue writer ----------
template <int OUTMODE>
__device__ __forceinline__ void gemm_epilogue(int row, int col, int N, const f4v& a,
        float bv, float* Cf, short* Cb, short* Kb_, short* Vt_)
{
    if (OUTMODE == 3) {
        int b = row >> 11, n0 = row & 2047;
        if (col < 512) {
            int h = col >> 6, d = col & 63;
            size_t base = (((size_t)(b * 8 + h) * NSEQ + n0) << 6) + d;
            #pragma unroll
            for (int rr = 0; rr < 4; ++rr)
                Cb[base + ((size_t)rr << 6)] = f2bf((a[rr] + bv) * 0.18033688f);
        } else if (col < 1024) {
            int cc = col - 512, h = cc >> 6, d = cc & 63;
            size_t base = (((size_t)(b * 8 + h) * NSEQ + n0) << 6) + d;
            #pragma unroll
            for (int rr = 0; rr < 4; ++rr)
                Kb_[base + ((size_t)rr << 6)] = f2bf(a[rr] + bv);
        } else {
            int cc = col - 1024, h = cc >> 6, d = cc & 63;
            short4 ov;
            ov.x = f2bf(a[0] + bv); ov.y = f2bf(a[1] + bv);
            ov.z = f2bf(a[2] + bv); ov.w = f2bf(a[3] + bv);
            *(short4*)(Vt_ + (((size_t)((b * 8 + h) * 64 + d)) << 11) + n0) = ov;
        }
    } else {
        #pragma unroll
        for (int rr = 0; rr < 4; ++rr) {
            float v = a[rr] + bv;
            if (OUTMODE == 0) Cf[(size_t)(row + rr) * N + col] = v;
            else if (OUTMODE == 1) Cb[(size_t)(row + rr) * N + col] = f2bf(v);
            else if (OUTMODE == 2) {
                Cf[(size_t)(row + rr) * N + col] = v;
                Cb[(size_t)(row + rr) * N + col] = f2bf(v);
            } else if (OUTMODE == 4) {
                Cb[(size_t)(row + rr) * N + col] = f2bf(0.5f * v * (1.f + erff(v * 0.70710678118654752f)));
            } else if (OUTMODE == 5) {
                Cf[(size_t)(row + rr) * N + col] = tanhf(v);
            }
        }
    }
}

// ---------- MFMA GEMM 64x64 tile, dbuf prefetch, swizzled LDS ----------
template <int OUTMODE>
__global__ __launch_bounds__(256) void mfma_gemm(
        const short* __restrict__ A, const short* __restrict__ W,
        const float* __restrict__ bias, float* __restrict__ Cf, short* __restrict__ Cb,
        int M, int N, int K)
{
    __shared__ short As[2][64 * 64];
    __shared__ short Bs[2][64 * 64];
    int tid = threadIdx.x;
    int wv = tid >> 6, l = tid & 63;
    int g = l >> 4, c = l & 15;
    int wr = wv >> 1, wc = wv & 1;
    int bm = blockIdx.y * 64, bn = blockIdx.x * 64;
    int sr = l >> 3, sc = ((l & 7) ^ sr) * 8;
    const short* Ap = A + (size_t)(bm + wv * 16 + sr) * K + sc;
    const short* Wp = W + (size_t)(bn + wv * 16 + sr) * K + sc;
    int ldsB = (wv * 16) * 64;

    #define GSTAGE(buf, k0) { \
        gload16(Ap + (k0), &As[buf][ldsB]); \
        gload16(Ap + (size_t)8 * K + (k0), &As[buf][ldsB + 8 * 64]); \
        gload16(Wp + (k0), &Bs[buf][ldsB]); \
        gload16(Wp + (size_t)8 * K + (k0), &Bs[buf][ldsB + 8 * 64]); }

    f4v acc[2][2] = {};
    GSTAGE(0, 0);
    __syncthreads();
    int nk = K >> 6;
    for (int t = 0; t < nk; ++t) {
        int cur = t & 1;
        if (t + 1 < nk) GSTAGE(cur ^ 1, (t + 1) << 6);
        #pragma unroll
        for (int ks = 0; ks < 2; ++ks) {
            bh8 af[2], bf_[2];
            #pragma unroll
            for (int mi = 0; mi < 2; ++mi) {
                int row = wr * 32 + mi * 16 + c;
                af[mi] = *(const bh8*)(&As[cur][row * 64 + (((ks * 4 + g) ^ (c & 7)) * 8)]);
            }
            #pragma unroll
            for (int ni = 0; ni < 2; ++ni) {
                int row = wc * 32 + ni * 16 + c;
                bf_[ni] = *(const bh8*)(&Bs[cur][row * 64 + (((ks * 4 + g) ^ (c & 7)) * 8)]);
            }
            #pragma unroll
            for (int mi = 0; mi < 2; ++mi)
                #pragma unroll
                for (int ni = 0; ni < 2; ++ni)
                    acc[mi][ni] = __builtin_amdgcn_mfma_f32_16x16x32_bf16(af[mi], bf_[ni], acc[mi][ni], 0, 0, 0);
        }
        __syncthreads();
    }
    #undef GSTAGE
    short* Kb_ = (OUTMODE == 3) ? Cb + 2097152 : nullptr;
    short* Vt_ = (OUTMODE == 3) ? Cb + 4194304 : nullptr;
    #pragma unroll
    for (int mi = 0; mi < 2; ++mi) {
        int row = bm + wr * 32 + mi * 16 + g * 4;
        #pragma unroll
        for (int ni = 0; ni < 2; ++ni) {
            int col = bn + wc * 32 + ni * 16 + c;
            gemm_epilogue<OUTMODE>(row, col, N, acc[mi][ni], bias[col], Cf, Cb, Kb_, Vt_);
        }
    }
}

// ---------- gram for KNN distances, hi/lo split, 64x64 tiles, swizzled LDS ----------
__global__ __launch_bounds__(256) void mfma_gram(
        const short* __restrict__ Hi, const short* __restrict__ Lo,
        const float* __restrict__ SQ, float* __restrict__ D2)
{
    __shared__ short HiR[64 * 64], LoR[64 * 64], HiC[64 * 64], LoC[64 * 64];
    int tid = threadIdx.x;
    int wv = tid >> 6, l = tid & 63;
    int g = l >> 4, c = l & 15;
    int wr = wv >> 1, wc = wv & 1;
    int bm = blockIdx.y * 64, bn = blockIdx.x * 64;
    int sr = l >> 3, sc = ((l & 7) ^ sr) * 8;
    const short* hiR = Hi + (size_t)(bm + wv * 16 + sr) * 512 + sc;
    const short* loR = Lo + (size_t)(bm + wv * 16 + sr) * 512 + sc;
    const short* hiC = Hi + (size_t)(bn + wv * 16 + sr) * 512 + sc;
    const short* loC = Lo + (size_t)(bn + wv * 16 + sr) * 512 + sc;
    int ldsOff = (wv * 16) * 64;
    f4v acc[2][2] = {};
    for (int k0 = 0; k0 < 512; k0 += 64) {
        __syncthreads();
        gload16(hiR + k0, HiR + ldsOff);
        gload16(hiR + (size_t)8 * 512 + k0, HiR + ldsOff + 8 * 64);
        gload16(loR + k0, LoR + ldsOff);
        gload16(loR + (size_t)8 * 512 + k0, LoR + ldsOff + 8 * 64);
        gload16(hiC + k0, HiC + ldsOff);
        gload16(hiC + (size_t)8 * 512 + k0, HiC + ldsOff + 8 * 64);
        gload16(loC + k0, LoC + ldsOff);
        gload16(loC + (size_t)8 * 512 + k0, LoC + ldsOff + 8 * 64);
        __syncthreads();
        #pragma unroll
        for (int ks = 0; ks < 2; ++ks) {
            bh8 hr[2], lr_[2], hc[2], lc[2];
            #pragma unroll
            for (int mi = 0; mi < 2; ++mi) {
                int o = (wr * 32 + mi * 16 + c) * 64 + (((ks * 4 + g) ^ (c & 7)) * 8);
                hr[mi] = *(const bh8*)(HiR + o);
                lr_[mi] = *(const bh8*)(LoR + o);
            }
            #pragma unroll
            for (int ni = 0; ni < 2; ++ni) {
                int o = (wc * 32 + ni * 16 + c) * 64 + (((ks * 4 + g) ^ (c & 7)) * 8);
                hc[ni] = *(const bh8*)(HiC + o);
                lc[ni] = *(const bh8*)(LoC + o);
            }
            #pragma unroll
            for (int mi = 0; mi < 2; ++mi)
                #pragma unroll
                for (int ni = 0; ni < 2; ++ni) {
                    acc[mi][ni] = __builtin_amdgcn_mfma_f32_16x16x32_bf16(hr[mi], hc[ni], acc[mi][ni], 0, 0, 0);
                    acc[mi][ni] = __builtin_amdgcn_mfma_f32_16x16x32_bf16(hr[mi], lc[ni], acc[mi][ni], 0, 0, 0);
                    acc[mi][ni] = __builtin_amdgcn_mfma_f32_16x16x32_bf16(lr_[mi], hc[ni], acc[mi][ni], 0, 0, 0);
                }
        }
    }
    #pragma unroll
    for (int mi = 0; mi < 2; ++mi) {
        int row = bm + wr * 32 + mi * 16 + g * 4;
        #pragma unroll
        for (int ni = 0; ni < 2; ++ni) {
            int col = bn + wc * 32 + ni * 16 + c;
            float sqc = SQ[col];
            #pragma unroll
            for (int rr = 0; rr < 4; ++rr)
                D2[(size_t)(row + rr) * NSEQ + col] = SQ[row + rr] + sqc - 2.f * acc[mi][ni][rr];
        }
    }
}

// ---------- top-9 smallest per row: u64 keys, sort8 + LDS merge tree ----------
__global__ __launch_bounds__(256) void topk9_k(const float* __restrict__ D2, int* __restrict__ idx)
{
    int n = blockIdx.x, tid = threadIdx.x;
    __shared__ u64k lists[256][9];
    u64k a[8];
    union { float f; unsigned u; } cv;
    #pragma unroll
    for (int j = 0; j < 8; ++j) {
        int mcol = tid + j * 256;
        cv.f = fmaxf(D2[(size_t)n * NSEQ + mcol], 0.f);
        a[j] = ((u64k)cv.u << 32) | (unsigned)mcol;
    }
    #define CE(i,j) { u64k x = a[i], y = a[j]; bool t = x < y; a[i] = t ? x : y; a[j] = t ? y : x; }
    CE(0,1) CE(2,3) CE(4,5) CE(6,7)
    CE(0,2) CE(1,3) CE(4,6) CE(5,7)
    CE(1,2) CE(5,6)
    CE(0,4) CE(1,5) CE(2,6) CE(3,7)
    CE(2,4) CE(3,5)
    CE(1,2) CE(3,4) CE(5,6)
    #undef CE
    #pragma unroll
    for (int j = 0; j < 8; ++j) lists[tid][j] = a[j];
    lists[tid][8] = ~0ull;
    __syncthreads();
    for (int s = 128; s >= 1; s >>= 1) {
        if (tid < s) {
            u64k out[9];
            u64k* Al = lists[tid];
            u64k* Bl = lists[tid + s];
            int ia = 0, ib = 0;
            #pragma unroll
            for (int o = 0; o < 9; ++o) {
                u64k av = Al[ia], bv = Bl[ib];
                bool t = av <= bv;
                out[o] = t ? av : bv;
                ia += t; ib += !t;
            }
            #pragma unroll
            for (int o = 0; o < 9; ++o) Al[o] = out[o];
        }
        __syncthreads();
    }
    if (tid < 9) idx[n * KNN + tid] = (int)(lists[0][tid] & 0xffffffffu);
}

// ---------- GCN aggregate + LN + leaky + residual (writes f32 + bf16) ----------
__global__ __launch_bounds__(256) void gcn_post(
        const float* __restrict__ s, const int* __restrict__ idx,
        const float* __restrict__ g, const float* __restrict__ be,
        float* __restrict__ hg, short* __restrict__ hgb)
{
    int row = blockIdx.x, tid = threadIdx.x;
    int bb = row >> 11;
    __shared__ float os[512];
    __shared__ float red[256];
    int id[KNN];
    #pragma unroll
    for (int j = 0; j < KNN; ++j) id[j] = idx[row * KNN + j] + (bb << 11);
    for (int c = tid; c < 512; c += 256) {
        float acc = 0.f;
        #pragma unroll
        for (int j = 0; j < KNN; ++j) acc += s[((size_t)id[j] << 9) + c];
        os[c] = acc * (1.f / 9.f);
    }
    __syncthreads();
    float mean = blockReduceSum(os[tid] + os[tid + 256], red) * (1.f / 512.f);
    float d0 = os[tid] - mean, d1 = os[tid + 256] - mean;
    float var = blockReduceSum(d0 * d0 + d1 * d1, red) * (1.f / 512.f);
    float rs = rsqrtf(var + 1e-5f);
    size_t base = (size_t)row << 9;
    for (int c = tid; c < 512; c += 256) {
        float y = (os[c] - mean) * rs * g[c] + be[c];
        y = y > 0.f ? y : 0.2f * y;
        float nv = y + hg[base + c];
        hg[base + c] = nv;
        hgb[base + c] = f2bf(nv);
    }
}

// ---------- x = LN(x + r)*g + b (writes f32 + bf16) ----------
__global__ __launch_bounds__(256) void ln_res(
        float* __restrict__ x, const float* __restrict__ r,
        const float* __restrict__ g, const float* __restrict__ b, short* __restrict__ xb)
{
    int row = blockIdx.x, tid = threadIdx.x;
    __shared__ float xs[512];
    __shared__ float red[256];
    size_t base = (size_t)row << 9;
    for (int c = tid; c < 512; c += 256) xs[c] = x[base + c] + r[base + c];
    __syncthreads();
    float mean = blockReduceSum(xs[tid] + xs[tid + 256], red) * (1.f / 512.f);
    float d0 = xs[tid] - mean, d1 = xs[tid + 256] - mean;
    float var = blockReduceSum(d0 * d0 + d1 * d1, red) * (1.f / 512.f);
    float rs = rsqrtf(var + 1e-5f);
    for (int c = tid; c < 512; c += 256) {
        float y = (xs[c] - mean) * rs * g[c] + b[c];
        x[base + c] = y;
        xb[base + c] = f2bf(y);
    }
}

// ---------- flash attention: swapped-operand, KV-split=4, K+V LDS dbuf ----------
__global__ __launch_bounds__(256) void flash_attn(
        const short* __restrict__ Qb, const short* __restrict__ Kb,
        const short* __restrict__ Vt, short* __restrict__ Opb, float* __restrict__ Ml)
{
    __shared__ short Ks[2][4096];
    __shared__ short Vs[2][4096];
    int tid = threadIdx.x;
    int wid = tid >> 6, lane = tid & 63;
    int g = lane >> 4, c = lane & 15;
    int s = blockIdx.y, bh = blockIdx.z;
    int q0 = blockIdx.x * 64 + wid * 16;
    int srow = lane >> 3;
    int sc8 = ((lane & 7) ^ srow) * 8;
    int w8 = wid * 8;

    const short* KbB = Kb + ((size_t)bh * NSEQ + s * 512) * 64;
    const short* VtB = Vt + (size_t)bh * 64 * NSEQ + s * 512;

    const short* qbase = Qb + ((size_t)bh * NSEQ + q0 + c) * 64 + g * 8;
    bh8 qa0 = *(const bh8*)(qbase);
    bh8 qa1 = *(const bh8*)(qbase + 32);

    f4v o0 = {0,0,0,0}, o1 = {0,0,0,0}, o2 = {0,0,0,0}, o3 = {0,0,0,0};
    float lloc = 0.f;
    float mrun = -INFINITY;
    int hi2 = g >> 1;
    int s1 = c + (((g << 1) & 3) << 4);
    int s2 = c + ((((g << 1) + 1) & 3) << 4);

    #define FSTAGE(buf, kt) { \
        const short* kp_ = KbB + (size_t)(kt) * 64 * 64; \
        gload16(kp_ + (size_t)(w8 + srow) * 64 + sc8,        &Ks[buf][w8 * 64]); \
        gload16(kp_ + (size_t)(32 + w8 + srow) * 64 + sc8,   &Ks[buf][(32 + w8) * 64]); \
        const short* vp_ = VtB + (size_t)(kt) * 64; \
        gload16(vp_ + (size_t)(w8 + srow) * NSEQ + sc8,      &Vs[buf][w8 * 64]); \
        gload16(vp_ + (size_t)(32 + w8 + srow) * NSEQ + sc8, &Vs[buf][(32 + w8) * 64]); }

    FSTAGE(0, 0);
    __syncthreads();
    for (int t = 0; t < 8; ++t) {
        int cur = t & 1;
        if (t < 7) FSTAGE(cur ^ 1, t + 1);
        f4v sv[4];
        #pragma unroll
        for (int cb = 0; cb < 4; ++cb) {
            int row = cb * 16 + c;
            const short* kr = &Ks[cur][row * 64];
            bh8 kb0 = *(const bh8*)(kr + ((g ^ (row & 7)) * 8));
            bh8 kb1 = *(const bh8*)(kr + (((4 + g) ^ (row & 7)) * 8));
            f4v a = {0,0,0,0};
            a = __builtin_amdgcn_mfma_f32_16x16x32_bf16(kb0, qa0, a, 0, 0, 0);
            a = __builtin_amdgcn_mfma_f32_16x16x32_bf16(kb1, qa1, a, 0, 0, 0);
            sv[cb] = a;
        }
        float mt = fmaxf(fmaxf(fmaxf(sv[0][0], sv[0][1]), fmaxf(sv[0][2], sv[0][3])),
                         fmaxf(fmaxf(sv[1][0], sv[1][1]), fmaxf(sv[1][2], sv[1][3])));
        mt = fmaxf(mt, fmaxf(fmaxf(sv[2][0], sv[2][1]), fmaxf(sv[2][2], sv[2][3])));
        mt = fmaxf(mt, fmaxf(fmaxf(sv[3][0], sv[3][1]), fmaxf(sv[3][2], sv[3][3])));
        mt = fmaxf(mt, __shfl_xor(mt, 16));
        mt = fmaxf(mt, __shfl_xor(mt, 32));
        if (__any(mt > mrun + 6.f)) {
            float mn = fmaxf(mrun, mt);
            float al = __builtin_amdgcn_exp2f(mrun - mn);
            mrun = mn;
            o0 *= al; o1 *= al; o2 *= al; o3 *= al; lloc *= al;
        }
        unsigned wv_[8];
        #pragma unroll
        for (int cb = 0; cb < 4; ++cb) {
            float p0 = __builtin_amdgcn_exp2f(sv[cb][0] - mrun);
            float p1 = __builtin_amdgcn_exp2f(sv[cb][1] - mrun);
            float p2 = __builtin_amdgcn_exp2f(sv[cb][2] - mrun);
            float p3 = __builtin_amdgcn_exp2f(sv[cb][3] - mrun);
            lloc += (p0 + p1) + (p2 + p3);
            asm("v_cvt_pk_bf16_f32 %0, %1, %2" : "=v"(wv_[cb * 2])     : "v"(p0), "v"(p1));
            asm("v_cvt_pk_bf16_f32 %0, %1, %2" : "=v"(wv_[cb * 2 + 1]) : "v"(p2), "v"(p3));
        }
        union { unsigned u[4]; bh8 h; } pa0u, pa1u;
        {
            unsigned t0 = __shfl((int)wv_[0], s1), t2 = __shfl((int)wv_[2], s1);
            unsigned t1 = __shfl((int)wv_[1], s1), t3 = __shfl((int)wv_[3], s1);
            unsigned u0 = __shfl((int)wv_[0], s2), u2 = __shfl((int)wv_[2], s2);
            unsigned u1 = __shfl((int)wv_[1], s2), u3 = __shfl((int)wv_[3], s2);
            pa0u.u[0] = hi2 ? t2 : t0;
            pa0u.u[1] = hi2 ? t3 : t1;
            pa0u.u[2] = hi2 ? u2 : u0;
            pa0u.u[3] = hi2 ? u3 : u1;
        }
        {
            unsigned t0 = __shfl((int)wv_[4], s1), t2 = __shfl((int)wv_[6], s1);
            unsigned t1 = __shfl((int)wv_[5], s1), t3 = __shfl((int)wv_[7], s1);
            unsigned u0 = __shfl((int)wv_[4], s2), u2 = __shfl((int)wv_[6], s2);
            unsigned u1 = __shfl((int)wv_[5], s2), u3 = __shfl((int)wv_[7], s2);
            pa1u.u[0] = hi2 ? t2 : t0;
            pa1u.u[1] = hi2 ? t3 : t1;
            pa1u.u[2] = hi2 ? u2 : u0;
            pa1u.u[3] = hi2 ? u3 : u1;
        }
        #pragma unroll
        for (int db = 0; db < 4; ++db) {
            int row = db * 16 + c;
            const short* vr = &Vs[cur][row * 64];
            bh8 vb0 = *(const bh8*)(vr + ((g ^ (row & 7)) * 8));
            bh8 vb1 = *(const bh8*)(vr + (((4 + g) ^ (row & 7)) * 8));
            f4v* op = (db == 0) ? &o0 : (db == 1) ? &o1 : (db == 2) ? &o2 : &o3;
            *op = __builtin_amdgcn_mfma_f32_16x16x32_bf16(vb0, pa0u.h, *op, 0, 0, 0);
            *op = __builtin_amdgcn_mfma_f32_16x16x32_bf16(vb1, pa1u.h, *op, 0, 0, 0);
        }
        __syncthreads();
    }
    #undef FSTAGE
    float lsum = lloc;
    lsum += __shfl_xor(lsum, 16);
    lsum += __shfl_xor(lsum, 32);
    size_t qrow = ((size_t)(s * 16 + bh) * NSEQ) + q0 + c;
    size_t rb = qrow * 64 + g * 4;
    #pragma unroll
    for (int r = 0; r < 4; ++r) {
        Opb[rb + r]      = f2bf(o0[r]);
        Opb[rb + 16 + r] = f2bf(o1[r]);
        Opb[rb + 32 + r] = f2bf(o2[r]);
        Opb[rb + 48 + r] = f2bf(o3[r]);
    }
    if (g == 0) {
        Ml[qrow * 2]     = mrun;
        Ml[qrow * 2 + 1] = lsum;
    }
}

// ---------- merge 4 KV-splits -> bf16 attention output ----------
__global__ __launch_bounds__(256) void merge_k(const short* __restrict__ Opb, const float* __restrict__ Ml,
                                               short* __restrict__ aob)
{
    int idx = blockIdx.x * 256 + threadIdx.x;   // 16*2048*64
    int d = idx & 63, q = (idx >> 6) & 2047, bh = idx >> 17;
    float M = -INFINITY;
    float mv[4], lv[4];
    #pragma unroll
    for (int s = 0; s < 4; ++s) {
        size_t r = (size_t)(s * 16 + bh) * NSEQ + q;
        mv[s] = Ml[r * 2]; lv[s] = Ml[r * 2 + 1];
        M = fmaxf(M, mv[s]);
    }
    float L = 0.f, num = 0.f;
    #pragma unroll
    for (int s = 0; s < 4; ++s) {
        float w = __builtin_amdgcn_exp2f(mv[s] - M);
        L += lv[s] * w;
        num += b2f(Opb[((size_t)(s * 16 + bh) * NSEQ + q) * 64 + d]) * w;
    }
    int b = bh >> 3, h = bh & 7;
    aob[((size_t)(b * NSEQ + q)) * 512 + h * 64 + d] = f2bf(num / L);
}

// ---------- GLU per-row: h, copies, hi/lo split, fused row-sq ----------
__global__ __launch_bounds__(256) void glu_row_k(const float* __restrict__ vg, float* __restrict__ h,
        float* __restrict__ hgf, short* __restrict__ hi, short* __restrict__ lo,
        float* __restrict__ sq) {
    int row = blockIdx.x, tid = threadIdx.x;
    __shared__ float red[256];
    size_t vb = (size_t)row << 10;
    size_t hb = (size_t)row << 9;
    float ss = 0.f;
    #pragma unroll
    for (int j = 0; j < 2; ++j) {
        int c = tid + j * 256;
        float v = vg[vb + c], gt = vg[vb + 512 + c];
        float hv = v * (1.f / (1.f + __expf(-gt)));
        h[hb + c] = hv; hgf[hb + c] = hv;
        short hbb = f2bf(hv);
        hi[hb + c] = hbb;
        lo[hb + c] = f2bf(hv - b2f(hbb));
        ss = fmaf(hv, hv, ss);
    }
    float sm = blockReduceSum(ss, red);
    if (tid == 0) sq[row] = sm;
}

__global__ void concat_bf(const short* __restrict__ hgb, const short* __restrict__ htb,
                          short* __restrict__ cat) {
    for (int i = blockIdx.x * 256 + threadIdx.x; i < ROWS * 256; i += gridDim.x * 256) {
        int row = i >> 8, c4 = (i & 255) * 4;
        short4 v = (c4 < 512) ? *(const short4*)(hgb + ((size_t)row << 9) + c4)
                              : *(const short4*)(htb + ((size_t)row << 9) + c4 - 512);
        *(short4*)(cat + ((size_t)row << 10) + c4) = v;
    }
}

// ---------- pooling / classifier ----------
__global__ __launch_bounds__(256) void rowdot_k(const float* __restrict__ t, const float* __restrict__ w2,
                                                const float* __restrict__ b2, float* __restrict__ srow) {
    int row = blockIdx.x, tid = threadIdx.x;
    __shared__ float red[256];
    float s = blockReduceSum(t[(size_t)row * 256 + tid] * w2[tid], red);
    if (tid == 0) srow[row] = s + b2[0];
}
__global__ __launch_bounds__(256) void softmax_n_k(const float* __restrict__ srow, float* __restrict__ a,
                                                   float* __restrict__ out) {
    int b = blockIdx.x, tid = threadIdx.x;
    __shared__ float red[256];
    float mx = -INFINITY;
    for (int n = tid; n < NSEQ; n += 256) mx = fmaxf(mx, srow[b * NSEQ + n]);
    red[tid] = mx; __syncthreads();
    for (int s = 128; s > 0; s >>= 1) {
        if (tid < s) red[tid] = fmaxf(red[tid], red[tid + s]);
        __syncthreads();
    }
    mx = red[0]; __syncthreads();
    float sm = 0.f;
    for (int n = tid; n < NSEQ; n += 256) {
        float e = expf(srow[b * NSEQ + n] - mx);
        a[b * NSEQ + n] = e; sm += e;
    }
    float inv = 1.f / blockReduceSum(sm, red);
    for (int n = tid; n < NSEQ; n += 256) {
        float v = a[b * NSEQ + n] * inv;
        a[b * NSEQ + n] = v;
        out[2 + b * NSEQ + n] = v;
    }
}
__global__ __launch_bounds__(256) void pool_part(const float* __restrict__ hf, const float* __restrict__ a,
                                                 float* __restrict__ part) {
    int b = blockIdx.y, chunk = blockIdx.x, tid = threadIdx.x;
    float a0 = 0.f, a1 = 0.f;
    for (int r = 0; r < 64; ++r) {
        int n = chunk * 64 + r;
        float wgt = a[b * NSEQ + n];
        const float* row = hf + ((size_t)(b * NSEQ + n) << 9);
        a0 = fmaf(row[tid], wgt, a0);
        a1 = fmaf(row[tid + 256], wgt, a1);
    }
    part[((b * 32 + chunk) << 9) + tid] = a0;
    part[((b * 32 + chunk) << 9) + tid + 256] = a1;
}
__global__ __launch_bounds__(256) void pool_fin(const float* __restrict__ part, float* __restrict__ Mb,
                                                float* __restrict__ out) {
    int b = blockIdx.x, tid = threadIdx.x;
    float s0 = 0.f, s1 = 0.f;
    for (int ch = 0; ch < 32; ++ch) {
        s0 += part[((b * 32 + ch) << 9) + tid];
        s1 += part[((b * 32 + ch) << 9) + tid + 256];
    }
    Mb[b * 512 + tid] = s0; Mb[b * 512 + tid + 256] = s1;
    out[2 + ROWS + b * 512 + tid] = s0; out[2 + ROWS + b * 512 + tid + 256] = s1;
}
__global__ __launch_bounds__(256) void classifier_k(const float* __restrict__ Mb,
        const float* __restrict__ w1, const float* __restrict__ b1,
        const float* __restrict__ w2, const float* __restrict__ b2, float* __restrict__ out) {
    int b = blockIdx.x, tid = threadIdx.x;
    __shared__ float Ms[512];
    __shared__ float red[256];
    for (int c = tid; c < 512; c += 256) Ms[c] = Mb[b * 512 + c];
    __syncthreads();
    float acc = 0.f;
    for (int c = 0; c < 512; ++c) acc = fmaf(Ms[c], w1[tid * 512 + c], acc);
    acc += b1[tid];
    float hj = acc > 0.f ? acc : expm1f(acc);   // ELU alpha=1
    float s = blockReduceSum(hj * w2[tid], red);
    if (tid == 0) out[b] = s + b2[0];
}

extern "C" void kernel_launch(void* const* d_in, const int* in_sizes, int n_in,
                              void* d_out, int out_size, void* d_ws, size_t ws_size,
                              hipStream_t stream)
{
    const float* X      = (const float*)d_in[0];
    const float* Wstart = (const float*)d_in[1];
    const float* Bstart = (const float*)d_in[2];
    const float* GluW   = (const float*)d_in[3];
    const float* GluB   = (const float*)d_in[4];
    const float* GcnW   = (const float*)d_in[5];
    const float* GcnB   = (const float*)d_in[6];
    const float* GcnG   = (const float*)d_in[7];
    const float* GcnBe  = (const float*)d_in[8];
    const float* QkvW   = (const float*)d_in[9];
    const float* QkvB   = (const float*)d_in[10];
    const float* OutW   = (const float*)d_in[11];
    const float* OutB   = (const float*)d_in[12];
    const float* Ln1G   = (const float*)d_in[13];
    const float* Ln1B   = (const float*)d_in[14];
    const float* Ffn1W  = (const float*)d_in[15];
    const float* Ffn1B  = (const float*)d_in[16];
    const float* Ffn2W  = (const float*)d_in[17];
    const float* Ffn2B  = (const float*)d_in[18];
    const float* Ln2G   = (const float*)d_in[19];
    const float* Ln2B   = (const float*)d_in[20];
    const float* FusW   = (const float*)d_in[21];
    const float* FusB   = (const float*)d_in[22];
    const float* AW1    = (const float*)d_in[23];
    const float* AB1    = (const float*)d_in[24];
    const float* AW2    = (const float*)d_in[25];
    const float* AB2    = (const float*)d_in[26];
    const float* CW1    = (const float*)d_in[27];
    const float* CB1    = (const float*)d_in[28];
    const float* CW2    = (const float*)d_in[29];
    const float* CB2    = (const float*)d_in[30];
    float* out = (float*)d_out;

    if (ws_size < 86 * MB) return;

    char* w = (char*)d_ws;
    // bf16 weight arena [0,13MB)
    short* Wb = (short*)w;
    short* wbStart = Wb;
    short* wbGlu   = Wb + 524288;
    short* wbGcn   = Wb + 1048576;
    short* wbQkv   = Wb + 1572864;
    short* wbOut   = Wb + 3145728;
    short* wbFfn1  = Wb + 3670016;
    short* wbFfn2  = Wb + 4718592;
    short* wbFus   = Wb + 5767168;
    short* wbAw1   = Wb + 6291456;
    // small [13MB,14MB)
    float* sq   = (float*)(w + 13 * MB);
    int*   idx  = (int*)  (w + 13 * MB + (16u << 10));
    float* srow = (float*)(w + 13 * MB + (176u << 10));
    float* afb  = (float*)(w + 13 * MB + (192u << 10));
    float* Mbuf = (float*)(w + 13 * MB + (208u << 10));
    float* part = (float*)(w + 13 * MB + (212u << 10));
    // overlapped big buffers
    short* Xbf  = (short*)(w + 14 * MB);   // 8MB -> hg after fc_start
    float* hg   = (float*)(w + 14 * MB);
    short* hpreb= (short*)(w + 22 * MB);   // 4MB -> hgb after GLU gemm
    short* hgb  = (short*)(w + 22 * MB);
    float* big  = (float*)(w + 26 * MB);   // 26..42MB: vg/D2/gcn-s/Opb/out-proj
    short* Opb  = (short*)(w + 26 * MB);   // 16MB: 4 splits (bf16 O-partials)
    float* Ml   = (float*)(w + 42 * MB);   // 1MB (dead ffn2o window during attn)
    float* ffn2o= (float*)(w + 42 * MB);   // 8MB
    float* h    = (float*)(w + 50 * MB);   // 8MB; doubles as ht residual
    short* hhi  = (short*)(w + 58 * MB);   // 4MB; -> hf low half after loop
    short* hlo  = (short*)(w + 62 * MB);   // 4MB; dead after gram -> htb
    short* htb  = (short*)(w + 62 * MB);   // 4MB
    float* hf   = (float*)(w + 58 * MB);   // 8MB (after transformer loop)
    short* hfb  = (short*)(w + 66 * MB);   // 4MB
    short* aob  = (short*)(w + 70 * MB);   // 4MB; -> t256 (pool)
    float* t256 = (float*)(w + 70 * MB);
    short* Qb   = (short*)(w + 74 * MB);   // 4MB  (OUTMODE=3: K=Qb+4MB, Vt=Qb+8MB)
    short* Kb   = (short*)(w + 78 * MB);   // 4MB
    short* Vt   = (short*)(w + 82 * MB);   // 4MB (transposed V, written by qkv GEMM)
    short* ffb  = (short*)(w + 74 * MB);   // 8MB (ffn1 out; Qb/Kb dead) -> catb
    short* catb = (short*)(w + 74 * MB);

    dim3 blk(256);

    // convert X + all GEMM weights to bf16
    CvtArgs ca;
    ca.src[0] = X;     ca.dst[0] = Xbf;     ca.n4[0] = ROWS * 1024 / 4;
    ca.src[1] = Wstart;ca.dst[1] = wbStart; ca.n4[1] = 524288 / 4;
    ca.src[2] = GluW;  ca.dst[2] = wbGlu;   ca.n4[2] = 524288 / 4;
    ca.src[3] = GcnW;  ca.dst[3] = wbGcn;   ca.n4[3] = 524288 / 4;
    ca.src[4] = QkvW;  ca.dst[4] = wbQkv;   ca.n4[4] = 1572864 / 4;
    ca.src[5] = OutW;  ca.dst[5] = wbOut;   ca.n4[5] = 524288 / 4;
    ca.src[6] = Ffn1W; ca.dst[6] = wbFfn1;  ca.n4[6] = 1048576 / 4;
    ca.src[7] = Ffn2W; ca.dst[7] = wbFfn2;  ca.n4[7] = 1048576 / 4;
    ca.src[8] = FusW;  ca.dst[8] = wbFus;   ca.n4[8] = 524288 / 4;
    ca.src[9] = AW1;   ca.dst[9] = wbAw1;   ca.n4[9] = 131072 / 4;
    cvt_k<<<dim3(256, 10), blk, 0, stream>>>(ca);

    // fc_start -> GLU (fused rowsq)
    mfma_gemm<1><<<dim3(8, 64), blk, 0, stream>>>(Xbf, wbStart, Bstart, nullptr, hpreb, ROWS, 512, 1024);
    mfma_gemm<0><<<dim3(16, 64), blk, 0, stream>>>(hpreb, wbGlu, GluB, big, nullptr, ROWS, 1024, 512);
    glu_row_k<<<dim3(ROWS), blk, 0, stream>>>(big, h, hg, hhi, hlo, sq);

    // KNN graph (hi/lo split gram, f32-equivalent ranking)
    for (int b = 0; b < 2; ++b) {
        mfma_gram<<<dim3(32, 32), blk, 0, stream>>>(hhi + (size_t)b * NSEQ * 512,
                                                    hlo + (size_t)b * NSEQ * 512,
                                                    sq + b * NSEQ, big);
        topk9_k<<<dim3(NSEQ), blk, 0, stream>>>(big, idx + b * NSEQ * KNN);
    }

    // GCN branch
    const short* gA = hhi;
    for (int i = 0; i < 2; ++i) {
        mfma_gemm<0><<<dim3(8, 64), blk, 0, stream>>>(gA, wbGcn + (size_t)i * 262144,
                                                      GcnB + i * 512, big, nullptr, ROWS, 512, 512);
        gcn_post<<<dim3(ROWS), blk, 0, stream>>>(big, idx, GcnG + i * 512, GcnBe + i * 512, hg, hgb);
        gA = hgb;
    }

    // Transformer branch (h doubles as ht residual)
    const short* tA = hhi;
    for (int i = 0; i < 2; ++i) {
        mfma_gemm<3><<<dim3(24, 64), blk, 0, stream>>>(tA, wbQkv + (size_t)i * 786432,
                                                       QkvB + i * 1536, nullptr, Qb, ROWS, 1536, 512);
        flash_attn<<<dim3(32, 4, 16), blk, 0, stream>>>(Qb, Kb, Vt, Opb, Ml);
        merge_k<<<dim3(8192), blk, 0, stream>>>(Opb, Ml, aob);
        mfma_gemm<0><<<dim3(8, 64), blk, 0, stream>>>(aob, wbOut + (size_t)i * 262144,
                                                      OutB + i * 512, big, nullptr, ROWS, 512, 512);
        ln_res<<<dim3(ROWS), blk, 0, stream>>>(h, big, Ln1G + i * 512, Ln1B + i * 512, htb);
        mfma_gemm<4><<<dim3(16, 64), blk, 0, stream>>>(htb, wbFfn1 + (size_t)i * 524288,
                                                       Ffn1B + i * 1024, nullptr, ffb, ROWS, 1024, 512);
        mfma_gemm<0><<<dim3(8, 64), blk, 0, stream>>>(ffb, wbFfn2 + (size_t)i * 524288,
                                                      Ffn2B + i * 512, ffn2o, nullptr, ROWS, 512, 1024);
        ln_res<<<dim3(ROWS), blk, 0, stream>>>(h, ffn2o, Ln2G + i * 512, Ln2B + i * 512, htb);
        tA = htb;
    }

    // fusion
    concat_bf<<<dim3(2048), blk, 0, stream>>>(hgb, htb, catb);
    mfma_gemm<2><<<dim3(8, 64), blk, 0, stream>>>(catb, wbFus, FusB, hf, hfb, ROWS, 512, 1024);

    // gated attention pooling (tanh fused into GEMM)
    mfma_gemm<5><<<dim3(4, 64), blk, 0, stream>>>(hfb, wbAw1, AB1, t256, nullptr, ROWS, 256, 512);
    rowdot_k<<<dim3(ROWS), blk, 0, stream>>>(t256, AW2, AB2, srow);
    softmax_n_k<<<dim3(2), blk, 0, stream>>>(srow, afb, out);
    pool_part<<<dim3(32, 2), blk, 0, stream>>>(hf, afb, part);
    pool_fin<<<dim3(2), blk, 0, stream>>>(part, Mbuf, out);

    // classifier
    classifier_k<<<dim3(2), blk, 0, stream>>>(Mbuf, CW1, CB1, CW2, CB2, out);
}

// Round 13
// 425.815 us; speedup vs baseline: 1.1863x; 1.0247x over previous
//
#include <hip/hip_runtime.h>
#include <hip/hip_bf16.h>
#include <math.h>

#define NSEQ 2048
#define ROWS 4096   // B*N
#define KNN 9
#define MB (1ull << 20)

typedef short bh8 __attribute__((ext_vector_type(8)));   // 8 bf16 in 4 VGPRs
typedef float f4v __attribute__((ext_vector_type(4)));
typedef unsigned long long u64k;

__device__ __forceinline__ short f2bf(float f) {
    union { float f; unsigned u; } v; v.f = f;
    unsigned r = (v.u + 0x7fffu + ((v.u >> 16) & 1u)) >> 16;
    return (short)r;
}
__device__ __forceinline__ float b2f(short s) {
    union { unsigned u; float f; } v; v.u = ((unsigned)(unsigned short)s) << 16; return v.f;
}

// async global->LDS, 16B per lane; LDS dest is wave-uniform base + lane*16
__device__ __forceinline__ void gload16(const void* g, void* l) {
    __builtin_amdgcn_global_load_lds(
        (const __attribute__((address_space(1))) void*)g,
        (__attribute__((address_space(3))) void*)l, 16, 0, 0);
}

// ---------- block reduce (blockDim.x == 256) ----------
__device__ __forceinline__ float blockReduceSum(float v, float* red) {
    int tid = threadIdx.x;
    red[tid] = v; __syncthreads();
    for (int s = 128; s > 0; s >>= 1) {
        if (tid < s) red[tid] += red[tid + s];
        __syncthreads();
    }
    float r = red[0]; __syncthreads();
    return r;
}

// ---------- f32 -> bf16 conversion (weights + X), 10 segments ----------
struct CvtArgs { const float* src[10]; short* dst[10]; int n4[10]; };
__global__ __launch_bounds__(256) void cvt_k(CvtArgs a) {
    int s = blockIdx.y;
    const float* sp = a.src[s]; short* dp = a.dst[s]; int n = a.n4[s];
    for (int i = blockIdx.x * 256 + threadIdx.x; i < n; i += gridDim.x * 256) {
        float4 v = ((const float4*)sp)[i];
        short4 o; o.x = f2bf(v.x); o.y = f2bf(v.y); o.z = f2bf(v.z); o.w = f2bf(v.w);
        ((short4*)dp)[i] = o;
    }
}

// ---------- shared epilogue writer ----------
template <int OUTMODE>
__device__ __forceinline__ void gemm_epilogue(int row, int col, int N, const f4v& a,
        float bv, float* Cf, short* Cb, short* Kb_, short* Vt_)
{
    if (OUTMODE == 3) {
        int b = row >> 11, n0 = row & 2047;
        if (col < 512) {
            int h = col >> 6, d = col & 63;
            size_t base = (((size_t)(b * 8 + h) * NSEQ + n0) << 6) + d;
            #pragma unroll
            for (int rr = 0; rr < 4; ++rr)
                Cb[base + ((size_t)rr << 6)] = f2bf((a[rr] + bv) * 0.18033688f);
        } else if (col < 1024) {
            int cc = col - 512, h = cc >> 6, d = cc & 63;
            size_t base = (((size_t)(b * 8 + h) * NSEQ + n0) << 6) + d;
            #pragma unroll
            for (int rr = 0; rr < 4; ++rr)
                Kb_[base + ((size_t)rr << 6)] = f2bf(a[rr] + bv);
        } else {
            int cc = col - 1024, h = cc >> 6, d = cc & 63;
            short4 ov;
            ov.x = f2bf(a[0] + bv); ov.y = f2bf(a[1] + bv);
            ov.z = f2bf(a[2] + bv); ov.w = f2bf(a[3] + bv);
            *(short4*)(Vt_ + (((size_t)((b * 8 + h) * 64 + d)) << 11) + n0) = ov;
        }
    } else {
        #pragma unroll
        for (int rr = 0; rr < 4; ++rr) {
            float v = a[rr] + bv;
            if (OUTMODE == 0) Cf[(size_t)(row + rr) * N + col] = v;
            else if (OUTMODE == 1) Cb[(size_t)(row + rr) * N + col] = f2bf(v);
            else if (OUTMODE == 2) {
                Cf[(size_t)(row + rr) * N + col] = v;
                Cb[(size_t)(row + rr) * N + col] = f2bf(v);
            } else if (OUTMODE == 4) {
                Cb[(size_t)(row + rr) * N + col] = f2bf(0.5f * v * (1.f + erff(v * 0.70710678118654752f)));
            } else if (OUTMODE == 5) {
                Cf[(size_t)(row + rr) * N + col] = tanhf(v);
            }
        }
    }
}

// ---------- MFMA GEMM 64x64 tile, dbuf prefetch, swizzled LDS ----------
template <int OUTMODE>
__global__ __launch_bounds__(256) void mfma_gemm(
        const short* __restrict__ A, const short* __restrict__ W,
        const float* __restrict__ bias, float* __restrict__ Cf, short* __restrict__ Cb,
        int M, int N, int K)
{
    __shared__ short As[2][64 * 64];
    __shared__ short Bs[2][64 * 64];
    int tid = threadIdx.x;
    int wv = tid >> 6, l = tid & 63;
    int g = l >> 4, c = l & 15;
    int wr = wv >> 1, wc = wv & 1;
    int bm = blockIdx.y * 64, bn = blockIdx.x * 64;
    int sr = l >> 3, sc = ((l & 7) ^ sr) * 8;
    const short* Ap = A + (size_t)(bm + wv * 16 + sr) * K + sc;
    const short* Wp = W + (size_t)(bn + wv * 16 + sr) * K + sc;
    int ldsB = (wv * 16) * 64;

    #define GSTAGE(buf, k0) { \
        gload16(Ap + (k0), &As[buf][ldsB]); \
        gload16(Ap + (size_t)8 * K + (k0), &As[buf][ldsB + 8 * 64]); \
        gload16(Wp + (k0), &Bs[buf][ldsB]); \
        gload16(Wp + (size_t)8 * K + (k0), &Bs[buf][ldsB + 8 * 64]); }

    f4v acc[2][2] = {};
    GSTAGE(0, 0);
    __syncthreads();
    int nk = K >> 6;
    for (int t = 0; t < nk; ++t) {
        int cur = t & 1;
        if (t + 1 < nk) GSTAGE(cur ^ 1, (t + 1) << 6);
        #pragma unroll
        for (int ks = 0; ks < 2; ++ks) {
            bh8 af[2], bf_[2];
            #pragma unroll
            for (int mi = 0; mi < 2; ++mi) {
                int row = wr * 32 + mi * 16 + c;
                af[mi] = *(const bh8*)(&As[cur][row * 64 + (((ks * 4 + g) ^ (c & 7)) * 8)]);
            }
            #pragma unroll
            for (int ni = 0; ni < 2; ++ni) {
                int row = wc * 32 + ni * 16 + c;
                bf_[ni] = *(const bh8*)(&Bs[cur][row * 64 + (((ks * 4 + g) ^ (c & 7)) * 8)]);
            }
            #pragma unroll
            for (int mi = 0; mi < 2; ++mi)
                #pragma unroll
                for (int ni = 0; ni < 2; ++ni)
                    acc[mi][ni] = __builtin_amdgcn_mfma_f32_16x16x32_bf16(af[mi], bf_[ni], acc[mi][ni], 0, 0, 0);
        }
        __syncthreads();
    }
    #undef GSTAGE
    short* Kb_ = (OUTMODE == 3) ? Cb + 2097152 : nullptr;
    short* Vt_ = (OUTMODE == 3) ? Cb + 4194304 : nullptr;
    #pragma unroll
    for (int mi = 0; mi < 2; ++mi) {
        int row = bm + wr * 32 + mi * 16 + g * 4;
        #pragma unroll
        for (int ni = 0; ni < 2; ++ni) {
            int col = bn + wc * 32 + ni * 16 + c;
            gemm_epilogue<OUTMODE>(row, col, N, acc[mi][ni], bias[col], Cf, Cb, Kb_, Vt_);
        }
    }
}

// ---------- gram for KNN distances, hi/lo split, batched over z (2 batches) ----------
__global__ __launch_bounds__(256) void mfma_gram(
        const short* __restrict__ Hi0, const short* __restrict__ Lo0,
        const float* __restrict__ SQ0, float* __restrict__ D2a, float* __restrict__ D2b)
{
    __shared__ short HiR[64 * 64], LoR[64 * 64], HiC[64 * 64], LoC[64 * 64];
    int tid = threadIdx.x;
    int bz = blockIdx.z;
    const short* Hi = Hi0 + (size_t)bz * NSEQ * 512;
    const short* Lo = Lo0 + (size_t)bz * NSEQ * 512;
    const float* SQ = SQ0 + bz * NSEQ;
    float* D2 = bz ? D2b : D2a;
    int wv = tid >> 6, l = tid & 63;
    int g = l >> 4, c = l & 15;
    int wr = wv >> 1, wc = wv & 1;
    int bm = blockIdx.y * 64, bn = blockIdx.x * 64;
    int sr = l >> 3, sc = ((l & 7) ^ sr) * 8;
    const short* hiR = Hi + (size_t)(bm + wv * 16 + sr) * 512 + sc;
    const short* loR = Lo + (size_t)(bm + wv * 16 + sr) * 512 + sc;
    const short* hiC = Hi + (size_t)(bn + wv * 16 + sr) * 512 + sc;
    const short* loC = Lo + (size_t)(bn + wv * 16 + sr) * 512 + sc;
    int ldsOff = (wv * 16) * 64;
    f4v acc[2][2] = {};
    for (int k0 = 0; k0 < 512; k0 += 64) {
        __syncthreads();
        gload16(hiR + k0, HiR + ldsOff);
        gload16(hiR + (size_t)8 * 512 + k0, HiR + ldsOff + 8 * 64);
        gload16(loR + k0, LoR + ldsOff);
        gload16(loR + (size_t)8 * 512 + k0, LoR + ldsOff + 8 * 64);
        gload16(hiC + k0, HiC + ldsOff);
        gload16(hiC + (size_t)8 * 512 + k0, HiC + ldsOff + 8 * 64);
        gload16(loC + k0, LoC + ldsOff);
        gload16(loC + (size_t)8 * 512 + k0, LoC + ldsOff + 8 * 64);
        __syncthreads();
        #pragma unroll
        for (int ks = 0; ks < 2; ++ks) {
            bh8 hr[2], lr_[2], hc[2], lc[2];
            #pragma unroll
            for (int mi = 0; mi < 2; ++mi) {
                int o = (wr * 32 + mi * 16 + c) * 64 + (((ks * 4 + g) ^ (c & 7)) * 8);
                hr[mi] = *(const bh8*)(HiR + o);
                lr_[mi] = *(const bh8*)(LoR + o);
            }
            #pragma unroll
            for (int ni = 0; ni < 2; ++ni) {
                int o = (wc * 32 + ni * 16 + c) * 64 + (((ks * 4 + g) ^ (c & 7)) * 8);
                hc[ni] = *(const bh8*)(HiC + o);
                lc[ni] = *(const bh8*)(LoC + o);
            }
            #pragma unroll
            for (int mi = 0; mi < 2; ++mi)
                #pragma unroll
                for (int ni = 0; ni < 2; ++ni) {
                    acc[mi][ni] = __builtin_amdgcn_mfma_f32_16x16x32_bf16(hr[mi], hc[ni], acc[mi][ni], 0, 0, 0);
                    acc[mi][ni] = __builtin_amdgcn_mfma_f32_16x16x32_bf16(hr[mi], lc[ni], acc[mi][ni], 0, 0, 0);
                    acc[mi][ni] = __builtin_amdgcn_mfma_f32_16x16x32_bf16(lr_[mi], hc[ni], acc[mi][ni], 0, 0, 0);
                }
        }
    }
    #pragma unroll
    for (int mi = 0; mi < 2; ++mi) {
        int row = bm + wr * 32 + mi * 16 + g * 4;
        #pragma unroll
        for (int ni = 0; ni < 2; ++ni) {
            int col = bn + wc * 32 + ni * 16 + c;
            float sqc = SQ[col];
            #pragma unroll
            for (int rr = 0; rr < 4; ++rr)
                D2[(size_t)(row + rr) * NSEQ + col] = SQ[row + rr] + sqc - 2.f * acc[mi][ni][rr];
        }
    }
}

// ---------- top-9 smallest per row (both batches in one grid of 4096) ----------
__global__ __launch_bounds__(256) void topk9_k(const float* __restrict__ D2a,
                                               const float* __restrict__ D2b, int* __restrict__ idx)
{
    int ng = blockIdx.x, tid = threadIdx.x;
    const float* D2 = (ng >> 11) ? D2b : D2a;
    int n = ng & 2047;
    __shared__ u64k lists[256][9];
    u64k a[8];
    union { float f; unsigned u; } cv;
    #pragma unroll
    for (int j = 0; j < 8; ++j) {
        int mcol = tid + j * 256;
        cv.f = fmaxf(D2[(size_t)n * NSEQ + mcol], 0.f);
        a[j] = ((u64k)cv.u << 32) | (unsigned)mcol;
    }
    #define CE(i,j) { u64k x = a[i], y = a[j]; bool t = x < y; a[i] = t ? x : y; a[j] = t ? y : x; }
    CE(0,1) CE(2,3) CE(4,5) CE(6,7)
    CE(0,2) CE(1,3) CE(4,6) CE(5,7)
    CE(1,2) CE(5,6)
    CE(0,4) CE(1,5) CE(2,6) CE(3,7)
    CE(2,4) CE(3,5)
    CE(1,2) CE(3,4) CE(5,6)
    #undef CE
    #pragma unroll
    for (int j = 0; j < 8; ++j) lists[tid][j] = a[j];
    lists[tid][8] = ~0ull;
    __syncthreads();
    for (int s = 128; s >= 1; s >>= 1) {
        if (tid < s) {
            u64k out[9];
            u64k* Al = lists[tid];
            u64k* Bl = lists[tid + s];
            int ia = 0, ib = 0;
            #pragma unroll
            for (int o = 0; o < 9; ++o) {
                u64k av = Al[ia], bv = Bl[ib];
                bool t = av <= bv;
                out[o] = t ? av : bv;
                ia += t; ib += !t;
            }
            #pragma unroll
            for (int o = 0; o < 9; ++o) Al[o] = out[o];
        }
        __syncthreads();
    }
    if (tid < 9) idx[ng * KNN + tid] = (int)(lists[0][tid] & 0xffffffffu);
}

// ---------- GCN aggregate + LN + leaky + residual (writes f32 + bf16) ----------
__global__ __launch_bounds__(256) void gcn_post(
        const float* __restrict__ s, const int* __restrict__ idx,
        const float* __restrict__ g, const float* __restrict__ be,
        float* __restrict__ hg, short* __restrict__ hgb)
{
    int row = blockIdx.x, tid = threadIdx.x;
    int bb = row >> 11;
    __shared__ float os[512];
    __shared__ float red[256];
    int id[KNN];
    #pragma unroll
    for (int j = 0; j < KNN; ++j) id[j] = idx[row * KNN + j] + (bb << 11);
    for (int c = tid; c < 512; c += 256) {
        float acc = 0.f;
        #pragma unroll
        for (int j = 0; j < KNN; ++j) acc += s[((size_t)id[j] << 9) + c];
        os[c] = acc * (1.f / 9.f);
    }
    __syncthreads();
    float mean = blockReduceSum(os[tid] + os[tid + 256], red) * (1.f / 512.f);
    float d0 = os[tid] - mean, d1 = os[tid + 256] - mean;
    float var = blockReduceSum(d0 * d0 + d1 * d1, red) * (1.f / 512.f);
    float rs = rsqrtf(var + 1e-5f);
    size_t base = (size_t)row << 9;
    for (int c = tid; c < 512; c += 256) {
        float y = (os[c] - mean) * rs * g[c] + be[c];
        y = y > 0.f ? y : 0.2f * y;
        float nv = y + hg[base + c];
        hg[base + c] = nv;
        hgb[base + c] = f2bf(nv);
    }
}

// ---------- x = LN(x + r)*g + b (writes f32 + bf16) ----------
__global__ __launch_bounds__(256) void ln_res(
        float* __restrict__ x, const float* __restrict__ r,
        const float* __restrict__ g, const float* __restrict__ b, short* __restrict__ xb)
{
    int row = blockIdx.x, tid = threadIdx.x;
    __shared__ float xs[512];
    __shared__ float red[256];
    size_t base = (size_t)row << 9;
    for (int c = tid; c < 512; c += 256) xs[c] = x[base + c] + r[base + c];
    __syncthreads();
    float mean = blockReduceSum(xs[tid] + xs[tid + 256], red) * (1.f / 512.f);
    float d0 = xs[tid] - mean, d1 = xs[tid + 256] - mean;
    float var = blockReduceSum(d0 * d0 + d1 * d1, red) * (1.f / 512.f);
    float rs = rsqrtf(var + 1e-5f);
    for (int c = tid; c < 512; c += 256) {
        float y = (xs[c] - mean) * rs * g[c] + b[c];
        x[base + c] = y;
        xb[base + c] = f2bf(y);
    }
}

// ---------- flash attention: swapped-operand, KV-split=4, K+V LDS dbuf ----------
__global__ __launch_bounds__(256) void flash_attn(
        const short* __restrict__ Qb, const short* __restrict__ Kb,
        const short* __restrict__ Vt, short* __restrict__ Opb, float* __restrict__ Ml)
{
    __shared__ short Ks[2][4096];
    __shared__ short Vs[2][4096];
    int tid = threadIdx.x;
    int wid = tid >> 6, lane = tid & 63;
    int g = lane >> 4, c = lane & 15;
    int s = blockIdx.y, bh = blockIdx.z;
    int q0 = blockIdx.x * 64 + wid * 16;
    int srow = lane >> 3;
    int sc8 = ((lane & 7) ^ srow) * 8;
    int w8 = wid * 8;

    const short* KbB = Kb + ((size_t)bh * NSEQ + s * 512) * 64;
    const short* VtB = Vt + (size_t)bh * 64 * NSEQ + s * 512;

    const short* qbase = Qb + ((size_t)bh * NSEQ + q0 + c) * 64 + g * 8;
    bh8 qa0 = *(const bh8*)(qbase);
    bh8 qa1 = *(const bh8*)(qbase + 32);

    f4v o0 = {0,0,0,0}, o1 = {0,0,0,0}, o2 = {0,0,0,0}, o3 = {0,0,0,0};
    float lloc = 0.f;
    float mrun = -INFINITY;
    int hi2 = g >> 1;
    int s1 = c + (((g << 1) & 3) << 4);
    int s2 = c + ((((g << 1) + 1) & 3) << 4);

    #define FSTAGE(buf, kt) { \
        const short* kp_ = KbB + (size_t)(kt) * 64 * 64; \
        gload16(kp_ + (size_t)(w8 + srow) * 64 + sc8,        &Ks[buf][w8 * 64]); \
        gload16(kp_ + (size_t)(32 + w8 + srow) * 64 + sc8,   &Ks[buf][(32 + w8) * 64]); \
        const short* vp_ = VtB + (size_t)(kt) * 64; \
        gload16(vp_ + (size_t)(w8 + srow) * NSEQ + sc8,      &Vs[buf][w8 * 64]); \
        gload16(vp_ + (size_t)(32 + w8 + srow) * NSEQ + sc8, &Vs[buf][(32 + w8) * 64]); }

    FSTAGE(0, 0);
    __syncthreads();
    for (int t = 0; t < 8; ++t) {
        int cur = t & 1;
        if (t < 7) FSTAGE(cur ^ 1, t + 1);
        f4v sv[4];
        #pragma unroll
        for (int cb = 0; cb < 4; ++cb) {
            int row = cb * 16 + c;
            const short* kr = &Ks[cur][row * 64];
            bh8 kb0 = *(const bh8*)(kr + ((g ^ (row & 7)) * 8));
            bh8 kb1 = *(const bh8*)(kr + (((4 + g) ^ (row & 7)) * 8));
            f4v a = {0,0,0,0};
            a = __builtin_amdgcn_mfma_f32_16x16x32_bf16(kb0, qa0, a, 0, 0, 0);
            a = __builtin_amdgcn_mfma_f32_16x16x32_bf16(kb1, qa1, a, 0, 0, 0);
            sv[cb] = a;
        }
        float mt = fmaxf(fmaxf(fmaxf(sv[0][0], sv[0][1]), fmaxf(sv[0][2], sv[0][3])),
                         fmaxf(fmaxf(sv[1][0], sv[1][1]), fmaxf(sv[1][2], sv[1][3])));
        mt = fmaxf(mt, fmaxf(fmaxf(sv[2][0], sv[2][1]), fmaxf(sv[2][2], sv[2][3])));
        mt = fmaxf(mt, fmaxf(fmaxf(sv[3][0], sv[3][1]), fmaxf(sv[3][2], sv[3][3])));
        mt = fmaxf(mt, __shfl_xor(mt, 16));
        mt = fmaxf(mt, __shfl_xor(mt, 32));
        if (__any(mt > mrun + 6.f)) {
            float mn = fmaxf(mrun, mt);
            float al = __builtin_amdgcn_exp2f(mrun - mn);
            mrun = mn;
            o0 *= al; o1 *= al; o2 *= al; o3 *= al; lloc *= al;
        }
        unsigned wv_[8];
        #pragma unroll
        for (int cb = 0; cb < 4; ++cb) {
            float p0 = __builtin_amdgcn_exp2f(sv[cb][0] - mrun);
            float p1 = __builtin_amdgcn_exp2f(sv[cb][1] - mrun);
            float p2 = __builtin_amdgcn_exp2f(sv[cb][2] - mrun);
            float p3 = __builtin_amdgcn_exp2f(sv[cb][3] - mrun);
            lloc += (p0 + p1) + (p2 + p3);
            asm("v_cvt_pk_bf16_f32 %0, %1, %2" : "=v"(wv_[cb * 2])     : "v"(p0), "v"(p1));
            asm("v_cvt_pk_bf16_f32 %0, %1, %2" : "=v"(wv_[cb * 2 + 1]) : "v"(p2), "v"(p3));
        }
        union { unsigned u[4]; bh8 h; } pa0u, pa1u;
        {
            unsigned t0 = __shfl((int)wv_[0], s1), t2 = __shfl((int)wv_[2], s1);
            unsigned t1 = __shfl((int)wv_[1], s1), t3 = __shfl((int)wv_[3], s1);
            unsigned u0 = __shfl((int)wv_[0], s2), u2 = __shfl((int)wv_[2], s2);
            unsigned u1 = __shfl((int)wv_[1], s2), u3 = __shfl((int)wv_[3], s2);
            pa0u.u[0] = hi2 ? t2 : t0;
            pa0u.u[1] = hi2 ? t3 : t1;
            pa0u.u[2] = hi2 ? u2 : u0;
            pa0u.u[3] = hi2 ? u3 : u1;
        }
        {
            unsigned t0 = __shfl((int)wv_[4], s1), t2 = __shfl((int)wv_[6], s1);
            unsigned t1 = __shfl((int)wv_[5], s1), t3 = __shfl((int)wv_[7], s1);
            unsigned u0 = __shfl((int)wv_[4], s2), u2 = __shfl((int)wv_[6], s2);
            unsigned u1 = __shfl((int)wv_[5], s2), u3 = __shfl((int)wv_[7], s2);
            pa1u.u[0] = hi2 ? t2 : t0;
            pa1u.u[1] = hi2 ? t3 : t1;
            pa1u.u[2] = hi2 ? u2 : u0;
            pa1u.u[3] = hi2 ? u3 : u1;
        }
        #pragma unroll
        for (int db = 0; db < 4; ++db) {
            int row = db * 16 + c;
            const short* vr = &Vs[cur][row * 64];
            bh8 vb0 = *(const bh8*)(vr + ((g ^ (row & 7)) * 8));
            bh8 vb1 = *(const bh8*)(vr + (((4 + g) ^ (row & 7)) * 8));
            f4v* op = (db == 0) ? &o0 : (db == 1) ? &o1 : (db == 2) ? &o2 : &o3;
            *op = __builtin_amdgcn_mfma_f32_16x16x32_bf16(vb0, pa0u.h, *op, 0, 0, 0);
            *op = __builtin_amdgcn_mfma_f32_16x16x32_bf16(vb1, pa1u.h, *op, 0, 0, 0);
        }
        __syncthreads();
    }
    #undef FSTAGE
    float lsum = lloc;
    lsum += __shfl_xor(lsum, 16);
    lsum += __shfl_xor(lsum, 32);
    size_t qrow = ((size_t)(s * 16 + bh) * NSEQ) + q0 + c;
    size_t rb = qrow * 64 + g * 4;
    #pragma unroll
    for (int r = 0; r < 4; ++r) {
        Opb[rb + r]      = f2bf(o0[r]);
        Opb[rb + 16 + r] = f2bf(o1[r]);
        Opb[rb + 32 + r] = f2bf(o2[r]);
        Opb[rb + 48 + r] = f2bf(o3[r]);
    }
    if (g == 0) {
        Ml[qrow * 2]     = mrun;
        Ml[qrow * 2 + 1] = lsum;
    }
}

// ---------- merge 4 KV-splits -> bf16 attention output ----------
__global__ __launch_bounds__(256) void merge_k(const short* __restrict__ Opb, const float* __restrict__ Ml,
                                               short* __restrict__ aob)
{
    int idx = blockIdx.x * 256 + threadIdx.x;   // 16*2048*64
    int d = idx & 63, q = (idx >> 6) & 2047, bh = idx >> 17;
    float M = -INFINITY;
    float mv[4], lv[4];
    #pragma unroll
    for (int s = 0; s < 4; ++s) {
        size_t r = (size_t)(s * 16 + bh) * NSEQ + q;
        mv[s] = Ml[r * 2]; lv[s] = Ml[r * 2 + 1];
        M = fmaxf(M, mv[s]);
    }
    float L = 0.f, num = 0.f;
    #pragma unroll
    for (int s = 0; s < 4; ++s) {
        float w = __builtin_amdgcn_exp2f(mv[s] - M);
        L += lv[s] * w;
        num += b2f(Opb[((size_t)(s * 16 + bh) * NSEQ + q) * 64 + d]) * w;
    }
    int b = bh >> 3, h = bh & 7;
    aob[((size_t)(b * NSEQ + q)) * 512 + h * 64 + d] = f2bf(num / L);
}

// ---------- GLU per-row: h, copies, hi/lo split, fused row-sq ----------
__global__ __launch_bounds__(256) void glu_row_k(const float* __restrict__ vg, float* __restrict__ h,
        float* __restrict__ hgf, short* __restrict__ hi, short* __restrict__ lo,
        float* __restrict__ sq) {
    int row = blockIdx.x, tid = threadIdx.x;
    __shared__ float red[256];
    size_t vb = (size_t)row << 10;
    size_t hb = (size_t)row << 9;
    float ss = 0.f;
    #pragma unroll
    for (int j = 0; j < 2; ++j) {
        int c = tid + j * 256;
        float v = vg[vb + c], gt = vg[vb + 512 + c];
        float hv = v * (1.f / (1.f + __expf(-gt)));
        h[hb + c] = hv; hgf[hb + c] = hv;
        short hbb = f2bf(hv);
        hi[hb + c] = hbb;
        lo[hb + c] = f2bf(hv - b2f(hbb));
        ss = fmaf(hv, hv, ss);
    }
    float sm = blockReduceSum(ss, red);
    if (tid == 0) sq[row] = sm;
}

__global__ void concat_bf(const short* __restrict__ hgb, const short* __restrict__ htb,
                          short* __restrict__ cat) {
    for (int i = blockIdx.x * 256 + threadIdx.x; i < ROWS * 256; i += gridDim.x * 256) {
        int row = i >> 8, c4 = (i & 255) * 4;
        short4 v = (c4 < 512) ? *(const short4*)(hgb + ((size_t)row << 9) + c4)
                              : *(const short4*)(htb + ((size_t)row << 9) + c4 - 512);
        *(short4*)(cat + ((size_t)row << 10) + c4) = v;
    }
}

// ---------- pooling / classifier ----------
__global__ __launch_bounds__(256) void rowdot_k(const float* __restrict__ t, const float* __restrict__ w2,
                                                const float* __restrict__ b2, float* __restrict__ srow) {
    int row = blockIdx.x, tid = threadIdx.x;
    __shared__ float red[256];
    float s = blockReduceSum(t[(size_t)row * 256 + tid] * w2[tid], red);
    if (tid == 0) srow[row] = s + b2[0];
}
__global__ __launch_bounds__(256) void softmax_n_k(const float* __restrict__ srow, float* __restrict__ a,
                                                   float* __restrict__ out) {
    int b = blockIdx.x, tid = threadIdx.x;
    __shared__ float red[256];
    float mx = -INFINITY;
    for (int n = tid; n < NSEQ; n += 256) mx = fmaxf(mx, srow[b * NSEQ + n]);
    red[tid] = mx; __syncthreads();
    for (int s = 128; s > 0; s >>= 1) {
        if (tid < s) red[tid] = fmaxf(red[tid], red[tid + s]);
        __syncthreads();
    }
    mx = red[0]; __syncthreads();
    float sm = 0.f;
    for (int n = tid; n < NSEQ; n += 256) {
        float e = expf(srow[b * NSEQ + n] - mx);
        a[b * NSEQ + n] = e; sm += e;
    }
    float inv = 1.f / blockReduceSum(sm, red);
    for (int n = tid; n < NSEQ; n += 256) {
        float v = a[b * NSEQ + n] * inv;
        a[b * NSEQ + n] = v;
        out[2 + b * NSEQ + n] = v;
    }
}
__global__ __launch_bounds__(256) void pool_part(const float* __restrict__ hf, const float* __restrict__ a,
                                                 float* __restrict__ part) {
    int b = blockIdx.y, chunk = blockIdx.x, tid = threadIdx.x;
    float a0 = 0.f, a1 = 0.f;
    for (int r = 0; r < 64; ++r) {
        int n = chunk * 64 + r;
        float wgt = a[b * NSEQ + n];
        const float* row = hf + ((size_t)(b * NSEQ + n) << 9);
        a0 = fmaf(row[tid], wgt, a0);
        a1 = fmaf(row[tid + 256], wgt, a1);
    }
    part[((b * 32 + chunk) << 9) + tid] = a0;
    part[((b * 32 + chunk) << 9) + tid + 256] = a1;
}
__global__ __launch_bounds__(256) void pool_fin(const float* __restrict__ part, float* __restrict__ Mb,
                                                float* __restrict__ out) {
    int b = blockIdx.x, tid = threadIdx.x;
    float s0 = 0.f, s1 = 0.f;
    for (int ch = 0; ch < 32; ++ch) {
        s0 += part[((b * 32 + ch) << 9) + tid];
        s1 += part[((b * 32 + ch) << 9) + tid + 256];
    }
    Mb[b * 512 + tid] = s0; Mb[b * 512 + tid + 256] = s1;
    out[2 + ROWS + b * 512 + tid] = s0; out[2 + ROWS + b * 512 + tid + 256] = s1;
}
__global__ __launch_bounds__(256) void classifier_k(const float* __restrict__ Mb,
        const float* __restrict__ w1, const float* __restrict__ b1,
        const float* __restrict__ w2, const float* __restrict__ b2, float* __restrict__ out) {
    int b = blockIdx.x, tid = threadIdx.x;
    __shared__ float Ms[512];
    __shared__ float red[256];
    for (int c = tid; c < 512; c += 256) Ms[c] = Mb[b * 512 + c];
    __syncthreads();
    float acc = 0.f;
    for (int c = 0; c < 512; ++c) acc = fmaf(Ms[c], w1[tid * 512 + c], acc);
    acc += b1[tid];
    float hj = acc > 0.f ? acc : expm1f(acc);   // ELU alpha=1
    float s = blockReduceSum(hj * w2[tid], red);
    if (tid == 0) out[b] = s + b2[0];
}

extern "C" void kernel_launch(void* const* d_in, const int* in_sizes, int n_in,
                              void* d_out, int out_size, void* d_ws, size_t ws_size,
                              hipStream_t stream)
{
    const float* X      = (const float*)d_in[0];
    const float* Wstart = (const float*)d_in[1];
    const float* Bstart = (const float*)d_in[2];
    const float* GluW   = (const float*)d_in[3];
    const float* GluB   = (const float*)d_in[4];
    const float* GcnW   = (const float*)d_in[5];
    const float* GcnB   = (const float*)d_in[6];
    const float* GcnG   = (const float*)d_in[7];
    const float* GcnBe  = (const float*)d_in[8];
    const float* QkvW   = (const float*)d_in[9];
    const float* QkvB   = (const float*)d_in[10];
    const float* OutW   = (const float*)d_in[11];
    const float* OutB   = (const float*)d_in[12];
    const float* Ln1G   = (const float*)d_in[13];
    const float* Ln1B   = (const float*)d_in[14];
    const float* Ffn1W  = (const float*)d_in[15];
    const float* Ffn1B  = (const float*)d_in[16];
    const float* Ffn2W  = (const float*)d_in[17];
    const float* Ffn2B  = (const float*)d_in[18];
    const float* Ln2G   = (const float*)d_in[19];
    const float* Ln2B   = (const float*)d_in[20];
    const float* FusW   = (const float*)d_in[21];
    const float* FusB   = (const float*)d_in[22];
    const float* AW1    = (const float*)d_in[23];
    const float* AB1    = (const float*)d_in[24];
    const float* AW2    = (const float*)d_in[25];
    const float* AB2    = (const float*)d_in[26];
    const float* CW1    = (const float*)d_in[27];
    const float* CB1    = (const float*)d_in[28];
    const float* CW2    = (const float*)d_in[29];
    const float* CB2    = (const float*)d_in[30];
    float* out = (float*)d_out;

    if (ws_size < 86 * MB) return;

    char* w = (char*)d_ws;
    // bf16 weight arena [0,13MB)
    short* Wb = (short*)w;
    short* wbStart = Wb;
    short* wbGlu   = Wb + 524288;
    short* wbGcn   = Wb + 1048576;
    short* wbQkv   = Wb + 1572864;
    short* wbOut   = Wb + 3145728;
    short* wbFfn1  = Wb + 3670016;
    short* wbFfn2  = Wb + 4718592;
    short* wbFus   = Wb + 5767168;
    short* wbAw1   = Wb + 6291456;
    // small [13MB,14MB)
    float* sq   = (float*)(w + 13 * MB);
    int*   idx  = (int*)  (w + 13 * MB + (16u << 10));
    float* srow = (float*)(w + 13 * MB + (176u << 10));
    float* afb  = (float*)(w + 13 * MB + (192u << 10));
    float* Mbuf = (float*)(w + 13 * MB + (208u << 10));
    float* part = (float*)(w + 13 * MB + (212u << 10));
    // overlapped big buffers
    short* Xbf  = (short*)(w + 14 * MB);   // 8MB -> hg after fc_start
    float* hg   = (float*)(w + 14 * MB);
    short* hpreb= (short*)(w + 22 * MB);   // 4MB -> hgb after GLU gemm
    short* hgb  = (short*)(w + 22 * MB);
    float* big  = (float*)(w + 26 * MB);   // 26..42MB: vg/D2a/gcn-s/Opb/out-proj
    short* Opb  = (short*)(w + 26 * MB);   // 16MB: 4 splits (bf16 O-partials)
    float* Ml   = (float*)(w + 42 * MB);   // 1MB (dead ffn2o window during attn)
    float* ffn2o= (float*)(w + 42 * MB);   // 8MB
    float* h    = (float*)(w + 50 * MB);   // 8MB; doubles as ht residual
    short* hhi  = (short*)(w + 58 * MB);   // 4MB; -> hf low half after loop
    short* hlo  = (short*)(w + 62 * MB);   // 4MB; dead after gram -> htb
    short* htb  = (short*)(w + 62 * MB);   // 4MB
    float* hf   = (float*)(w + 58 * MB);   // 8MB (after transformer loop)
    float* D2b1 = (float*)(w + 66 * MB);   // 16MB (KNN phase only: 66..82 all dead then)
    short* hfb  = (short*)(w + 66 * MB);   // 4MB
    short* aob  = (short*)(w + 70 * MB);   // 4MB; -> t256 (pool)
    float* t256 = (float*)(w + 70 * MB);
    short* Qb   = (short*)(w + 74 * MB);   // 4MB  (OUTMODE=3: K=Qb+4MB, Vt=Qb+8MB)
    short* Kb   = (short*)(w + 78 * MB);   // 4MB
    short* Vt   = (short*)(w + 82 * MB);   // 4MB (transposed V, written by qkv GEMM)
    short* ffb  = (short*)(w + 74 * MB);   // 8MB (ffn1 out; Qb/Kb dead) -> catb
    short* catb = (short*)(w + 74 * MB);

    dim3 blk(256);

    // convert X + all GEMM weights to bf16
    CvtArgs ca;
    ca.src[0] = X;     ca.dst[0] = Xbf;     ca.n4[0] = ROWS * 1024 / 4;
    ca.src[1] = Wstart;ca.dst[1] = wbStart; ca.n4[1] = 524288 / 4;
    ca.src[2] = GluW;  ca.dst[2] = wbGlu;   ca.n4[2] = 524288 / 4;
    ca.src[3] = GcnW;  ca.dst[3] = wbGcn;   ca.n4[3] = 524288 / 4;
    ca.src[4] = QkvW;  ca.dst[4] = wbQkv;   ca.n4[4] = 1572864 / 4;
    ca.src[5] = OutW;  ca.dst[5] = wbOut;   ca.n4[5] = 524288 / 4;
    ca.src[6] = Ffn1W; ca.dst[6] = wbFfn1;  ca.n4[6] = 1048576 / 4;
    ca.src[7] = Ffn2W; ca.dst[7] = wbFfn2;  ca.n4[7] = 1048576 / 4;
    ca.src[8] = FusW;  ca.dst[8] = wbFus;   ca.n4[8] = 524288 / 4;
    ca.src[9] = AW1;   ca.dst[9] = wbAw1;   ca.n4[9] = 131072 / 4;
    cvt_k<<<dim3(256, 10), blk, 0, stream>>>(ca);

    // fc_start -> GLU (fused rowsq)
    mfma_gemm<1><<<dim3(8, 64), blk, 0, stream>>>(Xbf, wbStart, Bstart, nullptr, hpreb, ROWS, 512, 1024);
    mfma_gemm<0><<<dim3(16, 64), blk, 0, stream>>>(hpreb, wbGlu, GluB, big, nullptr, ROWS, 1024, 512);
    glu_row_k<<<dim3(ROWS), blk, 0, stream>>>(big, h, hg, hhi, hlo, sq);

    // KNN graph: both batches in single gram + single topk dispatch
    mfma_gram<<<dim3(32, 32, 2), blk, 0, stream>>>(hhi, hlo, sq, big, D2b1);
    topk9_k<<<dim3(ROWS), blk, 0, stream>>>(big, D2b1, idx);

    // GCN branch
    const short* gA = hhi;
    for (int i = 0; i < 2; ++i) {
        mfma_gemm<0><<<dim3(8, 64), blk, 0, stream>>>(gA, wbGcn + (size_t)i * 262144,
                                                      GcnB + i * 512, big, nullptr, ROWS, 512, 512);
        gcn_post<<<dim3(ROWS), blk, 0, stream>>>(big, idx, GcnG + i * 512, GcnBe + i * 512, hg, hgb);
        gA = hgb;
    }

    // Transformer branch (h doubles as ht residual)
    const short* tA = hhi;
    for (int i = 0; i < 2; ++i) {
        mfma_gemm<3><<<dim3(24, 64), blk, 0, stream>>>(tA, wbQkv + (size_t)i * 786432,
                                                       QkvB + i * 1536, nullptr, Qb, ROWS, 1536, 512);
        flash_attn<<<dim3(32, 4, 16), blk, 0, stream>>>(Qb, Kb, Vt, Opb, Ml);
        merge_k<<<dim3(8192), blk, 0, stream>>>(Opb, Ml, aob);
        mfma_gemm<0><<<dim3(8, 64), blk, 0, stream>>>(aob, wbOut + (size_t)i * 262144,
                                                      OutB + i * 512, big, nullptr, ROWS, 512, 512);
        ln_res<<<dim3(ROWS), blk, 0, stream>>>(h, big, Ln1G + i * 512, Ln1B + i * 512, htb);
        mfma_gemm<4><<<dim3(16, 64), blk, 0, stream>>>(htb, wbFfn1 + (size_t)i * 524288,
                                                       Ffn1B + i * 1024, nullptr, ffb, ROWS, 1024, 512);
        mfma_gemm<0><<<dim3(8, 64), blk, 0, stream>>>(ffb, wbFfn2 + (size_t)i * 524288,
                                                      Ffn2B + i * 512, ffn2o, nullptr, ROWS, 512, 1024);
        ln_res<<<dim3(ROWS), blk, 0, stream>>>(h, ffn2o, Ln2G + i * 512, Ln2B + i * 512, htb);
        tA = htb;
    }

    // fusion
    concat_bf<<<dim3(2048), blk, 0, stream>>>(hgb, htb, catb);
    mfma_gemm<2><<<dim3(8, 64), blk, 0, stream>>>(catb, wbFus, FusB, hf, hfb, ROWS, 512, 1024);

    // gated attention pooling (tanh fused into GEMM)
    mfma_gemm<5><<<dim3(4, 64), blk, 0, stream>>>(hfb, wbAw1, AB1, t256, nullptr, ROWS, 256, 512);
    rowdot_k<<<dim3(ROWS), blk, 0, stream>>>(t256, AW2, AB2, srow);
    softmax_n_k<<<dim3(2), blk, 0, stream>>>(srow, afb, out);
    pool_part<<<dim3(32, 2), blk, 0, stream>>>(hf, afb, part);
    pool_fin<<<dim3(2), blk, 0, stream>>>(part, Mbuf, out);

    // classifier
    classifier_k<<<dim3(2), blk, 0, stream>>>(Mbuf, CW1, CB1, CW2, CB2, out);
}

// Round 15
// 410.103 us; speedup vs baseline: 1.2318x; 1.0383x over previous
//
#include <hip/hip_runtime.h>
#include <hip/hip_bf16.h>
#include <math.h>

#define NSEQ 2048
#define ROWS 4096   // B*N
#define KNN 9
#define MB (1ull << 20)

typedef short bh8 __attribute__((ext_vector_type(8)));   // 8 bf16 in 4 VGPRs
typedef float f4v __attribute__((ext_vector_type(4)));
typedef unsigned long long u64k;

__device__ __forceinline__ short f2bf(float f) {
    union { float f; unsigned u; } v; v.f = f;
    unsigned r = (v.u + 0x7fffu + ((v.u >> 16) & 1u)) >> 16;
    return (short)r;
}
__device__ __forceinline__ float b2f(short s) {
    union { unsigned u; float f; } v; v.u = ((unsigned)(unsigned short)s) << 16; return v.f;
}

// async global->LDS, 16B per lane; LDS dest is wave-uniform base + lane*16
__device__ __forceinline__ void gload16(const void* g, void* l) {
    __builtin_amdgcn_global_load_lds(
        (const __attribute__((address_space(1))) void*)g,
        (__attribute__((address_space(3))) void*)l, 16, 0, 0);
}

// ---------- block reduce (blockDim.x == 256) ----------
__device__ __forceinline__ float blockReduceSum(float v, float* red) {
    int tid = threadIdx.x;
    red[tid] = v; __syncthreads();
    for (int s = 128; s > 0; s >>= 1) {
        if (tid < s) red[tid] += red[tid + s];
        __syncthreads();
    }
    float r = red[0]; __syncthreads();
    return r;
}

// ---------- f32 -> bf16 conversion (weights + X), 10 segments ----------
struct CvtArgs { const float* src[10]; short* dst[10]; int n4[10]; };
__global__ __launch_bounds__(256) void cvt_k(CvtArgs a) {
    int s = blockIdx.y;
    const float* sp = a.src[s]; short* dp = a.dst[s]; int n = a.n4[s];
    for (int i = blockIdx.x * 256 + threadIdx.x; i < n; i += gridDim.x * 256) {
        float4 v = ((const float4*)sp)[i];
        short4 o; o.x = f2bf(v.x); o.y = f2bf(v.y); o.z = f2bf(v.z); o.w = f2bf(v.w);
        ((short4*)dp)[i] = o;
    }
}

// ---------- shared epilogue writer ----------
template <int OUTMODE>
__device__ __forceinline__ void gemm_epilogue(int row, int col, int N, const f4v& a,
        float bv, float* Cf, short* Cb, short* Kb_, short* Vt_)
{
    if (OUTMODE == 3) {
        int b = row >> 11, n0 = row & 2047;
        if (col < 512) {
            int h = col >> 6, d = col & 63;
            size_t base = (((size_t)(b * 8 + h) * NSEQ + n0) << 6) + d;
            #pragma unroll
            for (int rr = 0; rr < 4; ++rr)
                Cb[base + ((size_t)rr << 6)] = f2bf((a[rr] + bv) * 0.18033688f);
        } else if (col < 1024) {
            int cc = col - 512, h = cc >> 6, d = cc & 63;
            size_t base = (((size_t)(b * 8 + h) * NSEQ + n0) << 6) + d;
            #pragma unroll
            for (int rr = 0; rr < 4; ++rr)
                Kb_[base + ((size_t)rr << 6)] = f2bf(a[rr] + bv);
        } else {
            int cc = col - 1024, h = cc >> 6, d = cc & 63;
            short4 ov;
            ov.x = f2bf(a[0] + bv); ov.y = f2bf(a[1] + bv);
            ov.z = f2bf(a[2] + bv); ov.w = f2bf(a[3] + bv);
            *(short4*)(Vt_ + (((size_t)((b * 8 + h) * 64 + d)) << 11) + n0) = ov;
        }
    } else {
        #pragma unroll
        for (int rr = 0; rr < 4; ++rr) {
            float v = a[rr] + bv;
            if (OUTMODE == 0) Cf[(size_t)(row + rr) * N + col] = v;
            else if (OUTMODE == 1) Cb[(size_t)(row + rr) * N + col] = f2bf(v);
            else if (OUTMODE == 2) {
                Cf[(size_t)(row + rr) * N + col] = v;
                Cb[(size_t)(row + rr) * N + col] = f2bf(v);
            } else if (OUTMODE == 4) {
                Cb[(size_t)(row + rr) * N + col] = f2bf(0.5f * v * (1.f + erff(v * 0.70710678118654752f)));
            } else if (OUTMODE == 5) {
                Cf[(size_t)(row + rr) * N + col] = tanhf(v);
            }
        }
    }
}

// ---------- MFMA GEMM 64x64 tile, dbuf prefetch, swizzled LDS ----------
// CAT=1: A is logically [M,1024] = concat(A[.,0:512], A2[.,0:512]) per row.
template <int OUTMODE, int CAT>
__global__ __launch_bounds__(256) void mfma_gemm(
        const short* __restrict__ A, const short* __restrict__ A2,
        const short* __restrict__ W,
        const float* __restrict__ bias, float* __restrict__ Cf, short* __restrict__ Cb,
        int M, int N, int K)
{
    __shared__ short As[2][64 * 64];
    __shared__ short Bs[2][64 * 64];
    int tid = threadIdx.x;
    int wv = tid >> 6, l = tid & 63;
    int g = l >> 4, c = l & 15;
    int wr = wv >> 1, wc = wv & 1;
    int bm = blockIdx.y * 64, bn = blockIdx.x * 64;
    int sr = l >> 3, sc = ((l & 7) ^ sr) * 8;
    int arow = bm + wv * 16 + sr;
    size_t astr = CAT ? 512 : (size_t)K;
    const short* Ap  = A  + (size_t)arow * astr + sc;
    const short* Ap2 = CAT ? (A2 + (size_t)arow * 512 + sc) : nullptr;
    const short* Wp = W + (size_t)(bn + wv * 16 + sr) * K + sc;
    int ldsB = (wv * 16) * 64;

    #define GSTAGE(buf, k0) { \
        const short* ab_ = (CAT && (k0) >= 512) ? (Ap2 + (k0) - 512) : (Ap + (k0)); \
        gload16(ab_, &As[buf][ldsB]); \
        gload16(ab_ + 8 * astr, &As[buf][ldsB + 8 * 64]); \
        gload16(Wp + (k0), &Bs[buf][ldsB]); \
        gload16(Wp + (size_t)8 * K + (k0), &Bs[buf][ldsB + 8 * 64]); }

    f4v acc[2][2] = {};
    GSTAGE(0, 0);
    __syncthreads();
    int nk = K >> 6;
    for (int t = 0; t < nk; ++t) {
        int cur = t & 1;
        if (t + 1 < nk) GSTAGE(cur ^ 1, (t + 1) << 6);
        #pragma unroll
        for (int ks = 0; ks < 2; ++ks) {
            bh8 af[2], bf_[2];
            #pragma unroll
            for (int mi = 0; mi < 2; ++mi) {
                int row = wr * 32 + mi * 16 + c;
                af[mi] = *(const bh8*)(&As[cur][row * 64 + (((ks * 4 + g) ^ (c & 7)) * 8)]);
            }
            #pragma unroll
            for (int ni = 0; ni < 2; ++ni) {
                int row = wc * 32 + ni * 16 + c;
                bf_[ni] = *(const bh8*)(&Bs[cur][row * 64 + (((ks * 4 + g) ^ (c & 7)) * 8)]);
            }
            #pragma unroll
            for (int mi = 0; mi < 2; ++mi)
                #pragma unroll
                for (int ni = 0; ni < 2; ++ni)
                    acc[mi][ni] = __builtin_amdgcn_mfma_f32_16x16x32_bf16(af[mi], bf_[ni], acc[mi][ni], 0, 0, 0);
        }
        __syncthreads();
    }
    #undef GSTAGE
    short* Kb_ = (OUTMODE == 3) ? Cb + 2097152 : nullptr;
    short* Vt_ = (OUTMODE == 3) ? Cb + 4194304 : nullptr;
    #pragma unroll
    for (int mi = 0; mi < 2; ++mi) {
        int row = bm + wr * 32 + mi * 16 + g * 4;
        #pragma unroll
        for (int ni = 0; ni < 2; ++ni) {
            int col = bn + wc * 32 + ni * 16 + c;
            gemm_epilogue<OUTMODE>(row, col, N, acc[mi][ni], bias[col], Cf, Cb, Kb_, Vt_);
        }
    }
}

// ---------- gram for KNN distances, hi/lo split, batched over z (2 batches) ----------
__global__ __launch_bounds__(256) void mfma_gram(
        const short* __restrict__ Hi0, const short* __restrict__ Lo0,
        const float* __restrict__ SQ0, float* __restrict__ D2a, float* __restrict__ D2b)
{
    __shared__ short HiR[64 * 64], LoR[64 * 64], HiC[64 * 64], LoC[64 * 64];
    int tid = threadIdx.x;
    int bz = blockIdx.z;
    const short* Hi = Hi0 + (size_t)bz * NSEQ * 512;
    const short* Lo = Lo0 + (size_t)bz * NSEQ * 512;
    const float* SQ = SQ0 + bz * NSEQ;
    float* D2 = bz ? D2b : D2a;
    int wv = tid >> 6, l = tid & 63;
    int g = l >> 4, c = l & 15;
    int wr = wv >> 1, wc = wv & 1;
    int bm = blockIdx.y * 64, bn = blockIdx.x * 64;
    int sr = l >> 3, sc = ((l & 7) ^ sr) * 8;
    const short* hiR = Hi + (size_t)(bm + wv * 16 + sr) * 512 + sc;
    const short* loR = Lo + (size_t)(bm + wv * 16 + sr) * 512 + sc;
    const short* hiC = Hi + (size_t)(bn + wv * 16 + sr) * 512 + sc;
    const short* loC = Lo + (size_t)(bn + wv * 16 + sr) * 512 + sc;
    int ldsOff = (wv * 16) * 64;
    f4v acc[2][2] = {};
    for (int k0 = 0; k0 < 512; k0 += 64) {
        __syncthreads();
        gload16(hiR + k0, HiR + ldsOff);
        gload16(hiR + (size_t)8 * 512 + k0, HiR + ldsOff + 8 * 64);
        gload16(loR + k0, LoR + ldsOff);
        gload16(loR + (size_t)8 * 512 + k0, LoR + ldsOff + 8 * 64);
        gload16(hiC + k0, HiC + ldsOff);
        gload16(hiC + (size_t)8 * 512 + k0, HiC + ldsOff + 8 * 64);
        gload16(loC + k0, LoC + ldsOff);
        gload16(loC + (size_t)8 * 512 + k0, LoC + ldsOff + 8 * 64);
        __syncthreads();
        #pragma unroll
        for (int ks = 0; ks < 2; ++ks) {
            bh8 hr[2], lr_[2], hc[2], lc[2];
            #pragma unroll
            for (int mi = 0; mi < 2; ++mi) {
                int o = (wr * 32 + mi * 16 + c) * 64 + (((ks * 4 + g) ^ (c & 7)) * 8);
                hr[mi] = *(const bh8*)(HiR + o);
                lr_[mi] = *(const bh8*)(LoR + o);
            }
            #pragma unroll
            for (int ni = 0; ni < 2; ++ni) {
                int o = (wc * 32 + ni * 16 + c) * 64 + (((ks * 4 + g) ^ (c & 7)) * 8);
                hc[ni] = *(const bh8*)(HiC + o);
                lc[ni] = *(const bh8*)(LoC + o);
            }
            #pragma unroll
            for (int mi = 0; mi < 2; ++mi)
                #pragma unroll
                for (int ni = 0; ni < 2; ++ni) {
                    acc[mi][ni] = __builtin_amdgcn_mfma_f32_16x16x32_bf16(hr[mi], hc[ni], acc[mi][ni], 0, 0, 0);
                    acc[mi][ni] = __builtin_amdgcn_mfma_f32_16x16x32_bf16(hr[mi], lc[ni], acc[mi][ni], 0, 0, 0);
                    acc[mi][ni] = __builtin_amdgcn_mfma_f32_16x16x32_bf16(lr_[mi], hc[ni], acc[mi][ni], 0, 0, 0);
                }
        }
    }
    #pragma unroll
    for (int mi = 0; mi < 2; ++mi) {
        int row = bm + wr * 32 + mi * 16 + g * 4;
        #pragma unroll
        for (int ni = 0; ni < 2; ++ni) {
            int col = bn + wc * 32 + ni * 16 + c;
            float sqc = SQ[col];
            #pragma unroll
            for (int rr = 0; rr < 4; ++rr)
                D2[(size_t)(row + rr) * NSEQ + col] = SQ[row + rr] + sqc - 2.f * acc[mi][ni][rr];
        }
    }
}

// ---------- top-9 smallest per row (both batches in one grid of 4096) ----------
__global__ __launch_bounds__(256) void topk9_k(const float* __restrict__ D2a,
                                               const float* __restrict__ D2b, int* __restrict__ idx)
{
    int ng = blockIdx.x, tid = threadIdx.x;
    const float* D2 = (ng >> 11) ? D2b : D2a;
    int n = ng & 2047;
    __shared__ u64k lists[256][9];
    u64k a[8];
    union { float f; unsigned u; } cv;
    #pragma unroll
    for (int j = 0; j < 8; ++j) {
        int mcol = tid + j * 256;
        cv.f = fmaxf(D2[(size_t)n * NSEQ + mcol], 0.f);
        a[j] = ((u64k)cv.u << 32) | (unsigned)mcol;
    }
    #define CE(i,j) { u64k x = a[i], y = a[j]; bool t = x < y; a[i] = t ? x : y; a[j] = t ? y : x; }
    CE(0,1) CE(2,3) CE(4,5) CE(6,7)
    CE(0,2) CE(1,3) CE(4,6) CE(5,7)
    CE(1,2) CE(5,6)
    CE(0,4) CE(1,5) CE(2,6) CE(3,7)
    CE(2,4) CE(3,5)
    CE(1,2) CE(3,4) CE(5,6)
    #undef CE
    #pragma unroll
    for (int j = 0; j < 8; ++j) lists[tid][j] = a[j];
    lists[tid][8] = ~0ull;
    __syncthreads();
    for (int s = 128; s >= 1; s >>= 1) {
        if (tid < s) {
            u64k out[9];
            u64k* Al = lists[tid];
            u64k* Bl = lists[tid + s];
            int ia = 0, ib = 0;
            #pragma unroll
            for (int o = 0; o < 9; ++o) {
                u64k av = Al[ia], bv = Bl[ib];
                bool t = av <= bv;
                out[o] = t ? av : bv;
                ia += t; ib += !t;
            }
            #pragma unroll
            for (int o = 0; o < 9; ++o) Al[o] = out[o];
        }
        __syncthreads();
    }
    if (tid < 9) idx[ng * KNN + tid] = (int)(lists[0][tid] & 0xffffffffu);
}

// ---------- GCN aggregate + LN + leaky + residual (bf16 residual state) ----------
__global__ __launch_bounds__(256) void gcn_post(
        const float* __restrict__ s, const int* __restrict__ idx,
        const float* __restrict__ g, const float* __restrict__ be,
        const short* __restrict__ rin, short* __restrict__ rout)
{
    int row = blockIdx.x, tid = threadIdx.x;
    int bb = row >> 11;
    __shared__ float os[512];
    __shared__ float red[256];
    int id[KNN];
    #pragma unroll
    for (int j = 0; j < KNN; ++j) id[j] = idx[row * KNN + j] + (bb << 11);
    for (int c = tid; c < 512; c += 256) {
        float acc = 0.f;
        #pragma unroll
        for (int j = 0; j < KNN; ++j) acc += s[((size_t)id[j] << 9) + c];
        os[c] = acc * (1.f / 9.f);
    }
    __syncthreads();
    float mean = blockReduceSum(os[tid] + os[tid + 256], red) * (1.f / 512.f);
    float d0 = os[tid] - mean, d1 = os[tid + 256] - mean;
    float var = blockReduceSum(d0 * d0 + d1 * d1, red) * (1.f / 512.f);
    float rs = rsqrtf(var + 1e-5f);
    size_t base = (size_t)row << 9;
    for (int c = tid; c < 512; c += 256) {
        float y = (os[c] - mean) * rs * g[c] + be[c];
        y = y > 0.f ? y : 0.2f * y;
        rout[base + c] = f2bf(y + b2f(rin[base + c]));
    }
}

// ---------- xout = LN(xin + r)*g + b (bf16 state, f32 r) ----------
__global__ __launch_bounds__(256) void ln_res(
        const short* __restrict__ xin, const float* __restrict__ r,
        const float* __restrict__ g, const float* __restrict__ b, short* __restrict__ xout)
{
    int row = blockIdx.x, tid = threadIdx.x;
    __shared__ float xs[512];
    __shared__ float red[256];
    size_t base = (size_t)row << 9;
    for (int c = tid; c < 512; c += 256) xs[c] = b2f(xin[base + c]) + r[base + c];
    __syncthreads();
    float mean = blockReduceSum(xs[tid] + xs[tid + 256], red) * (1.f / 512.f);
    float d0 = xs[tid] - mean, d1 = xs[tid + 256] - mean;
    float var = blockReduceSum(d0 * d0 + d1 * d1, red) * (1.f / 512.f);
    float rs = rsqrtf(var + 1e-5f);
    for (int c = tid; c < 512; c += 256)
        xout[base + c] = f2bf((xs[c] - mean) * rs * g[c] + b[c]);
}

// ---------- flash attention: swapped-operand, KV-split=4, K+V LDS dbuf ----------
__global__ __launch_bounds__(256) void flash_attn(
        const short* __restrict__ Qb, const short* __restrict__ Kb,
        const short* __restrict__ Vt, short* __restrict__ Opb, float* __restrict__ Ml)
{
    __shared__ short Ks[2][4096];
    __shared__ short Vs[2][4096];
    int tid = threadIdx.x;
    int wid = tid >> 6, lane = tid & 63;
    int g = lane >> 4, c = lane & 15;
    int s = blockIdx.y, bh = blockIdx.z;
    int q0 = blockIdx.x * 64 + wid * 16;
    int srow = lane >> 3;
    int sc8 = ((lane & 7) ^ srow) * 8;
    int w8 = wid * 8;

    const short* KbB = Kb + ((size_t)bh * NSEQ + s * 512) * 64;
    const short* VtB = Vt + (size_t)bh * 64 * NSEQ + s * 512;

    const short* qbase = Qb + ((size_t)bh * NSEQ + q0 + c) * 64 + g * 8;
    bh8 qa0 = *(const bh8*)(qbase);
    bh8 qa1 = *(const bh8*)(qbase + 32);

    f4v o0 = {0,0,0,0}, o1 = {0,0,0,0}, o2 = {0,0,0,0}, o3 = {0,0,0,0};
    float lloc = 0.f;
    float mrun = -INFINITY;
    int hi2 = g >> 1;
    int s1 = c + (((g << 1) & 3) << 4);
    int s2 = c + ((((g << 1) + 1) & 3) << 4);

    #define FSTAGE(buf, kt) { \
        const short* kp_ = KbB + (size_t)(kt) * 64 * 64; \
        gload16(kp_ + (size_t)(w8 + srow) * 64 + sc8,        &Ks[buf][w8 * 64]); \
        gload16(kp_ + (size_t)(32 + w8 + srow) * 64 + sc8,   &Ks[buf][(32 + w8) * 64]); \
        const short* vp_ = VtB + (size_t)(kt) * 64; \
        gload16(vp_ + (size_t)(w8 + srow) * NSEQ + sc8,      &Vs[buf][w8 * 64]); \
        gload16(vp_ + (size_t)(32 + w8 + srow) * NSEQ + sc8, &Vs[buf][(32 + w8) * 64]); }

    FSTAGE(0, 0);
    __syncthreads();
    for (int t = 0; t < 8; ++t) {
        int cur = t & 1;
        if (t < 7) FSTAGE(cur ^ 1, t + 1);
        f4v sv[4];
        #pragma unroll
        for (int cb = 0; cb < 4; ++cb) {
            int row = cb * 16 + c;
            const short* kr = &Ks[cur][row * 64];
            bh8 kb0 = *(const bh8*)(kr + ((g ^ (row & 7)) * 8));
            bh8 kb1 = *(const bh8*)(kr + (((4 + g) ^ (row & 7)) * 8));
            f4v a = {0,0,0,0};
            a = __builtin_amdgcn_mfma_f32_16x16x32_bf16(kb0, qa0, a, 0, 0, 0);
            a = __builtin_amdgcn_mfma_f32_16x16x32_bf16(kb1, qa1, a, 0, 0, 0);
            sv[cb] = a;
        }
        float mt = fmaxf(fmaxf(fmaxf(sv[0][0], sv[0][1]), fmaxf(sv[0][2], sv[0][3])),
                         fmaxf(fmaxf(sv[1][0], sv[1][1]), fmaxf(sv[1][2], sv[1][3])));
        mt = fmaxf(mt, fmaxf(fmaxf(sv[2][0], sv[2][1]), fmaxf(sv[2][2], sv[2][3])));
        mt = fmaxf(mt, fmaxf(fmaxf(sv[3][0], sv[3][1]), fmaxf(sv[3][2], sv[3][3])));
        mt = fmaxf(mt, __shfl_xor(mt, 16));
        mt = fmaxf(mt, __shfl_xor(mt, 32));
        if (__any(mt > mrun + 6.f)) {
            float mn = fmaxf(mrun, mt);
            float al = __builtin_amdgcn_exp2f(mrun - mn);
            mrun = mn;
            o0 *= al; o1 *= al; o2 *= al; o3 *= al; lloc *= al;
        }
        unsigned wv_[8];
        #pragma unroll
        for (int cb = 0; cb < 4; ++cb) {
            float p0 = __builtin_amdgcn_exp2f(sv[cb][0] - mrun);
            float p1 = __builtin_amdgcn_exp2f(sv[cb][1] - mrun);
            float p2 = __builtin_amdgcn_exp2f(sv[cb][2] - mrun);
            float p3 = __builtin_amdgcn_exp2f(sv[cb][3] - mrun);
            lloc += (p0 + p1) + (p2 + p3);
            asm("v_cvt_pk_bf16_f32 %0, %1, %2" : "=v"(wv_[cb * 2])     : "v"(p0), "v"(p1));
            asm("v_cvt_pk_bf16_f32 %0, %1, %2" : "=v"(wv_[cb * 2 + 1]) : "v"(p2), "v"(p3));
        }
        union { unsigned u[4]; bh8 h; } pa0u, pa1u;
        {
            unsigned t0 = __shfl((int)wv_[0], s1), t2 = __shfl((int)wv_[2], s1);
            unsigned t1 = __shfl((int)wv_[1], s1), t3 = __shfl((int)wv_[3], s1);
            unsigned u0 = __shfl((int)wv_[0], s2), u2 = __shfl((int)wv_[2], s2);
            unsigned u1 = __shfl((int)wv_[1], s2), u3 = __shfl((int)wv_[3], s2);
            pa0u.u[0] = hi2 ? t2 : t0;
            pa0u.u[1] = hi2 ? t3 : t1;
            pa0u.u[2] = hi2 ? u2 : u0;
            pa0u.u[3] = hi2 ? u3 : u1;
        }
        {
            unsigned t0 = __shfl((int)wv_[4], s1), t2 = __shfl((int)wv_[6], s1);
            unsigned t1 = __shfl((int)wv_[5], s1), t3 = __shfl((int)wv_[7], s1);
            unsigned u0 = __shfl((int)wv_[4], s2), u2 = __shfl((int)wv_[6], s2);
            unsigned u1 = __shfl((int)wv_[5], s2), u3 = __shfl((int)wv_[7], s2);
            pa1u.u[0] = hi2 ? t2 : t0;
            pa1u.u[1] = hi2 ? t3 : t1;
            pa1u.u[2] = hi2 ? u2 : u0;
            pa1u.u[3] = hi2 ? u3 : u1;
        }
        #pragma unroll
        for (int db = 0; db < 4; ++db) {
            int row = db * 16 + c;
            const short* vr = &Vs[cur][row * 64];
            bh8 vb0 = *(const bh8*)(vr + ((g ^ (row & 7)) * 8));
            bh8 vb1 = *(const bh8*)(vr + (((4 + g) ^ (row & 7)) * 8));
            f4v* op = (db == 0) ? &o0 : (db == 1) ? &o1 : (db == 2) ? &o2 : &o3;
            *op = __builtin_amdgcn_mfma_f32_16x16x32_bf16(vb0, pa0u.h, *op, 0, 0, 0);
            *op = __builtin_amdgcn_mfma_f32_16x16x32_bf16(vb1, pa1u.h, *op, 0, 0, 0);
        }
        __syncthreads();
    }
    #undef FSTAGE
    float lsum = lloc;
    lsum += __shfl_xor(lsum, 16);
    lsum += __shfl_xor(lsum, 32);
    size_t qrow = ((size_t)(s * 16 + bh) * NSEQ) + q0 + c;
    size_t rb = qrow * 64 + g * 4;
    #pragma unroll
    for (int r = 0; r < 4; ++r) {
        Opb[rb + r]      = f2bf(o0[r]);
        Opb[rb + 16 + r] = f2bf(o1[r]);
        Opb[rb + 32 + r] = f2bf(o2[r]);
        Opb[rb + 48 + r] = f2bf(o3[r]);
    }
    if (g == 0) {
        Ml[qrow * 2]     = mrun;
        Ml[qrow * 2 + 1] = lsum;
    }
}

// ---------- merge 4 KV-splits -> bf16 attention output ----------
__global__ __launch_bounds__(256) void merge_k(const short* __restrict__ Opb, const float* __restrict__ Ml,
                                               short* __restrict__ aob)
{
    int idx = blockIdx.x * 256 + threadIdx.x;   // 16*2048*64
    int d = idx & 63, q = (idx >> 6) & 2047, bh = idx >> 17;
    float M = -INFINITY;
    float mv[4], lv[4];
    #pragma unroll
    for (int s = 0; s < 4; ++s) {
        size_t r = (size_t)(s * 16 + bh) * NSEQ + q;
        mv[s] = Ml[r * 2]; lv[s] = Ml[r * 2 + 1];
        M = fmaxf(M, mv[s]);
    }
    float L = 0.f, num = 0.f;
    #pragma unroll
    for (int s = 0; s < 4; ++s) {
        float w = __builtin_amdgcn_exp2f(mv[s] - M);
        L += lv[s] * w;
        num += b2f(Opb[((size_t)(s * 16 + bh) * NSEQ + q) * 64 + d]) * w;
    }
    int b = bh >> 3, h = bh & 7;
    aob[((size_t)(b * NSEQ + q)) * 512 + h * 64 + d] = f2bf(num / L);
}

// ---------- GLU per-row: hi/lo split + fused row-sq (no f32 outputs) ----------
__global__ __launch_bounds__(256) void glu_row_k(const float* __restrict__ vg,
        short* __restrict__ hi, short* __restrict__ lo, float* __restrict__ sq) {
    int row = blockIdx.x, tid = threadIdx.x;
    __shared__ float red[256];
    size_t vb = (size_t)row << 10;
    size_t hb = (size_t)row << 9;
    float ss = 0.f;
    #pragma unroll
    for (int j = 0; j < 2; ++j) {
        int c = tid + j * 256;
        float v = vg[vb + c], gt = vg[vb + 512 + c];
        float hv = v * (1.f / (1.f + __expf(-gt)));
        short hbb = f2bf(hv);
        hi[hb + c] = hbb;
        lo[hb + c] = f2bf(hv - b2f(hbb));
        ss = fmaf(hv, hv, ss);
    }
    float sm = blockReduceSum(ss, red);
    if (tid == 0) sq[row] = sm;
}

// ---------- pooling / classifier ----------
__global__ __launch_bounds__(256) void rowdot_k(const float* __restrict__ t, const float* __restrict__ w2,
                                                const float* __restrict__ b2, float* __restrict__ srow) {
    int row = blockIdx.x, tid = threadIdx.x;
    __shared__ float red[256];
    float s = blockReduceSum(t[(size_t)row * 256 + tid] * w2[tid], red);
    if (tid == 0) srow[row] = s + b2[0];
}
__global__ __launch_bounds__(256) void softmax_n_k(const float* __restrict__ srow, float* __restrict__ a,
                                                   float* __restrict__ out) {
    int b = blockIdx.x, tid = threadIdx.x;
    __shared__ float red[256];
    float mx = -INFINITY;
    for (int n = tid; n < NSEQ; n += 256) mx = fmaxf(mx, srow[b * NSEQ + n]);
    red[tid] = mx; __syncthreads();
    for (int s = 128; s > 0; s >>= 1) {
        if (tid < s) red[tid] = fmaxf(red[tid], red[tid + s]);
        __syncthreads();
    }
    mx = red[0]; __syncthreads();
    float sm = 0.f;
    for (int n = tid; n < NSEQ; n += 256) {
        float e = expf(srow[b * NSEQ + n] - mx);
        a[b * NSEQ + n] = e; sm += e;
    }
    float inv = 1.f / blockReduceSum(sm, red);
    for (int n = tid; n < NSEQ; n += 256) {
        float v = a[b * NSEQ + n] * inv;
        a[b * NSEQ + n] = v;
        out[2 + b * NSEQ + n] = v;
    }
}
__global__ __launch_bounds__(256) void pool_part(const float* __restrict__ hf, const float* __restrict__ a,
                                                 float* __restrict__ part) {
    int b = blockIdx.y, chunk = blockIdx.x, tid = threadIdx.x;
    float a0 = 0.f, a1 = 0.f;
    for (int r = 0; r < 64; ++r) {
        int n = chunk * 64 + r;
        float wgt = a[b * NSEQ + n];
        const float* row = hf + ((size_t)(b * NSEQ + n) << 9);
        a0 = fmaf(row[tid], wgt, a0);
        a1 = fmaf(row[tid + 256], wgt, a1);
    }
    part[((b * 32 + chunk) << 9) + tid] = a0;
    part[((b * 32 + chunk) << 9) + tid + 256] = a1;
}
__global__ __launch_bounds__(256) void pool_fin(const float* __restrict__ part, float* __restrict__ Mb,
                                                float* __restrict__ out) {
    int b = blockIdx.x, tid = threadIdx.x;
    float s0 = 0.f, s1 = 0.f;
    for (int ch = 0; ch < 32; ++ch) {
        s0 += part[((b * 32 + ch) << 9) + tid];
        s1 += part[((b * 32 + ch) << 9) + tid + 256];
    }
    Mb[b * 512 + tid] = s0; Mb[b * 512 + tid + 256] = s1;
    out[2 + ROWS + b * 512 + tid] = s0; out[2 + ROWS + b * 512 + tid + 256] = s1;
}
__global__ __launch_bounds__(256) void classifier_k(const float* __restrict__ Mb,
        const float* __restrict__ w1, const float* __restrict__ b1,
        const float* __restrict__ w2, const float* __restrict__ b2, float* __restrict__ out) {
    int b = blockIdx.x, tid = threadIdx.x;
    __shared__ float Ms[512];
    __shared__ float red[256];
    for (int c = tid; c < 512; c += 256) Ms[c] = Mb[b * 512 + c];
    __syncthreads();
    float acc = 0.f;
    for (int c = 0; c < 512; ++c) acc = fmaf(Ms[c], w1[tid * 512 + c], acc);
    acc += b1[tid];
    float hj = acc > 0.f ? acc : expm1f(acc);   // ELU alpha=1
    float s = blockReduceSum(hj * w2[tid], red);
    if (tid == 0) out[b] = s + b2[0];
}

extern "C" void kernel_launch(void* const* d_in, const int* in_sizes, int n_in,
                              void* d_out, int out_size, void* d_ws, size_t ws_size,
                              hipStream_t stream)
{
    const float* X      = (const float*)d_in[0];
    const float* Wstart = (const float*)d_in[1];
    const float* Bstart = (const float*)d_in[2];
    const float* GluW   = (const float*)d_in[3];
    const float* GluB   = (const float*)d_in[4];
    const float* GcnW   = (const float*)d_in[5];
    const float* GcnB   = (const float*)d_in[6];
    const float* GcnG   = (const float*)d_in[7];
    const float* GcnBe  = (const float*)d_in[8];
    const float* QkvW   = (const float*)d_in[9];
    const float* QkvB   = (const float*)d_in[10];
    const float* OutW   = (const float*)d_in[11];
    const float* OutB   = (const float*)d_in[12];
    const float* Ln1G   = (const float*)d_in[13];
    const float* Ln1B   = (const float*)d_in[14];
    const float* Ffn1W  = (const float*)d_in[15];
    const float* Ffn1B  = (const float*)d_in[16];
    const float* Ffn2W  = (const float*)d_in[17];
    const float* Ffn2B  = (const float*)d_in[18];
    const float* Ln2G   = (const float*)d_in[19];
    const float* Ln2B   = (const float*)d_in[20];
    const float* FusW   = (const float*)d_in[21];
    const float* FusB   = (const float*)d_in[22];
    const float* AW1    = (const float*)d_in[23];
    const float* AB1    = (const float*)d_in[24];
    const float* AW2    = (const float*)d_in[25];
    const float* AB2    = (const float*)d_in[26];
    const float* CW1    = (const float*)d_in[27];
    const float* CB1    = (const float*)d_in[28];
    const float* CW2    = (const float*)d_in[29];
    const float* CB2    = (const float*)d_in[30];
    float* out = (float*)d_out;

    if (ws_size < 86 * MB) return;

    char* w = (char*)d_ws;
    // bf16 weight arena [0,13MB)
    short* Wb = (short*)w;
    short* wbStart = Wb;
    short* wbGlu   = Wb + 524288;
    short* wbGcn   = Wb + 1048576;
    short* wbQkv   = Wb + 1572864;
    short* wbOut   = Wb + 3145728;
    short* wbFfn1  = Wb + 3670016;
    short* wbFfn2  = Wb + 4718592;
    short* wbFus   = Wb + 5767168;
    short* wbAw1   = Wb + 6291456;
    // small [13MB,14MB)
    float* sq   = (float*)(w + 13 * MB);
    int*   idx  = (int*)  (w + 13 * MB + (16u << 10));
    float* srow = (float*)(w + 13 * MB + (176u << 10));
    float* afb  = (float*)(w + 13 * MB + (192u << 10));
    float* Mbuf = (float*)(w + 13 * MB + (208u << 10));
    float* part = (float*)(w + 13 * MB + (212u << 10));
    // overlapped big buffers
    short* Xbf  = (short*)(w + 14 * MB);   // 8MB (dead after fc_start)
    short* hpreb= (short*)(w + 22 * MB);   // 4MB -> hgb after GLU gemm
    short* hgb  = (short*)(w + 22 * MB);   // 4MB bf16 GCN residual state
    float* big  = (float*)(w + 26 * MB);   // 26..42MB: vg/D2a/gcn-s/Opb/out-proj
    short* Opb  = (short*)(w + 26 * MB);   // 16MB: 4 splits (bf16 O-partials)
    float* hf   = (float*)(w + 26 * MB);   // 8MB f32 fusion out (big dead by then)
    float* Ml   = (float*)(w + 42 * MB);   // 1MB (dead ffn2o window during attn)
    float* ffn2o= (float*)(w + 42 * MB);   // 8MB
    short* hhi  = (short*)(w + 58 * MB);   // 4MB bf16 (GLU out, lives to fusion)
    short* hlo  = (short*)(w + 62 * MB);   // 4MB; dead after gram -> htb
    short* htb  = (short*)(w + 62 * MB);   // 4MB bf16 transformer state
    float* D2b1 = (float*)(w + 66 * MB);   // 16MB (KNN phase only)
    short* hfb  = (short*)(w + 66 * MB);   // 4MB
    short* aob  = (short*)(w + 70 * MB);   // 4MB; -> t256 (pool)
    float* t256 = (float*)(w + 70 * MB);
    short* Qb   = (short*)(w + 74 * MB);   // 4MB  (OUTMODE=3: K=Qb+4MB, Vt=Qb+8MB)
    short* Kb   = (short*)(w + 78 * MB);   // 4MB
    short* Vt   = (short*)(w + 82 * MB);   // 4MB (transposed V, written by qkv GEMM)
    short* ffb  = (short*)(w + 74 * MB);   // 8MB (ffn1 out; Qb/Kb dead)

    dim3 blk(256);

    // convert X + all GEMM weights to bf16
    CvtArgs ca;
    ca.src[0] = X;     ca.dst[0] = Xbf;     ca.n4[0] = ROWS * 1024 / 4;
    ca.src[1] = Wstart;ca.dst[1] = wbStart; ca.n4[1] = 524288 / 4;
    ca.src[2] = GluW;  ca.dst[2] = wbGlu;   ca.n4[2] = 524288 / 4;
    ca.src[3] = GcnW;  ca.dst[3] = wbGcn;   ca.n4[3] = 524288 / 4;
    ca.src[4] = QkvW;  ca.dst[4] = wbQkv;   ca.n4[4] = 1572864 / 4;
    ca.src[5] = OutW;  ca.dst[5] = wbOut;   ca.n4[5] = 524288 / 4;
    ca.src[6] = Ffn1W; ca.dst[6] = wbFfn1;  ca.n4[6] = 1048576 / 4;
    ca.src[7] = Ffn2W; ca.dst[7] = wbFfn2;  ca.n4[7] = 1048576 / 4;
    ca.src[8] = FusW;  ca.dst[8] = wbFus;   ca.n4[8] = 524288 / 4;
    ca.src[9] = AW1;   ca.dst[9] = wbAw1;   ca.n4[9] = 131072 / 4;
    cvt_k<<<dim3(256, 10), blk, 0, stream>>>(ca);

    // fc_start -> GLU (fused rowsq)
    mfma_gemm<1, 0><<<dim3(8, 64), blk, 0, stream>>>(Xbf, nullptr, wbStart, Bstart, nullptr, hpreb, ROWS, 512, 1024);
    mfma_gemm<0, 0><<<dim3(16, 64), blk, 0, stream>>>(hpreb, nullptr, wbGlu, GluB, big, nullptr, ROWS, 1024, 512);
    glu_row_k<<<dim3(ROWS), blk, 0, stream>>>(big, hhi, hlo, sq);

    // KNN graph: both batches in single gram + single topk dispatch
    mfma_gram<<<dim3(32, 32, 2), blk, 0, stream>>>(hhi, hlo, sq, big, D2b1);
    topk9_k<<<dim3(ROWS), blk, 0, stream>>>(big, D2b1, idx);

    // GCN branch (bf16 residual state: hhi -> hgb -> hgb)
    const short* gA = hhi;
    const short* gR = hhi;
    for (int i = 0; i < 2; ++i) {
        mfma_gemm<0, 0><<<dim3(8, 64), blk, 0, stream>>>(gA, nullptr, wbGcn + (size_t)i * 262144,
                                                         GcnB + i * 512, big, nullptr, ROWS, 512, 512);
        gcn_post<<<dim3(ROWS), blk, 0, stream>>>(big, idx, GcnG + i * 512, GcnBe + i * 512, gR, hgb);
        gA = hgb; gR = hgb;
    }

    // Transformer branch (bf16 state: hhi -> htb -> ... -> htb)
    const short* tA = hhi;
    for (int i = 0; i < 2; ++i) {
        mfma_gemm<3, 0><<<dim3(24, 64), blk, 0, stream>>>(tA, nullptr, wbQkv + (size_t)i * 786432,
                                                          QkvB + i * 1536, nullptr, Qb, ROWS, 1536, 512);
        flash_attn<<<dim3(32, 4, 16), blk, 0, stream>>>(Qb, Kb, Vt, Opb, Ml);
        merge_k<<<dim3(8192), blk, 0, stream>>>(Opb, Ml, aob);
        mfma_gemm<0, 0><<<dim3(8, 64), blk, 0, stream>>>(aob, nullptr, wbOut + (size_t)i * 262144,
                                                         OutB + i * 512, big, nullptr, ROWS, 512, 512);
        ln_res<<<dim3(ROWS), blk, 0, stream>>>(tA, big, Ln1G + i * 512, Ln1B + i * 512, htb);
        mfma_gemm<4, 0><<<dim3(16, 64), blk, 0, stream>>>(htb, nullptr, wbFfn1 + (size_t)i * 524288,
                                                          Ffn1B + i * 1024, nullptr, ffb, ROWS, 1024, 512);
        mfma_gemm<0, 0><<<dim3(8, 64), blk, 0, stream>>>(ffb, nullptr, wbFfn2 + (size_t)i * 524288,
                                                         Ffn2B + i * 512, ffn2o, nullptr, ROWS, 512, 1024);
        ln_res<<<dim3(ROWS), blk, 0, stream>>>(htb, ffn2o, Ln2G + i * 512, Ln2B + i * 512, htb);
        tA = htb;
    }

    // fusion: A = concat(hgb, htb) read directly by CAT GEMM; hf at 26MB (no overlap)
    mfma_gemm<2, 1><<<dim3(8, 64), blk, 0, stream>>>(hgb, htb, wbFus, FusB, hf, hfb, ROWS, 512, 1024);

    // gated attention pooling (tanh fused into GEMM)
    mfma_gemm<5, 0><<<dim3(4, 64), blk, 0, stream>>>(hfb, nullptr, wbAw1, AB1, t256, nullptr, ROWS, 256, 512);
    rowdot_k<<<dim3(ROWS), blk, 0, stream>>>(t256, AW2, AB2, srow);
    softmax_n_k<<<dim3(2), blk, 0, stream>>>(srow, afb, out);
    pool_part<<<dim3(32, 2), blk, 0, stream>>>(hf, afb, part);
    pool_fin<<<dim3(2), blk, 0, stream>>>(part, Mbuf, out);

    // classifier
    classifier_k<<<dim3(2), blk, 0, stream>>>(Mbuf, CW1, CB1, CW2, CB2, out);
}

// Round 16
// 397.128 us; speedup vs baseline: 1.2720x; 1.0327x over previous
//
#include <hip/hip_runtime.h>
#include <hip/hip_bf16.h>
#include <math.h>

#define NSEQ 2048
#define ROWS 4096   // B*N
#define KNN 9
#define MB (1ull << 20)

typedef short bh8 __attribute__((ext_vector_type(8)));   // 8 bf16 in 4 VGPRs
typedef float f4v __attribute__((ext_vector_type(4)));
typedef unsigned long long u64k;

__device__ __forceinline__ short f2bf(float f) {
    union { float f; unsigned u; } v; v.f = f;
    unsigned r = (v.u + 0x7fffu + ((v.u >> 16) & 1u)) >> 16;
    return (short)r;
}
__device__ __forceinline__ float b2f(short s) {
    union { unsigned u; float f; } v; v.u = ((unsigned)(unsigned short)s) << 16; return v.f;
}

// async global->LDS, 16B per lane; LDS dest is wave-uniform base + lane*16
__device__ __forceinline__ void gload16(const void* g, void* l) {
    __builtin_amdgcn_global_load_lds(
        (const __attribute__((address_space(1))) void*)g,
        (__attribute__((address_space(3))) void*)l, 16, 0, 0);
}

// ---------- block reduce (blockDim.x == 256) ----------
__device__ __forceinline__ float blockReduceSum(float v, float* red) {
    int tid = threadIdx.x;
    red[tid] = v; __syncthreads();
    for (int s = 128; s > 0; s >>= 1) {
        if (tid < s) red[tid] += red[tid + s];
        __syncthreads();
    }
    float r = red[0]; __syncthreads();
    return r;
}

// ---------- f32 -> bf16 conversion (weights + X), 10 segments ----------
struct CvtArgs { const float* src[10]; short* dst[10]; int n4[10]; };
__global__ __launch_bounds__(256) void cvt_k(CvtArgs a) {
    int s = blockIdx.y;
    const float* sp = a.src[s]; short* dp = a.dst[s]; int n = a.n4[s];
    for (int i = blockIdx.x * 256 + threadIdx.x; i < n; i += gridDim.x * 256) {
        float4 v = ((const float4*)sp)[i];
        short4 o; o.x = f2bf(v.x); o.y = f2bf(v.y); o.z = f2bf(v.z); o.w = f2bf(v.w);
        ((short4*)dp)[i] = o;
    }
}

// ---------- shared epilogue writer ----------
template <int OUTMODE>
__device__ __forceinline__ void gemm_epilogue(int row, int col, int N, const f4v& a,
        float bv, float* Cf, short* Cb, short* Kb_, short* Vt_)
{
    if (OUTMODE == 3) {
        int b = row >> 11, n0 = row & 2047;
        if (col < 512) {
            int h = col >> 6, d = col & 63;
            size_t base = (((size_t)(b * 8 + h) * NSEQ + n0) << 6) + d;
            #pragma unroll
            for (int rr = 0; rr < 4; ++rr)
                Cb[base + ((size_t)rr << 6)] = f2bf((a[rr] + bv) * 0.18033688f);
        } else if (col < 1024) {
            int cc = col - 512, h = cc >> 6, d = cc & 63;
            size_t base = (((size_t)(b * 8 + h) * NSEQ + n0) << 6) + d;
            #pragma unroll
            for (int rr = 0; rr < 4; ++rr)
                Kb_[base + ((size_t)rr << 6)] = f2bf(a[rr] + bv);
        } else {
            int cc = col - 1024, h = cc >> 6, d = cc & 63;
            short4 ov;
            ov.x = f2bf(a[0] + bv); ov.y = f2bf(a[1] + bv);
            ov.z = f2bf(a[2] + bv); ov.w = f2bf(a[3] + bv);
            *(short4*)(Vt_ + (((size_t)((b * 8 + h) * 64 + d)) << 11) + n0) = ov;
        }
    } else {
        #pragma unroll
        for (int rr = 0; rr < 4; ++rr) {
            float v = a[rr] + bv;
            if (OUTMODE == 0) Cf[(size_t)(row + rr) * N + col] = v;
            else if (OUTMODE == 1) Cb[(size_t)(row + rr) * N + col] = f2bf(v);
            else if (OUTMODE == 2) {
                Cf[(size_t)(row + rr) * N + col] = v;
                Cb[(size_t)(row + rr) * N + col] = f2bf(v);
            } else if (OUTMODE == 4) {
                Cb[(size_t)(row + rr) * N + col] = f2bf(0.5f * v * (1.f + erff(v * 0.70710678118654752f)));
            } else if (OUTMODE == 5) {
                Cf[(size_t)(row + rr) * N + col] = tanhf(v);
            }
        }
    }
}

// ---------- MFMA GEMM 64x64 tile, dbuf prefetch, swizzled LDS ----------
// CAT=1: A is logically [M,1024] = concat(A[.,0:512], A2[.,0:512]) per row.
template <int OUTMODE, int CAT>
__global__ __launch_bounds__(256) void mfma_gemm(
        const short* __restrict__ A, const short* __restrict__ A2,
        const short* __restrict__ W,
        const float* __restrict__ bias, float* __restrict__ Cf, short* __restrict__ Cb,
        int M, int N, int K)
{
    __shared__ short As[2][64 * 64];
    __shared__ short Bs[2][64 * 64];
    int tid = threadIdx.x;
    int wv = tid >> 6, l = tid & 63;
    int g = l >> 4, c = l & 15;
    int wr = wv >> 1, wc = wv & 1;
    int bm = blockIdx.y * 64, bn = blockIdx.x * 64;
    int sr = l >> 3, sc = ((l & 7) ^ sr) * 8;
    int arow = bm + wv * 16 + sr;
    size_t astr = CAT ? 512 : (size_t)K;
    const short* Ap  = A  + (size_t)arow * astr + sc;
    const short* Ap2 = CAT ? (A2 + (size_t)arow * 512 + sc) : nullptr;
    const short* Wp = W + (size_t)(bn + wv * 16 + sr) * K + sc;
    int ldsB = (wv * 16) * 64;

    #define GSTAGE(buf, k0) { \
        const short* ab_ = (CAT && (k0) >= 512) ? (Ap2 + (k0) - 512) : (Ap + (k0)); \
        gload16(ab_, &As[buf][ldsB]); \
        gload16(ab_ + 8 * astr, &As[buf][ldsB + 8 * 64]); \
        gload16(Wp + (k0), &Bs[buf][ldsB]); \
        gload16(Wp + (size_t)8 * K + (k0), &Bs[buf][ldsB + 8 * 64]); }

    f4v acc[2][2] = {};
    GSTAGE(0, 0);
    __syncthreads();
    int nk = K >> 6;
    for (int t = 0; t < nk; ++t) {
        int cur = t & 1;
        if (t + 1 < nk) GSTAGE(cur ^ 1, (t + 1) << 6);
        #pragma unroll
        for (int ks = 0; ks < 2; ++ks) {
            bh8 af[2], bf_[2];
            #pragma unroll
            for (int mi = 0; mi < 2; ++mi) {
                int row = wr * 32 + mi * 16 + c;
                af[mi] = *(const bh8*)(&As[cur][row * 64 + (((ks * 4 + g) ^ (c & 7)) * 8)]);
            }
            #pragma unroll
            for (int ni = 0; ni < 2; ++ni) {
                int row = wc * 32 + ni * 16 + c;
                bf_[ni] = *(const bh8*)(&Bs[cur][row * 64 + (((ks * 4 + g) ^ (c & 7)) * 8)]);
            }
            #pragma unroll
            for (int mi = 0; mi < 2; ++mi)
                #pragma unroll
                for (int ni = 0; ni < 2; ++ni)
                    acc[mi][ni] = __builtin_amdgcn_mfma_f32_16x16x32_bf16(af[mi], bf_[ni], acc[mi][ni], 0, 0, 0);
        }
        __syncthreads();
    }
    #undef GSTAGE
    short* Kb_ = (OUTMODE == 3) ? Cb + 2097152 : nullptr;
    short* Vt_ = (OUTMODE == 3) ? Cb + 4194304 : nullptr;
    #pragma unroll
    for (int mi = 0; mi < 2; ++mi) {
        int row = bm + wr * 32 + mi * 16 + g * 4;
        #pragma unroll
        for (int ni = 0; ni < 2; ++ni) {
            int col = bn + wc * 32 + ni * 16 + c;
            gemm_epilogue<OUTMODE>(row, col, N, acc[mi][ni], bias[col], Cf, Cb, Kb_, Vt_);
        }
    }
}

// ---------- dual GEMM: sub-A = GCN scores (N=512, f32), sub-B = QKV (N=1536, mode3) ----------
// grid (8+24, 64). Both K=512, M=4096. bx<8 -> GCN; bx>=8 -> QKV (bn=(bx-8)*64).
__global__ __launch_bounds__(256) void dual_gemm(
        const short* __restrict__ Aa, const short* __restrict__ Wa,
        const float* __restrict__ biasa, float* __restrict__ Cfa,
        const short* __restrict__ Ab, const short* __restrict__ Wb,
        const float* __restrict__ biasb, short* __restrict__ Cbq)
{
    __shared__ short As[2][64 * 64];
    __shared__ short Bs[2][64 * 64];
    int tid = threadIdx.x;
    int wv = tid >> 6, l = tid & 63;
    int g = l >> 4, c = l & 15;
    int wr = wv >> 1, wc = wv & 1;
    bool isA = blockIdx.x < 8;
    int bn = (isA ? blockIdx.x : (blockIdx.x - 8)) * 64;
    int bm = blockIdx.y * 64;
    const short* A = isA ? Aa : Ab;
    const short* W = isA ? Wa : Wb;
    const float* bias = isA ? biasa : biasb;
    int sr = l >> 3, sc = ((l & 7) ^ sr) * 8;
    const short* Ap = A + (size_t)(bm + wv * 16 + sr) * 512 + sc;
    const short* Wp = W + (size_t)(bn + wv * 16 + sr) * 512 + sc;
    int ldsB = (wv * 16) * 64;

    #define GSTAGE(buf, k0) { \
        gload16(Ap + (k0), &As[buf][ldsB]); \
        gload16(Ap + (size_t)8 * 512 + (k0), &As[buf][ldsB + 8 * 64]); \
        gload16(Wp + (k0), &Bs[buf][ldsB]); \
        gload16(Wp + (size_t)8 * 512 + (k0), &Bs[buf][ldsB + 8 * 64]); }

    f4v acc[2][2] = {};
    GSTAGE(0, 0);
    __syncthreads();
    for (int t = 0; t < 8; ++t) {
        int cur = t & 1;
        if (t + 1 < 8) GSTAGE(cur ^ 1, (t + 1) << 6);
        #pragma unroll
        for (int ks = 0; ks < 2; ++ks) {
            bh8 af[2], bf_[2];
            #pragma unroll
            for (int mi = 0; mi < 2; ++mi) {
                int row = wr * 32 + mi * 16 + c;
                af[mi] = *(const bh8*)(&As[cur][row * 64 + (((ks * 4 + g) ^ (c & 7)) * 8)]);
            }
            #pragma unroll
            for (int ni = 0; ni < 2; ++ni) {
                int row = wc * 32 + ni * 16 + c;
                bf_[ni] = *(const bh8*)(&Bs[cur][row * 64 + (((ks * 4 + g) ^ (c & 7)) * 8)]);
            }
            #pragma unroll
            for (int mi = 0; mi < 2; ++mi)
                #pragma unroll
                for (int ni = 0; ni < 2; ++ni)
                    acc[mi][ni] = __builtin_amdgcn_mfma_f32_16x16x32_bf16(af[mi], bf_[ni], acc[mi][ni], 0, 0, 0);
        }
        __syncthreads();
    }
    #undef GSTAGE
    #pragma unroll
    for (int mi = 0; mi < 2; ++mi) {
        int row = bm + wr * 32 + mi * 16 + g * 4;
        #pragma unroll
        for (int ni = 0; ni < 2; ++ni) {
            int col = bn + wc * 32 + ni * 16 + c;
            if (isA)
                gemm_epilogue<0>(row, col, 512, acc[mi][ni], bias[col], Cfa, nullptr, nullptr, nullptr);
            else
                gemm_epilogue<3>(row, col, 1536, acc[mi][ni], bias[col], nullptr, Cbq,
                                 Cbq + 2097152, Cbq + 4194304);
        }
    }
}

// ---------- gram for KNN distances, hi/lo split, batched over z (2 batches) ----------
__global__ __launch_bounds__(256) void mfma_gram(
        const short* __restrict__ Hi0, const short* __restrict__ Lo0,
        const float* __restrict__ SQ0, float* __restrict__ D2a, float* __restrict__ D2b)
{
    __shared__ short HiR[64 * 64], LoR[64 * 64], HiC[64 * 64], LoC[64 * 64];
    int tid = threadIdx.x;
    int bz = blockIdx.z;
    const short* Hi = Hi0 + (size_t)bz * NSEQ * 512;
    const short* Lo = Lo0 + (size_t)bz * NSEQ * 512;
    const float* SQ = SQ0 + bz * NSEQ;
    float* D2 = bz ? D2b : D2a;
    int wv = tid >> 6, l = tid & 63;
    int g = l >> 4, c = l & 15;
    int wr = wv >> 1, wc = wv & 1;
    int bm = blockIdx.y * 64, bn = blockIdx.x * 64;
    int sr = l >> 3, sc = ((l & 7) ^ sr) * 8;
    const short* hiR = Hi + (size_t)(bm + wv * 16 + sr) * 512 + sc;
    const short* loR = Lo + (size_t)(bm + wv * 16 + sr) * 512 + sc;
    const short* hiC = Hi + (size_t)(bn + wv * 16 + sr) * 512 + sc;
    const short* loC = Lo + (size_t)(bn + wv * 16 + sr) * 512 + sc;
    int ldsOff = (wv * 16) * 64;
    f4v acc[2][2] = {};
    for (int k0 = 0; k0 < 512; k0 += 64) {
        __syncthreads();
        gload16(hiR + k0, HiR + ldsOff);
        gload16(hiR + (size_t)8 * 512 + k0, HiR + ldsOff + 8 * 64);
        gload16(loR + k0, LoR + ldsOff);
        gload16(loR + (size_t)8 * 512 + k0, LoR + ldsOff + 8 * 64);
        gload16(hiC + k0, HiC + ldsOff);
        gload16(hiC + (size_t)8 * 512 + k0, HiC + ldsOff + 8 * 64);
        gload16(loC + k0, LoC + ldsOff);
        gload16(loC + (size_t)8 * 512 + k0, LoC + ldsOff + 8 * 64);
        __syncthreads();
        #pragma unroll
        for (int ks = 0; ks < 2; ++ks) {
            bh8 hr[2], lr_[2], hc[2], lc[2];
            #pragma unroll
            for (int mi = 0; mi < 2; ++mi) {
                int o = (wr * 32 + mi * 16 + c) * 64 + (((ks * 4 + g) ^ (c & 7)) * 8);
                hr[mi] = *(const bh8*)(HiR + o);
                lr_[mi] = *(const bh8*)(LoR + o);
            }
            #pragma unroll
            for (int ni = 0; ni < 2; ++ni) {
                int o = (wc * 32 + ni * 16 + c) * 64 + (((ks * 4 + g) ^ (c & 7)) * 8);
                hc[ni] = *(const bh8*)(HiC + o);
                lc[ni] = *(const bh8*)(LoC + o);
            }
            #pragma unroll
            for (int mi = 0; mi < 2; ++mi)
                #pragma unroll
                for (int ni = 0; ni < 2; ++ni) {
                    acc[mi][ni] = __builtin_amdgcn_mfma_f32_16x16x32_bf16(hr[mi], hc[ni], acc[mi][ni], 0, 0, 0);
                    acc[mi][ni] = __builtin_amdgcn_mfma_f32_16x16x32_bf16(hr[mi], lc[ni], acc[mi][ni], 0, 0, 0);
                    acc[mi][ni] = __builtin_amdgcn_mfma_f32_16x16x32_bf16(lr_[mi], hc[ni], acc[mi][ni], 0, 0, 0);
                }
        }
    }
    #pragma unroll
    for (int mi = 0; mi < 2; ++mi) {
        int row = bm + wr * 32 + mi * 16 + g * 4;
        #pragma unroll
        for (int ni = 0; ni < 2; ++ni) {
            int col = bn + wc * 32 + ni * 16 + c;
            float sqc = SQ[col];
            #pragma unroll
            for (int rr = 0; rr < 4; ++rr)
                D2[(size_t)(row + rr) * NSEQ + col] = SQ[row + rr] + sqc - 2.f * acc[mi][ni][rr];
        }
    }
}

// ---------- top-9 smallest per row (both batches in one grid of 4096) ----------
__global__ __launch_bounds__(256) void topk9_k(const float* __restrict__ D2a,
                                               const float* __restrict__ D2b, int* __restrict__ idx)
{
    int ng = blockIdx.x, tid = threadIdx.x;
    const float* D2 = (ng >> 11) ? D2b : D2a;
    int n = ng & 2047;
    __shared__ u64k lists[256][9];
    u64k a[8];
    union { float f; unsigned u; } cv;
    #pragma unroll
    for (int j = 0; j < 8; ++j) {
        int mcol = tid + j * 256;
        cv.f = fmaxf(D2[(size_t)n * NSEQ + mcol], 0.f);
        a[j] = ((u64k)cv.u << 32) | (unsigned)mcol;
    }
    #define CE(i,j) { u64k x = a[i], y = a[j]; bool t = x < y; a[i] = t ? x : y; a[j] = t ? y : x; }
    CE(0,1) CE(2,3) CE(4,5) CE(6,7)
    CE(0,2) CE(1,3) CE(4,6) CE(5,7)
    CE(1,2) CE(5,6)
    CE(0,4) CE(1,5) CE(2,6) CE(3,7)
    CE(2,4) CE(3,5)
    CE(1,2) CE(3,4) CE(5,6)
    #undef CE
    #pragma unroll
    for (int j = 0; j < 8; ++j) lists[tid][j] = a[j];
    lists[tid][8] = ~0ull;
    __syncthreads();
    for (int s = 128; s >= 1; s >>= 1) {
        if (tid < s) {
            u64k out[9];
            u64k* Al = lists[tid];
            u64k* Bl = lists[tid + s];
            int ia = 0, ib = 0;
            #pragma unroll
            for (int o = 0; o < 9; ++o) {
                u64k av = Al[ia], bv = Bl[ib];
                bool t = av <= bv;
                out[o] = t ? av : bv;
                ia += t; ib += !t;
            }
            #pragma unroll
            for (int o = 0; o < 9; ++o) Al[o] = out[o];
        }
        __syncthreads();
    }
    if (tid < 9) idx[ng * KNN + tid] = (int)(lists[0][tid] & 0xffffffffu);
}

// ---------- GCN aggregate + LN + leaky + residual (bf16 residual state) ----------
__global__ __launch_bounds__(256) void gcn_post(
        const float* __restrict__ s, const int* __restrict__ idx,
        const float* __restrict__ g, const float* __restrict__ be,
        const short* __restrict__ rin, short* __restrict__ rout)
{
    int row = blockIdx.x, tid = threadIdx.x;
    int bb = row >> 11;
    __shared__ float os[512];
    __shared__ float red[256];
    int id[KNN];
    #pragma unroll
    for (int j = 0; j < KNN; ++j) id[j] = idx[row * KNN + j] + (bb << 11);
    for (int c = tid; c < 512; c += 256) {
        float acc = 0.f;
        #pragma unroll
        for (int j = 0; j < KNN; ++j) acc += s[((size_t)id[j] << 9) + c];
        os[c] = acc * (1.f / 9.f);
    }
    __syncthreads();
    float mean = blockReduceSum(os[tid] + os[tid + 256], red) * (1.f / 512.f);
    float d0 = os[tid] - mean, d1 = os[tid + 256] - mean;
    float var = blockReduceSum(d0 * d0 + d1 * d1, red) * (1.f / 512.f);
    float rs = rsqrtf(var + 1e-5f);
    size_t base = (size_t)row << 9;
    for (int c = tid; c < 512; c += 256) {
        float y = (os[c] - mean) * rs * g[c] + be[c];
        y = y > 0.f ? y : 0.2f * y;
        rout[base + c] = f2bf(y + b2f(rin[base + c]));
    }
}

// ---------- xout = LN(xin + r)*g + b (bf16 state, f32 r) ----------
__global__ __launch_bounds__(256) void ln_res(
        const short* __restrict__ xin, const float* __restrict__ r,
        const float* __restrict__ g, const float* __restrict__ b, short* __restrict__ xout)
{
    int row = blockIdx.x, tid = threadIdx.x;
    __shared__ float xs[512];
    __shared__ float red[256];
    size_t base = (size_t)row << 9;
    for (int c = tid; c < 512; c += 256) xs[c] = b2f(xin[base + c]) + r[base + c];
    __syncthreads();
    float mean = blockReduceSum(xs[tid] + xs[tid + 256], red) * (1.f / 512.f);
    float d0 = xs[tid] - mean, d1 = xs[tid + 256] - mean;
    float var = blockReduceSum(d0 * d0 + d1 * d1, red) * (1.f / 512.f);
    float rs = rsqrtf(var + 1e-5f);
    for (int c = tid; c < 512; c += 256)
        xout[base + c] = f2bf((xs[c] - mean) * rs * g[c] + b[c]);
}

// ---------- flash attention: swapped-operand, KV-split=4, K+V LDS dbuf ----------
__global__ __launch_bounds__(256) void flash_attn(
        const short* __restrict__ Qb, const short* __restrict__ Kb,
        const short* __restrict__ Vt, short* __restrict__ Opb, float* __restrict__ Ml)
{
    __shared__ short Ks[2][4096];
    __shared__ short Vs[2][4096];
    int tid = threadIdx.x;
    int wid = tid >> 6, lane = tid & 63;
    int g = lane >> 4, c = lane & 15;
    int s = blockIdx.y, bh = blockIdx.z;
    int q0 = blockIdx.x * 64 + wid * 16;
    int srow = lane >> 3;
    int sc8 = ((lane & 7) ^ srow) * 8;
    int w8 = wid * 8;

    const short* KbB = Kb + ((size_t)bh * NSEQ + s * 512) * 64;
    const short* VtB = Vt + (size_t)bh * 64 * NSEQ + s * 512;

    const short* qbase = Qb + ((size_t)bh * NSEQ + q0 + c) * 64 + g * 8;
    bh8 qa0 = *(const bh8*)(qbase);
    bh8 qa1 = *(const bh8*)(qbase + 32);

    f4v o0 = {0,0,0,0}, o1 = {0,0,0,0}, o2 = {0,0,0,0}, o3 = {0,0,0,0};
    float lloc = 0.f;
    float mrun = -INFINITY;
    int hi2 = g >> 1;
    int s1 = c + (((g << 1) & 3) << 4);
    int s2 = c + ((((g << 1) + 1) & 3) << 4);

    #define FSTAGE(buf, kt) { \
        const short* kp_ = KbB + (size_t)(kt) * 64 * 64; \
        gload16(kp_ + (size_t)(w8 + srow) * 64 + sc8,        &Ks[buf][w8 * 64]); \
        gload16(kp_ + (size_t)(32 + w8 + srow) * 64 + sc8,   &Ks[buf][(32 + w8) * 64]); \
        const short* vp_ = VtB + (size_t)(kt) * 64; \
        gload16(vp_ + (size_t)(w8 + srow) * NSEQ + sc8,      &Vs[buf][w8 * 64]); \
        gload16(vp_ + (size_t)(32 + w8 + srow) * NSEQ + sc8, &Vs[buf][(32 + w8) * 64]); }

    FSTAGE(0, 0);
    __syncthreads();
    for (int t = 0; t < 8; ++t) {
        int cur = t & 1;
        if (t < 7) FSTAGE(cur ^ 1, t + 1);
        f4v sv[4];
        #pragma unroll
        for (int cb = 0; cb < 4; ++cb) {
            int row = cb * 16 + c;
            const short* kr = &Ks[cur][row * 64];
            bh8 kb0 = *(const bh8*)(kr + ((g ^ (row & 7)) * 8));
            bh8 kb1 = *(const bh8*)(kr + (((4 + g) ^ (row & 7)) * 8));
            f4v a = {0,0,0,0};
            a = __builtin_amdgcn_mfma_f32_16x16x32_bf16(kb0, qa0, a, 0, 0, 0);
            a = __builtin_amdgcn_mfma_f32_16x16x32_bf16(kb1, qa1, a, 0, 0, 0);
            sv[cb] = a;
        }
        float mt = fmaxf(fmaxf(fmaxf(sv[0][0], sv[0][1]), fmaxf(sv[0][2], sv[0][3])),
                         fmaxf(fmaxf(sv[1][0], sv[1][1]), fmaxf(sv[1][2], sv[1][3])));
        mt = fmaxf(mt, fmaxf(fmaxf(sv[2][0], sv[2][1]), fmaxf(sv[2][2], sv[2][3])));
        mt = fmaxf(mt, fmaxf(fmaxf(sv[3][0], sv[3][1]), fmaxf(sv[3][2], sv[3][3])));
        mt = fmaxf(mt, __shfl_xor(mt, 16));
        mt = fmaxf(mt, __shfl_xor(mt, 32));
        if (__any(mt > mrun + 6.f)) {
            float mn = fmaxf(mrun, mt);
            float al = __builtin_amdgcn_exp2f(mrun - mn);
            mrun = mn;
            o0 *= al; o1 *= al; o2 *= al; o3 *= al; lloc *= al;
        }
        unsigned wv_[8];
        #pragma unroll
        for (int cb = 0; cb < 4; ++cb) {
            float p0 = __builtin_amdgcn_exp2f(sv[cb][0] - mrun);
            float p1 = __builtin_amdgcn_exp2f(sv[cb][1] - mrun);
            float p2 = __builtin_amdgcn_exp2f(sv[cb][2] - mrun);
            float p3 = __builtin_amdgcn_exp2f(sv[cb][3] - mrun);
            lloc += (p0 + p1) + (p2 + p3);
            asm("v_cvt_pk_bf16_f32 %0, %1, %2" : "=v"(wv_[cb * 2])     : "v"(p0), "v"(p1));
            asm("v_cvt_pk_bf16_f32 %0, %1, %2" : "=v"(wv_[cb * 2 + 1]) : "v"(p2), "v"(p3));
        }
        union { unsigned u[4]; bh8 h; } pa0u, pa1u;
        {
            unsigned t0 = __shfl((int)wv_[0], s1), t2 = __shfl((int)wv_[2], s1);
            unsigned t1 = __shfl((int)wv_[1], s1), t3 = __shfl((int)wv_[3], s1);
            unsigned u0 = __shfl((int)wv_[0], s2), u2 = __shfl((int)wv_[2], s2);
            unsigned u1 = __shfl((int)wv_[1], s2), u3 = __shfl((int)wv_[3], s2);
            pa0u.u[0] = hi2 ? t2 : t0;
            pa0u.u[1] = hi2 ? t3 : t1;
            pa0u.u[2] = hi2 ? u2 : u0;
            pa0u.u[3] = hi2 ? u3 : u1;
        }
        {
            unsigned t0 = __shfl((int)wv_[4], s1), t2 = __shfl((int)wv_[6], s1);
            unsigned t1 = __shfl((int)wv_[5], s1), t3 = __shfl((int)wv_[7], s1);
            unsigned u0 = __shfl((int)wv_[4], s2), u2 = __shfl((int)wv_[6], s2);
            unsigned u1 = __shfl((int)wv_[5], s2), u3 = __shfl((int)wv_[7], s2);
            pa1u.u[0] = hi2 ? t2 : t0;
            pa1u.u[1] = hi2 ? t3 : t1;
            pa1u.u[2] = hi2 ? u2 : u0;
            pa1u.u[3] = hi2 ? u3 : u1;
        }
        #pragma unroll
        for (int db = 0; db < 4; ++db) {
            int row = db * 16 + c;
            const short* vr = &Vs[cur][row * 64];
            bh8 vb0 = *(const bh8*)(vr + ((g ^ (row & 7)) * 8));
            bh8 vb1 = *(const bh8*)(vr + (((4 + g) ^ (row & 7)) * 8));
            f4v* op = (db == 0) ? &o0 : (db == 1) ? &o1 : (db == 2) ? &o2 : &o3;
            *op = __builtin_amdgcn_mfma_f32_16x16x32_bf16(vb0, pa0u.h, *op, 0, 0, 0);
            *op = __builtin_amdgcn_mfma_f32_16x16x32_bf16(vb1, pa1u.h, *op, 0, 0, 0);
        }
        __syncthreads();
    }
    #undef FSTAGE
    float lsum = lloc;
    lsum += __shfl_xor(lsum, 16);
    lsum += __shfl_xor(lsum, 32);
    size_t qrow = ((size_t)(s * 16 + bh) * NSEQ) + q0 + c;
    size_t rb = qrow * 64 + g * 4;
    #pragma unroll
    for (int r = 0; r < 4; ++r) {
        Opb[rb + r]      = f2bf(o0[r]);
        Opb[rb + 16 + r] = f2bf(o1[r]);
        Opb[rb + 32 + r] = f2bf(o2[r]);
        Opb[rb + 48 + r] = f2bf(o3[r]);
    }
    if (g == 0) {
        Ml[qrow * 2]     = mrun;
        Ml[qrow * 2 + 1] = lsum;
    }
}

// ---------- merge 4 KV-splits -> bf16 attention output (4 d's per thread) ----------
__global__ __launch_bounds__(256) void merge_k(const short* __restrict__ Opb, const float* __restrict__ Ml,
                                               short* __restrict__ aob)
{
    int idx = blockIdx.x * 256 + threadIdx.x;   // 16*2048*16
    int d4 = (idx & 15) * 4, q = (idx >> 4) & 2047, bh = idx >> 15;
    float M = -INFINITY;
    float mv[4], lv[4];
    #pragma unroll
    for (int s = 0; s < 4; ++s) {
        size_t r = (size_t)(s * 16 + bh) * NSEQ + q;
        mv[s] = Ml[r * 2]; lv[s] = Ml[r * 2 + 1];
        M = fmaxf(M, mv[s]);
    }
    float L = 0.f;
    float n0 = 0.f, n1 = 0.f, n2 = 0.f, n3 = 0.f;
    #pragma unroll
    for (int s = 0; s < 4; ++s) {
        float w = __builtin_amdgcn_exp2f(mv[s] - M);
        L += lv[s] * w;
        short4 ov = *(const short4*)(Opb + ((size_t)(s * 16 + bh) * NSEQ + q) * 64 + d4);
        n0 = fmaf(b2f(ov.x), w, n0);
        n1 = fmaf(b2f(ov.y), w, n1);
        n2 = fmaf(b2f(ov.z), w, n2);
        n3 = fmaf(b2f(ov.w), w, n3);
    }
    float inv = 1.f / L;
    int b = bh >> 3, h = bh & 7;
    short4 r4;
    r4.x = f2bf(n0 * inv); r4.y = f2bf(n1 * inv);
    r4.z = f2bf(n2 * inv); r4.w = f2bf(n3 * inv);
    *(short4*)(aob + ((size_t)(b * NSEQ + q)) * 512 + h * 64 + d4) = r4;
}

// ---------- GLU per-row: hi/lo split + fused row-sq ----------
__global__ __launch_bounds__(256) void glu_row_k(const float* __restrict__ vg,
        short* __restrict__ hi, short* __restrict__ lo, float* __restrict__ sq) {
    int row = blockIdx.x, tid = threadIdx.x;
    __shared__ float red[256];
    size_t vb = (size_t)row << 10;
    size_t hb = (size_t)row << 9;
    float ss = 0.f;
    #pragma unroll
    for (int j = 0; j < 2; ++j) {
        int c = tid + j * 256;
        float v = vg[vb + c], gt = vg[vb + 512 + c];
        float hv = v * (1.f / (1.f + __expf(-gt)));
        short hbb = f2bf(hv);
        hi[hb + c] = hbb;
        lo[hb + c] = f2bf(hv - b2f(hbb));
        ss = fmaf(hv, hv, ss);
    }
    float sm = blockReduceSum(ss, red);
    if (tid == 0) sq[row] = sm;
}

// ---------- pooling / classifier ----------
__global__ __launch_bounds__(256) void rowdot_k(const float* __restrict__ t, const float* __restrict__ w2,
                                                const float* __restrict__ b2, float* __restrict__ srow) {
    int row = blockIdx.x, tid = threadIdx.x;
    __shared__ float red[256];
    float s = blockReduceSum(t[(size_t)row * 256 + tid] * w2[tid], red);
    if (tid == 0) srow[row] = s + b2[0];
}
__global__ __launch_bounds__(256) void softmax_n_k(const float* __restrict__ srow, float* __restrict__ a,
                                                   float* __restrict__ out) {
    int b = blockIdx.x, tid = threadIdx.x;
    __shared__ float red[256];
    float mx = -INFINITY;
    for (int n = tid; n < NSEQ; n += 256) mx = fmaxf(mx, srow[b * NSEQ + n]);
    red[tid] = mx; __syncthreads();
    for (int s = 128; s > 0; s >>= 1) {
        if (tid < s) red[tid] = fmaxf(red[tid], red[tid + s]);
        __syncthreads();
    }
    mx = red[0]; __syncthreads();
    float sm = 0.f;
    for (int n = tid; n < NSEQ; n += 256) {
        float e = expf(srow[b * NSEQ + n] - mx);
        a[b * NSEQ + n] = e; sm += e;
    }
    float inv = 1.f / blockReduceSum(sm, red);
    for (int n = tid; n < NSEQ; n += 256) {
        float v = a[b * NSEQ + n] * inv;
        a[b * NSEQ + n] = v;
        out[2 + b * NSEQ + n] = v;
    }
}
__global__ __launch_bounds__(256) void pool_part(const float* __restrict__ hf, const float* __restrict__ a,
                                                 float* __restrict__ part) {
    int b = blockIdx.y, chunk = blockIdx.x, tid = threadIdx.x;
    float a0 = 0.f, a1 = 0.f;
    for (int r = 0; r < 64; ++r) {
        int n = chunk * 64 + r;
        float wgt = a[b * NSEQ + n];
        const float* row = hf + ((size_t)(b * NSEQ + n) << 9);
        a0 = fmaf(row[tid], wgt, a0);
        a1 = fmaf(row[tid + 256], wgt, a1);
    }
    part[((b * 32 + chunk) << 9) + tid] = a0;
    part[((b * 32 + chunk) << 9) + tid + 256] = a1;
}
__global__ __launch_bounds__(256) void pool_fin(const float* __restrict__ part, float* __restrict__ Mb,
                                                float* __restrict__ out) {
    int b = blockIdx.x, tid = threadIdx.x;
    float s0 = 0.f, s1 = 0.f;
    for (int ch = 0; ch < 32; ++ch) {
        s0 += part[((b * 32 + ch) << 9) + tid];
        s1 += part[((b * 32 + ch) << 9) + tid + 256];
    }
    Mb[b * 512 + tid] = s0; Mb[b * 512 + tid + 256] = s1;
    out[2 + ROWS + b * 512 + tid] = s0; out[2 + ROWS + b * 512 + tid + 256] = s1;
}
__global__ __launch_bounds__(256) void classifier_k(const float* __restrict__ Mb,
        const float* __restrict__ w1, const float* __restrict__ b1,
        const float* __restrict__ w2, const float* __restrict__ b2, float* __restrict__ out) {
    int b = blockIdx.x, tid = threadIdx.x;
    __shared__ float Ms[512];
    __shared__ float red[256];
    for (int c = tid; c < 512; c += 256) Ms[c] = Mb[b * 512 + c];
    __syncthreads();
    float acc = 0.f;
    for (int c = 0; c < 512; ++c) acc = fmaf(Ms[c], w1[tid * 512 + c], acc);
    acc += b1[tid];
    float hj = acc > 0.f ? acc : expm1f(acc);   // ELU alpha=1
    float s = blockReduceSum(hj * w2[tid], red);
    if (tid == 0) out[b] = s + b2[0];
}

extern "C" void kernel_launch(void* const* d_in, const int* in_sizes, int n_in,
                              void* d_out, int out_size, void* d_ws, size_t ws_size,
                              hipStream_t stream)
{
    const float* X      = (const float*)d_in[0];
    const float* Wstart = (const float*)d_in[1];
    const float* Bstart = (const float*)d_in[2];
    const float* GluW   = (const float*)d_in[3];
    const float* GluB   = (const float*)d_in[4];
    const float* GcnW   = (const float*)d_in[5];
    const float* GcnB   = (const float*)d_in[6];
    const float* GcnG   = (const float*)d_in[7];
    const float* GcnBe  = (const float*)d_in[8];
    const float* QkvW   = (const float*)d_in[9];
    const float* QkvB   = (const float*)d_in[10];
    const float* OutW   = (const float*)d_in[11];
    const float* OutB   = (const float*)d_in[12];
    const float* Ln1G   = (const float*)d_in[13];
    const float* Ln1B   = (const float*)d_in[14];
    const float* Ffn1W  = (const float*)d_in[15];
    const float* Ffn1B  = (const float*)d_in[16];
    const float* Ffn2W  = (const float*)d_in[17];
    const float* Ffn2B  = (const float*)d_in[18];
    const float* Ln2G   = (const float*)d_in[19];
    const float* Ln2B   = (const float*)d_in[20];
    const float* FusW   = (const float*)d_in[21];
    const float* FusB   = (const float*)d_in[22];
    const float* AW1    = (const float*)d_in[23];
    const float* AB1    = (const float*)d_in[24];
    const float* AW2    = (const float*)d_in[25];
    const float* AB2    = (const float*)d_in[26];
    const float* CW1    = (const float*)d_in[27];
    const float* CB1    = (const float*)d_in[28];
    const float* CW2    = (const float*)d_in[29];
    const float* CB2    = (const float*)d_in[30];
    float* out = (float*)d_out;

    if (ws_size < 86 * MB) return;

    char* w = (char*)d_ws;
    // bf16 weight arena [0,13MB)
    short* Wb = (short*)w;
    short* wbStart = Wb;
    short* wbGlu   = Wb + 524288;
    short* wbGcn   = Wb + 1048576;
    short* wbQkv   = Wb + 1572864;
    short* wbOut   = Wb + 3145728;
    short* wbFfn1  = Wb + 3670016;
    short* wbFfn2  = Wb + 4718592;
    short* wbFus   = Wb + 5767168;
    short* wbAw1   = Wb + 6291456;
    // small [13MB,14MB)
    float* sq   = (float*)(w + 13 * MB);
    int*   idx  = (int*)  (w + 13 * MB + (16u << 10));
    float* srow = (float*)(w + 13 * MB + (176u << 10));
    float* afb  = (float*)(w + 13 * MB + (192u << 10));
    float* Mbuf = (float*)(w + 13 * MB + (208u << 10));
    float* part = (float*)(w + 13 * MB + (212u << 10));
    // overlapped big buffers
    short* Xbf  = (short*)(w + 14 * MB);   // 8MB (dead after fc_start)
    short* hpreb= (short*)(w + 22 * MB);   // 4MB -> hgb after GLU gemm
    short* hgb  = (short*)(w + 22 * MB);   // 4MB bf16 GCN residual state
    float* big  = (float*)(w + 26 * MB);   // 26..42MB: vg/D2a/gcn-s/Opb/out-proj
    short* Opb  = (short*)(w + 26 * MB);   // 16MB: 4 splits (bf16 O-partials)
    float* hf   = (float*)(w + 26 * MB);   // 8MB f32 fusion out (big dead by then)
    float* Ml   = (float*)(w + 42 * MB);   // 1MB (dead ffn2o window during attn)
    float* ffn2o= (float*)(w + 42 * MB);   // 8MB
    short* hhi  = (short*)(w + 58 * MB);   // 4MB bf16 (GLU out, lives to fusion)
    short* hlo  = (short*)(w + 62 * MB);   // 4MB; dead after gram -> htb
    short* htb  = (short*)(w + 62 * MB);   // 4MB bf16 transformer state
    float* D2b1 = (float*)(w + 66 * MB);   // 16MB (KNN phase only)
    short* hfb  = (short*)(w + 66 * MB);   // 4MB
    short* aob  = (short*)(w + 70 * MB);   // 4MB; -> t256 (pool)
    float* t256 = (float*)(w + 70 * MB);
    short* Qb   = (short*)(w + 74 * MB);   // 4MB  (K=Qb+4MB, Vt=Qb+8MB)
    short* ffb  = (short*)(w + 74 * MB);   // 8MB (ffn1 out; Qb/Kb dead then)

    dim3 blk(256);

    // convert X + all GEMM weights to bf16
    CvtArgs ca;
    ca.src[0] = X;     ca.dst[0] = Xbf;     ca.n4[0] = ROWS * 1024 / 4;
    ca.src[1] = Wstart;ca.dst[1] = wbStart; ca.n4[1] = 524288 / 4;
    ca.src[2] = GluW;  ca.dst[2] = wbGlu;   ca.n4[2] = 524288 / 4;
    ca.src[3] = GcnW;  ca.dst[3] = wbGcn;   ca.n4[3] = 524288 / 4;
    ca.src[4] = QkvW;  ca.dst[4] = wbQkv;   ca.n4[4] = 1572864 / 4;
    ca.src[5] = OutW;  ca.dst[5] = wbOut;   ca.n4[5] = 524288 / 4;
    ca.src[6] = Ffn1W; ca.dst[6] = wbFfn1;  ca.n4[6] = 1048576 / 4;
    ca.src[7] = Ffn2W; ca.dst[7] = wbFfn2;  ca.n4[7] = 1048576 / 4;
    ca.src[8] = FusW;  ca.dst[8] = wbFus;   ca.n4[8] = 524288 / 4;
    ca.src[9] = AW1;   ca.dst[9] = wbAw1;   ca.n4[9] = 131072 / 4;
    cvt_k<<<dim3(256, 10), blk, 0, stream>>>(ca);

    // fc_start -> GLU (fused rowsq)
    mfma_gemm<1, 0><<<dim3(8, 64), blk, 0, stream>>>(Xbf, nullptr, wbStart, Bstart, nullptr, hpreb, ROWS, 512, 1024);
    mfma_gemm<0, 0><<<dim3(16, 64), blk, 0, stream>>>(hpreb, nullptr, wbGlu, GluB, big, nullptr, ROWS, 1024, 512);
    glu_row_k<<<dim3(ROWS), blk, 0, stream>>>(big, hhi, hlo, sq);

    // KNN graph: both batches in single gram + single topk dispatch
    mfma_gram<<<dim3(32, 32, 2), blk, 0, stream>>>(hhi, hlo, sq, big, D2b1);
    topk9_k<<<dim3(ROWS), blk, 0, stream>>>(big, D2b1, idx);

    // Layer 0: dual GEMM (GCN-L0 scores -> big; QKV-L0 -> Qb/Kb/Vt), both A = hhi
    dual_gemm<<<dim3(32, 64), blk, 0, stream>>>(hhi, wbGcn, GcnB, big,
                                                hhi, wbQkv, QkvB, Qb);
    gcn_post<<<dim3(ROWS), blk, 0, stream>>>(big, idx, GcnG, GcnBe, hhi, hgb);
    // Transformer L0
    flash_attn<<<dim3(32, 4, 16), blk, 0, stream>>>(Qb, Qb + 2097152, Qb + 4194304, Opb, Ml);
    merge_k<<<dim3(2048), blk, 0, stream>>>(Opb, Ml, aob);
    mfma_gemm<0, 0><<<dim3(8, 64), blk, 0, stream>>>(aob, nullptr, wbOut, OutB, big, nullptr, ROWS, 512, 512);
    ln_res<<<dim3(ROWS), blk, 0, stream>>>(hhi, big, Ln1G, Ln1B, htb);
    mfma_gemm<4, 0><<<dim3(16, 64), blk, 0, stream>>>(htb, nullptr, wbFfn1, Ffn1B, nullptr, ffb, ROWS, 1024, 512);
    mfma_gemm<0, 0><<<dim3(8, 64), blk, 0, stream>>>(ffb, nullptr, wbFfn2, Ffn2B, ffn2o, nullptr, ROWS, 512, 1024);
    ln_res<<<dim3(ROWS), blk, 0, stream>>>(htb, ffn2o, Ln2G, Ln2B, htb);

    // Layer 1: dual GEMM (GCN-L1 A=hgb; QKV-L1 A=htb)
    dual_gemm<<<dim3(32, 64), blk, 0, stream>>>(hgb, wbGcn + 262144, GcnB + 512, big,
                                                htb, wbQkv + 786432, QkvB + 1536, Qb);
    gcn_post<<<dim3(ROWS), blk, 0, stream>>>(big, idx, GcnG + 512, GcnBe + 512, hgb, hgb);
    // Transformer L1
    flash_attn<<<dim3(32, 4, 16), blk, 0, stream>>>(Qb, Qb + 2097152, Qb + 4194304, Opb, Ml);
    merge_k<<<dim3(2048), blk, 0, stream>>>(Opb, Ml, aob);
    mfma_gemm<0, 0><<<dim3(8, 64), blk, 0, stream>>>(aob, nullptr, wbOut + 262144, OutB + 512, big, nullptr, ROWS, 512, 512);
    ln_res<<<dim3(ROWS), blk, 0, stream>>>(htb, big, Ln1G + 512, Ln1B + 512, htb);
    mfma_gemm<4, 0><<<dim3(16, 64), blk, 0, stream>>>(htb, nullptr, wbFfn1 + 524288, Ffn1B + 1024, nullptr, ffb, ROWS, 1024, 512);
    mfma_gemm<0, 0><<<dim3(8, 64), blk, 0, stream>>>(ffb, nullptr, wbFfn2 + 524288, Ffn2B + 512, ffn2o, nullptr, ROWS, 512, 1024);
    ln_res<<<dim3(ROWS), blk, 0, stream>>>(htb, ffn2o, Ln2G + 512, Ln2B + 512, htb);

    // fusion: A = concat(hgb, htb) read directly by CAT GEMM; hf at 26MB (no overlap)
    mfma_gemm<2, 1><<<dim3(8, 64), blk, 0, stream>>>(hgb, htb, wbFus, FusB, hf, hfb, ROWS, 512, 1024);

    // gated attention pooling (tanh fused into GEMM)
    mfma_gemm<5, 0><<<dim3(4, 64), blk, 0, stream>>>(hfb, nullptr, wbAw1, AB1, t256, nullptr, ROWS, 256, 512);
    rowdot_k<<<dim3(ROWS), blk, 0, stream>>>(t256, AW2, AB2, srow);
    softmax_n_k<<<dim3(2), blk, 0, stream>>>(srow, afb, out);
    pool_part<<<dim3(32, 2), blk, 0, stream>>>(hf, afb, part);
    pool_fin<<<dim3(2), blk, 0, stream>>>(part, Mbuf, out);

    // classifier
    classifier_k<<<dim3(2), blk, 0, stream>>>(Mbuf, CW1, CB1, CW2, CB2, out);
}